// Round 11
// baseline (1611.445 us; speedup 1.0000x reference)
//
#include <hip/hip_runtime.h>
#include <hip/hip_bf16.h>

typedef __hip_bfloat16 bf16;
typedef unsigned short ushort_t;

// Problem constants
constexpr int kB = 16;    // batch
constexpr int kN = 2048;  // points
constexpr int kF = 1024;  // feat dims
constexpr int kC = 256;   // channels
constexpr int kH = 64;    // head dim

using f32x4 = __attribute__((ext_vector_type(4))) float;
using bf16x8 = __attribute__((ext_vector_type(8))) short;  // 8 bf16 (4 VGPRs)

__device__ __forceinline__ float us2f(unsigned short u) {
  union { unsigned int i; float f; } w;
  w.i = ((unsigned int)u) << 16;
  return w.f;
}
__device__ __forceinline__ unsigned short f2bu(float f) {
  union { bf16 h; unsigned short s; } u;
  u.h = __float2bfloat16(f);
  return u.s;
}

// ---------------------------------------------------------------------------
// fb[b,c] = mlp_b[c] + sum_f mlp_w[c,f] * feature[b,f]
// ---------------------------------------------------------------------------
__global__ __launch_bounds__(256) void k_fb(const float* __restrict__ feat,
                                            const float* __restrict__ mlp_w,
                                            const float* __restrict__ mlp_b,
                                            float* __restrict__ fb) {
  const int b = blockIdx.x >> 8;
  const int c = blockIdx.x & 255;
  const int t = threadIdx.x;
  const float* wr = mlp_w + (size_t)c * (kF + 3);
  const float* fr = feat + (size_t)b * kF;
  float s = 0.f;
  for (int f = t; f < kF; f += 256) s += wr[f] * fr[f];
  __shared__ float red[256];
  red[t] = s;
  __syncthreads();
  for (int k = 128; k > 0; k >>= 1) {
    if (t < k) red[t] += red[t + k];
    __syncthreads();
  }
  if (t == 0) fb[blockIdx.x] = red[0] + mlp_b[c];
}

// ---------------------------------------------------------------------------
// p[b,n,c] = fb[b,c] + sum_{j<3} mlp_w[c,1024+j] * prior[b,j,n]  (split bf16)
// ---------------------------------------------------------------------------
__global__ __launch_bounds__(256) void k_p0(const float* __restrict__ prior,
                                            const float* __restrict__ mlp_w,
                                            const float* __restrict__ fb,
                                            ushort_t* __restrict__ psh,
                                            ushort_t* __restrict__ psl) {
  const size_t i = (size_t)blockIdx.x * 256 + threadIdx.x;  // over B*N*C
  const int c = (int)(i & 255);
  const int n = (int)((i >> 8) & 2047);
  const int b = (int)(i >> 19);
  const float* wr = mlp_w + (size_t)c * (kF + 3) + kF;
  const float* pr = prior + (size_t)b * 3 * kN + n;
  const float v = fb[b * kC + c] + wr[0] * pr[0] + wr[1] * pr[kN] + wr[2] * pr[2 * kN];
  const ushort_t h = f2bu(v);
  psh[i] = h;
  psl[i] = f2bu(v - us2f(h));
}

// ---------------------------------------------------------------------------
// Pre-split weights into MFMA A-fragment order (hi/lo bf16).
// Regions (group = 8 elems): qk 4x2048 | v 4x8192 | t 4x8192 | dc1 4x8192
// ---------------------------------------------------------------------------
__global__ __launch_bounds__(256) void k_wsplit(const float* __restrict__ qk_w,
                                                const float* __restrict__ v_w,
                                                const float* __restrict__ t_w,
                                                const float* __restrict__ dc1_w,
                                                ushort_t* __restrict__ wfh,
                                                ushort_t* __restrict__ wfl) {
  const int idx = blockIdx.x * 256 + threadIdx.x;  // group index
  const float* src;
  int stride, OS_;
  size_t dstoff;
  int g;
  if (idx < 8192) {
    const int l = idx >> 11; g = idx & 2047;
    src = qk_w + (size_t)l * 64 * 256; stride = 256; OS_ = 4;
    dstoff = (size_t)l * 16384;
  } else if (idx < 40960) {
    const int i2 = idx - 8192; const int l = i2 >> 13; g = i2 & 8191;
    src = v_w + (size_t)l * 256 * 256; stride = 256; OS_ = 16;
    dstoff = 65536 + (size_t)l * 65536;
  } else if (idx < 73728) {
    const int i2 = idx - 40960; const int l = i2 >> 13; g = i2 & 8191;
    src = t_w + (size_t)l * 256 * 256; stride = 256; OS_ = 16;
    dstoff = 327680 + (size_t)l * 65536;
  } else {
    const int i2 = idx - 73728; const int l = i2 >> 13; g = i2 & 8191;
    src = dc1_w + (size_t)l * 256; stride = 1024; OS_ = 16;
    dstoff = 589824 + (size_t)l * 65536;
  }
  const int kk = g / (OS_ * 64);
  const int rem = g % (OS_ * 64);
  const int osub = rem >> 6;
  const int lane = rem & 63;
  const int o = osub * 16 + (lane & 15);
  const int c = kk * 32 + (lane >> 4) * 8;
  const float* sp = src + (size_t)o * stride + c;
  ushort_t h[8], l8[8];
#pragma unroll
  for (int j = 0; j < 8; ++j) {
    const float v = sp[j];
    h[j] = f2bu(v);
    l8[j] = f2bu(v - us2f(h[j]));
  }
  *(uint4*)(wfh + dstoff + (size_t)g * 8) = *(const uint4*)h;
  *(uint4*)(wfl + dstoff + (size_t)g * 8) = *(const uint4*)l8;
}

// ---------------------------------------------------------------------------
// Fused Q+V conv (split-bf16 MFMA, x read once). Block: 64 n, 4 waves.
// ---------------------------------------------------------------------------
__global__ __launch_bounds__(256) void k_qv(
    const ushort_t* __restrict__ xh, const ushort_t* __restrict__ xl,
    const ushort_t* __restrict__ wqh, const ushort_t* __restrict__ wql,
    const ushort_t* __restrict__ wvh, const ushort_t* __restrict__ wvl,
    const float* __restrict__ qbias, const float* __restrict__ vbias,
    ushort_t* __restrict__ Qh, ushort_t* __restrict__ Ql,
    bf16* __restrict__ Vo) {
  const int t = threadIdx.x;
  const int b = blockIdx.y;
  const int n0 = blockIdx.x * 64;
  const int lane = t & 63, wv = t >> 6;
  const int fr = lane & 15, fq = lane >> 4;
  const ushort_t* xbh = xh + ((size_t)b * kN + n0) * kC;
  const ushort_t* xbl = xl + ((size_t)b * kN + n0) * kC;
  f32x4 accq[4];
  f32x4 accv[4][4];
#pragma unroll
  for (int ns = 0; ns < 4; ++ns) {
    accq[ns] = (f32x4){0.f, 0.f, 0.f, 0.f};
#pragma unroll
    for (int s = 0; s < 4; ++s) accv[s][ns] = (f32x4){0.f, 0.f, 0.f, 0.f};
  }
  for (int kk = 0; kk < 8; ++kk) {
    bf16x8 bh[4], bl[4];
#pragma unroll
    for (int ns = 0; ns < 4; ++ns) {
      const size_t xi = (size_t)(ns * 16 + fr) * kC + kk * 32 + fq * 8;
      bh[ns] = *(const bf16x8*)(xbh + xi);
      bl[ns] = *(const bf16x8*)(xbl + xi);
    }
    {  // Q weights: region OS=4
      const size_t wi = (((size_t)kk * 4 + wv) * 64 + lane) * 8;
      const bf16x8 ah = *(const bf16x8*)(wqh + wi);
      const bf16x8 al = *(const bf16x8*)(wql + wi);
#pragma unroll
      for (int ns = 0; ns < 4; ++ns) {
        accq[ns] = __builtin_amdgcn_mfma_f32_16x16x32_bf16(ah, bh[ns], accq[ns], 0, 0, 0);
        accq[ns] = __builtin_amdgcn_mfma_f32_16x16x32_bf16(ah, bl[ns], accq[ns], 0, 0, 0);
        accq[ns] = __builtin_amdgcn_mfma_f32_16x16x32_bf16(al, bh[ns], accq[ns], 0, 0, 0);
      }
    }
#pragma unroll
    for (int s = 0; s < 4; ++s) {  // V weights: region OS=16
      const size_t wi = (((size_t)kk * 16 + wv * 4 + s) * 64 + lane) * 8;
      const bf16x8 ah = *(const bf16x8*)(wvh + wi);
      const bf16x8 al = *(const bf16x8*)(wvl + wi);
#pragma unroll
      for (int ns = 0; ns < 4; ++ns) {
        accv[s][ns] = __builtin_amdgcn_mfma_f32_16x16x32_bf16(ah, bh[ns], accv[s][ns], 0, 0, 0);
        accv[s][ns] = __builtin_amdgcn_mfma_f32_16x16x32_bf16(ah, bl[ns], accv[s][ns], 0, 0, 0);
        accv[s][ns] = __builtin_amdgcn_mfma_f32_16x16x32_bf16(al, bh[ns], accv[s][ns], 0, 0, 0);
      }
    }
  }
  {
    const int o0 = wv * 16 + fq * 4;
#pragma unroll
    for (int ns = 0; ns < 4; ++ns) {
      const int n = n0 + ns * 16 + fr;
      ushort_t h4[4], l4[4];
#pragma unroll
      for (int r = 0; r < 4; ++r) {
        const float v = accq[ns][r] + qbias[o0 + r];
        h4[r] = f2bu(v);
        l4[r] = f2bu(v - us2f(h4[r]));
      }
      *(ushort4*)(Qh + ((size_t)b * kN + n) * kH + o0) = *(const ushort4*)h4;
      *(ushort4*)(Ql + ((size_t)b * kN + n) * kH + o0) = *(const ushort4*)l4;
    }
  }
#pragma unroll
  for (int s = 0; s < 4; ++s) {
    const int o0 = (wv * 4 + s) * 16 + fq * 4;
#pragma unroll
    for (int ns = 0; ns < 4; ++ns) {
      const int n = n0 + ns * 16 + fr;
#pragma unroll
      for (int r = 0; r < 4; ++r)
        Vo[((size_t)b * kC + o0 + r) * kN + n] = __float2bfloat16(accv[s][ns][r] + vbias[o0 + r]);
    }
  }
}

// ---------------------------------------------------------------------------
// MFMA 1x1 conv (split-bf16). x: [b][n][256] split. Block: 64 n, 4 waves.
// MODE 2: BN partial stats only    MODE 3: fused BN+leaky+residual into p
// MODE 4: fp32 accumulate [b][o][N] (dc1)
// ---------------------------------------------------------------------------
template <int O, int MODE>
__global__ __launch_bounds__(256) void k_conv(
    const ushort_t* __restrict__ xh, const ushort_t* __restrict__ xl,
    const ushort_t* __restrict__ wfh, const ushort_t* __restrict__ wfl,
    const float* __restrict__ bias,
    ushort_t* __restrict__ o1, ushort_t* __restrict__ o2,  // psh/psl (MODE3)
    float* __restrict__ of,                                // part or hacc
    const float* __restrict__ mean, const float* __restrict__ rsig,
    const float* __restrict__ g, const float* __restrict__ bb, int first) {
  constexpr int KK = 8;
  constexpr int OS = O / 16;
  constexpr int OSW = OS / 4;
  const int t = threadIdx.x;
  const int b = blockIdx.y;
  const int n0 = blockIdx.x * 64;
  const int lane = t & 63, wv = t >> 6;
  const int fr = lane & 15, fq = lane >> 4;
  const ushort_t* xbh = xh + ((size_t)b * kN + n0) * kC;
  const ushort_t* xbl = xl + ((size_t)b * kN + n0) * kC;
  f32x4 acc[OSW][4];
#pragma unroll
  for (int s = 0; s < OSW; ++s)
#pragma unroll
    for (int ns = 0; ns < 4; ++ns) acc[s][ns] = (f32x4){0.f, 0.f, 0.f, 0.f};
  for (int kk = 0; kk < KK; ++kk) {
    bf16x8 bh[4], bl[4];
#pragma unroll
    for (int ns = 0; ns < 4; ++ns) {
      const size_t xi = (size_t)(ns * 16 + fr) * kC + kk * 32 + fq * 8;
      bh[ns] = *(const bf16x8*)(xbh + xi);
      bl[ns] = *(const bf16x8*)(xbl + xi);
    }
#pragma unroll
    for (int s = 0; s < OSW; ++s) {
      const size_t wi = (((size_t)kk * OS + wv * OSW + s) * 64 + lane) * 8;
      const bf16x8 ah = *(const bf16x8*)(wfh + wi);
      const bf16x8 al = *(const bf16x8*)(wfl + wi);
#pragma unroll
      for (int ns = 0; ns < 4; ++ns) {
        acc[s][ns] = __builtin_amdgcn_mfma_f32_16x16x32_bf16(ah, bh[ns], acc[s][ns], 0, 0, 0);
        acc[s][ns] = __builtin_amdgcn_mfma_f32_16x16x32_bf16(ah, bl[ns], acc[s][ns], 0, 0, 0);
        acc[s][ns] = __builtin_amdgcn_mfma_f32_16x16x32_bf16(al, bh[ns], acc[s][ns], 0, 0, 0);
      }
    }
  }
  if (MODE == 2) {
    const int blk = blockIdx.y * gridDim.x + blockIdx.x;  // 0..511
#pragma unroll
    for (int s = 0; s < OSW; ++s) {
      const int o0 = (wv * OSW + s) * 16 + fq * 4;
#pragma unroll
      for (int r = 0; r < 4; ++r) {
        const float bz = bias[o0 + r];
        float s1 = 0.f, s2 = 0.f;
#pragma unroll
        for (int ns = 0; ns < 4; ++ns) {
          const float y = acc[s][ns][r] + bz;
          s1 += y;
          s2 += y * y;
        }
#pragma unroll
        for (int mask = 1; mask < 16; mask <<= 1) {
          s1 += __shfl_xor(s1, mask);
          s2 += __shfl_xor(s2, mask);
        }
        if (fr == 0) {
          of[(size_t)(o0 + r) * 512 + blk] = s1;
          of[131072 + (size_t)(o0 + r) * 512 + blk] = s2;
        }
      }
    }
  } else if (MODE == 3) {
#pragma unroll
    for (int s = 0; s < OSW; ++s) {
      const int o0 = (wv * OSW + s) * 16 + fq * 4;
      float av[4], cv[4];
#pragma unroll
      for (int r = 0; r < 4; ++r) {
        const float a = g[o0 + r] * rsig[o0 + r];
        av[r] = a;
        cv[r] = bb[o0 + r] + a * (bias[o0 + r] - mean[o0 + r]);
      }
#pragma unroll
      for (int ns = 0; ns < 4; ++ns) {
        const int n = n0 + ns * 16 + fr;
        const size_t idx = ((size_t)b * kN + n) * kC + o0;
        ushort_t ph4[4], pl4[4], nh4[4], nl4[4];
        *(ushort4*)ph4 = *(const ushort4*)(o1 + idx);
        *(ushort4*)pl4 = *(const ushort4*)(o2 + idx);
#pragma unroll
        for (int r = 0; r < 4; ++r) {
          float z = av[r] * acc[s][ns][r] + cv[r];
          z = z > 0.f ? z : 0.2f * z;
          const float pv = us2f(ph4[r]) + us2f(pl4[r]) + z;
          nh4[r] = f2bu(pv);
          nl4[r] = f2bu(pv - us2f(nh4[r]));
        }
        *(ushort4*)(o1 + idx) = *(const ushort4*)nh4;
        *(ushort4*)(o2 + idx) = *(const ushort4*)nl4;
      }
    }
  } else {  // MODE 4: accumulate into hacc [b][o][N]
#pragma unroll
    for (int s = 0; s < OSW; ++s) {
      const int o0 = (wv * OSW + s) * 16 + fq * 4;
#pragma unroll
      for (int ns = 0; ns < 4; ++ns) {
        const int n = n0 + ns * 16 + fr;
#pragma unroll
        for (int r = 0; r < 4; ++r) {
          float* pp = of + ((size_t)b * kC + o0 + r) * kN + n;
          *pp = (first ? 0.f : *pp) + acc[s][ns][r];
        }
      }
    }
  }
}

// ---------------------------------------------------------------------------
// Reduce BN partials (part [c][512] sums + [c][512] sumsq at offset 131072)
// ---------------------------------------------------------------------------
__global__ __launch_bounds__(128) void k_bnred(const float* __restrict__ part,
                                               float* __restrict__ mean,
                                               float* __restrict__ rsig) {
  const int c = blockIdx.x, t = threadIdx.x;
  const float4 v1 = *(const float4*)&part[(size_t)c * 512 + t * 4];
  const float4 v2 = *(const float4*)&part[131072 + (size_t)c * 512 + t * 4];
  float s1 = v1.x + v1.y + v1.z + v1.w;
  float s2 = v2.x + v2.y + v2.z + v2.w;
  __shared__ float r1[128], r2[128];
  r1[t] = s1;
  r2[t] = s2;
  __syncthreads();
  for (int k = 64; k > 0; k >>= 1) {
    if (t < k) {
      r1[t] += r1[t + k];
      r2[t] += r2[t + k];
    }
    __syncthreads();
  }
  if (t == 0) {
    const float im = 1.f / (float)(kB * kN);
    const float m = r1[0] * im;
    const float var = r2[0] * im - m * m;
    mean[c] = m;
    rsig[c] = rsqrtf(var + 1e-5f);
  }
}

// ---------------------------------------------------------------------------
// Row softmax stats via split-bf16 MFMA. T14 staging: load regs at tile top,
// ds_write at tile bottom (latency hidden under the E compute).
// ---------------------------------------------------------------------------
__global__ __launch_bounds__(256) void k_rowstats(const ushort_t* __restrict__ Qhi,
                                                  const ushort_t* __restrict__ Qlo,
                                                  float* __restrict__ rmx,
                                                  float* __restrict__ rsn) {
  __shared__ __align__(16) ushort_t Bh[2][64][72];
  __shared__ __align__(16) ushort_t Bl[2][64][72];
  const int b = blockIdx.y, t = threadIdx.x;
  const int r0 = blockIdx.x * 64;
  const int lane = t & 63, w = t >> 6;
  const int fr = lane & 15, fq = lane >> 4;
  const size_t qbase = (size_t)b * kN * kH;
  bf16x8 ah0, ah1, al0, al1;
  {
    const ushort_t* qh = Qhi + qbase + (size_t)(r0 + w * 16 + fr) * kH;
    const ushort_t* ql = Qlo + qbase + (size_t)(r0 + w * 16 + fr) * kH;
    ah0 = *(const bf16x8*)(qh + fq * 8);
    ah1 = *(const bf16x8*)(qh + 32 + fq * 8);
    al0 = *(const bf16x8*)(ql + fq * 8);
    al1 = *(const bf16x8*)(ql + 32 + fq * 8);
  }
  float mx[4] = {-3.0e38f, -3.0e38f, -3.0e38f, -3.0e38f};
  float sm[4] = {0.f, 0.f, 0.f, 0.f};
  const int srow = t >> 2, scol = (t & 3) * 16;
  {  // prologue: stage tile 0 directly
    const ushort_t* qh = Qhi + qbase + (size_t)srow * kH + scol;
    const ushort_t* ql = Qlo + qbase + (size_t)srow * kH + scol;
    *(uint4*)&Bh[0][srow][scol] = *(const uint4*)qh;
    *(uint4*)&Bh[0][srow][scol + 8] = *(const uint4*)(qh + 8);
    *(uint4*)&Bl[0][srow][scol] = *(const uint4*)ql;
    *(uint4*)&Bl[0][srow][scol + 8] = *(const uint4*)(ql + 8);
  }
  __syncthreads();
  int cur = 0;
  for (int m0 = 0; m0 < kN; m0 += 64) {
    // T14: issue next tile's loads into registers
    uint4 rh0, rh1, rl0, rl1;
    const bool pf = (m0 + 64 < kN);
    if (pf) {
      const ushort_t* qh = Qhi + qbase + (size_t)(m0 + 64 + srow) * kH + scol;
      const ushort_t* ql = Qlo + qbase + (size_t)(m0 + 64 + srow) * kH + scol;
      rh0 = *(const uint4*)qh;
      rh1 = *(const uint4*)(qh + 8);
      rl0 = *(const uint4*)ql;
      rl1 = *(const uint4*)(ql + 8);
    }
    float ev[4][4];
#pragma unroll
    for (int cs = 0; cs < 4; ++cs) {
      const bf16x8 bh0 = *(const bf16x8*)&Bh[cur][cs * 16 + fr][fq * 8];
      const bf16x8 bh1 = *(const bf16x8*)&Bh[cur][cs * 16 + fr][32 + fq * 8];
      const bf16x8 bl0 = *(const bf16x8*)&Bl[cur][cs * 16 + fr][fq * 8];
      const bf16x8 bl1 = *(const bf16x8*)&Bl[cur][cs * 16 + fr][32 + fq * 8];
      f32x4 e = {0.f, 0.f, 0.f, 0.f};
      e = __builtin_amdgcn_mfma_f32_16x16x32_bf16(ah0, bh0, e, 0, 0, 0);
      e = __builtin_amdgcn_mfma_f32_16x16x32_bf16(ah1, bh1, e, 0, 0, 0);
      e = __builtin_amdgcn_mfma_f32_16x16x32_bf16(ah0, bl0, e, 0, 0, 0);
      e = __builtin_amdgcn_mfma_f32_16x16x32_bf16(ah1, bl1, e, 0, 0, 0);
      e = __builtin_amdgcn_mfma_f32_16x16x32_bf16(al0, bh0, e, 0, 0, 0);
      e = __builtin_amdgcn_mfma_f32_16x16x32_bf16(al1, bh1, e, 0, 0, 0);
      ev[cs][0] = e[0]; ev[cs][1] = e[1]; ev[cs][2] = e[2]; ev[cs][3] = e[3];
    }
#pragma unroll
    for (int r = 0; r < 4; ++r) {
      const float tmax = fmaxf(fmaxf(ev[0][r], ev[1][r]), fmaxf(ev[2][r], ev[3][r]));
      const float nm = fmaxf(mx[r], tmax);
      sm[r] = sm[r] * __expf(mx[r] - nm) + __expf(ev[0][r] - nm) + __expf(ev[1][r] - nm) +
              __expf(ev[2][r] - nm) + __expf(ev[3][r] - nm);
      mx[r] = nm;
    }
    // T14: write staged regs late
    if (pf) {
      *(uint4*)&Bh[cur ^ 1][srow][scol] = rh0;
      *(uint4*)&Bh[cur ^ 1][srow][scol + 8] = rh1;
      *(uint4*)&Bl[cur ^ 1][srow][scol] = rl0;
      *(uint4*)&Bl[cur ^ 1][srow][scol + 8] = rl1;
    }
    __syncthreads();
    cur ^= 1;
  }
#pragma unroll
  for (int mask = 1; mask < 16; mask <<= 1) {
#pragma unroll
    for (int r = 0; r < 4; ++r) {
      const float om = __shfl_xor(mx[r], mask);
      const float os = __shfl_xor(sm[r], mask);
      const float nm = fmaxf(mx[r], om);
      sm[r] = sm[r] * __expf(mx[r] - nm) + os * __expf(om - nm);
      mx[r] = nm;
    }
  }
  if (fr == 0) {
#pragma unroll
    for (int r = 0; r < 4; ++r) {
      const int row = r0 + w * 16 + fq * 4 + r;
      rmx[(size_t)b * kN + row] = mx[r];
      rsn[(size_t)b * kN + row] = 1.f / sm[r];
    }
  }
}

// ---------------------------------------------------------------------------
// Column pass, MT=64, de-staged: Q A-frags and V B-frags read DIRECTLY from
// global (L2-resident; V has zero intra-block reuse, Q is L2-hot). Only the
// wave-crossing P tile lives in LDS, double-buffered -> ONE barrier per tile.
// LDS 10.5 KB (occupancy now VGPR-bound). Numerics identical to r7-r10.
// ---------------------------------------------------------------------------
__global__ __launch_bounds__(256) void k_colpass(const ushort_t* __restrict__ Qhi,
                                                 const ushort_t* __restrict__ Qlo,
                                                 const bf16* __restrict__ V,
                                                 const float* __restrict__ rmx,
                                                 const float* __restrict__ rsn,
                                                 const ushort_t* __restrict__ psh,
                                                 const ushort_t* __restrict__ psl,
                                                 ushort_t* __restrict__ ush,
                                                 ushort_t* __restrict__ usl) {
  constexpr int MT = 64, NT = 32;
  __shared__ __align__(16) ushort_t Pl[2][MT][40];
  __shared__ float CsI[MT];
  const int t = threadIdx.x;
  const int b = blockIdx.y;
  const int mBase = blockIdx.x * MT;
  const size_t qbase = (size_t)b * kN * kH;
  const ushort_t* Vb_ = (const ushort_t*)V + (size_t)b * kC * kN;
  const int lane = t & 63, wv = t >> 6;
  const int fr = lane & 15, fq = lane >> 4;
  // Persistent B fragments for E: my wave's m-slice, m = mBase + wv*16 + fr
  bf16x8 bmh0, bmh1, bml0, bml1;
  {
    const ushort_t* qh = Qhi + qbase + (size_t)(mBase + wv * 16 + fr) * kH;
    const ushort_t* ql = Qlo + qbase + (size_t)(mBase + wv * 16 + fr) * kH;
    bmh0 = *(const bf16x8*)(qh + fq * 8);
    bmh1 = *(const bf16x8*)(qh + 32 + fq * 8);
    bml0 = *(const bf16x8*)(ql + fq * 8);
    bml1 = *(const bf16x8*)(ql + 32 + fq * 8);
  }
  f32x4 acc[4][4];
#pragma unroll
  for (int i = 0; i < 4; ++i)
#pragma unroll
    for (int j = 0; j < 4; ++j) acc[i][j] = (f32x4){0.f, 0.f, 0.f, 0.f};
  float csloc = 0.f;
  int cur = 0;
  for (int n0 = 0; n0 < kN; n0 += NT) {
    // V B-fragments for PV: issue FIRST (latency hides under E + barrier)
    bf16x8 bv[4];
#pragma unroll
    for (int cs = 0; cs < 4; ++cs)
      bv[cs] = *(const bf16x8*)(Vb_ + (size_t)(wv * 64 + cs * 16 + fr) * kN + n0 + fq * 8);
    // softmax stats (vectorized)
    const float4 rm0 = *(const float4*)&rmx[(size_t)b * kN + n0 + fq * 4];
    const float4 rm1 = *(const float4*)&rmx[(size_t)b * kN + n0 + 16 + fq * 4];
    const float4 rs0 = *(const float4*)&rsn[(size_t)b * kN + n0 + fq * 4];
    const float4 rs1 = *(const float4*)&rsn[(size_t)b * kN + n0 + 16 + fq * 4];
    // E phase: Q A-fragments direct from global (same rows for all 4 waves,
    // L2-hot). 6 split-MFMAs per n-subtile, identical order to k_rowstats.
#pragma unroll
    for (int ns = 0; ns < 2; ++ns) {
      const ushort_t* qh = Qhi + qbase + (size_t)(n0 + ns * 16 + fr) * kH;
      const ushort_t* ql = Qlo + qbase + (size_t)(n0 + ns * 16 + fr) * kH;
      const bf16x8 ah0 = *(const bf16x8*)(qh + fq * 8);
      const bf16x8 ah1 = *(const bf16x8*)(qh + 32 + fq * 8);
      const bf16x8 al0 = *(const bf16x8*)(ql + fq * 8);
      const bf16x8 al1 = *(const bf16x8*)(ql + 32 + fq * 8);
      f32x4 e = {0.f, 0.f, 0.f, 0.f};
      e = __builtin_amdgcn_mfma_f32_16x16x32_bf16(ah0, bmh0, e, 0, 0, 0);
      e = __builtin_amdgcn_mfma_f32_16x16x32_bf16(ah1, bmh1, e, 0, 0, 0);
      e = __builtin_amdgcn_mfma_f32_16x16x32_bf16(ah0, bml0, e, 0, 0, 0);
      e = __builtin_amdgcn_mfma_f32_16x16x32_bf16(ah1, bml1, e, 0, 0, 0);
      e = __builtin_amdgcn_mfma_f32_16x16x32_bf16(al0, bmh0, e, 0, 0, 0);
      e = __builtin_amdgcn_mfma_f32_16x16x32_bf16(al1, bmh1, e, 0, 0, 0);
      const float4 rm = ns ? rm1 : rm0;
      const float4 rs = ns ? rs1 : rs0;
      ushort_t p4[4];
      {
        const float p0 = __expf(e[0] - rm.x) * rs.x;
        const float p1 = __expf(e[1] - rm.y) * rs.y;
        const float p2 = __expf(e[2] - rm.z) * rs.z;
        const float p3 = __expf(e[3] - rm.w) * rs.w;
        p4[0] = f2bu(p0); p4[1] = f2bu(p1); p4[2] = f2bu(p2); p4[3] = f2bu(p3);
        csloc += p0 + p1 + p2 + p3;
      }
      *(ushort4*)&Pl[cur][wv * 16 + fr][ns * 16 + fq * 4] = *(const ushort4*)p4;
    }
    __syncthreads();  // Pl[cur] complete (the ONLY barrier per tile; the
                      // 2-buffer alternation makes a second one unnecessary)
    // PV: A = Pl[cur] (rows m), B = V global regs (cols c = wave's 64-c slice)
    bf16x8 am[4];
#pragma unroll
    for (int ms = 0; ms < 4; ++ms)
      am[ms] = *(const bf16x8*)&Pl[cur][ms * 16 + fr][fq * 8];
#pragma unroll
    for (int ms = 0; ms < 4; ++ms)
#pragma unroll
      for (int cs = 0; cs < 4; ++cs)
        acc[ms][cs] = __builtin_amdgcn_mfma_f32_16x16x32_bf16(am[ms], bv[cs], acc[ms][cs], 0, 0, 0);
    cur ^= 1;
  }
  // colsum reduce over fq
  csloc += __shfl_xor(csloc, 16);
  csloc += __shfl_xor(csloc, 32);
  if (fq == 0) CsI[wv * 16 + fr] = 1.f / (1e-9f + csloc);
  __syncthreads();
  // epilogue: row = m = ms*16+fq*4+r, col = c = wv*64+cs*16+fr
#pragma unroll
  for (int ms = 0; ms < 4; ++ms) {
#pragma unroll
    for (int r = 0; r < 4; ++r) {
      const int ml = ms * 16 + fq * 4 + r;
      const float inv = CsI[ml];
      const size_t row = ((size_t)b * kN + mBase + ml) * kC;
#pragma unroll
      for (int cs = 0; cs < 4; ++cs) {
        const int c = wv * 64 + cs * 16 + fr;
        const float xv = us2f(psh[row + c]) + us2f(psl[row + c]);
        const float u = xv - acc[ms][cs][r] * inv;
        const ushort_t h = f2bu(u);
        ush[row + c] = h;
        usl[row + c] = f2bu(u - us2f(h));
      }
    }
  }
}

// ---------------------------------------------------------------------------
// BN stats per channel over (B, N), fp32 [b][nch][N] input, biased var.
// ---------------------------------------------------------------------------
__global__ __launch_bounds__(256) void k_bnstats(const float* __restrict__ y, int nch,
                                                 float* __restrict__ mean,
                                                 float* __restrict__ rsig) {
  const int c = blockIdx.x, t = threadIdx.x;
  float s = 0.f, s2 = 0.f;
  for (int b = 0; b < kB; ++b) {
    const float* p = y + ((size_t)b * nch + c) * kN;
    for (int n = t; n < kN; n += 256) {
      const float v = p[n];
      s += v;
      s2 += v * v;
    }
  }
  __shared__ float r1[256], r2[256];
  r1[t] = s;
  r2[t] = s2;
  __syncthreads();
  for (int k = 128; k > 0; k >>= 1) {
    if (t < k) {
      r1[t] += r1[t + k];
      r2[t] += r2[t + k];
    }
    __syncthreads();
  }
  if (t == 0) {
    const float im = 1.f / (float)(kB * kN);
    const float m = r1[0] * im;
    const float var = r2[0] * im - m * m;
    mean[c] = m;
    rsig[c] = rsqrtf(var + 1e-5f);
  }
}

// ---------------------------------------------------------------------------
// dc2: tpre[b,j,n] = dc2_b[j] + sum_c dc2_w[j,c] * leaky(bn(h[b,c,n]))
// ---------------------------------------------------------------------------
__global__ __launch_bounds__(256) void k_dc2(const float* __restrict__ h,
                                             const float* __restrict__ mean,
                                             const float* __restrict__ rsig,
                                             const float* __restrict__ g,
                                             const float* __restrict__ bb,
                                             const float* __restrict__ w,
                                             const float* __restrict__ d2b,
                                             float* __restrict__ tpre) {
  __shared__ float wS[3][kC];
  __shared__ float aS[kC], cS[kC];
  const int t = threadIdx.x, b = blockIdx.y;
  const int n = blockIdx.x * 256 + t;
  {
    const float a = g[t] * rsig[t];
    aS[t] = a;
    cS[t] = bb[t] - a * mean[t];
    wS[0][t] = w[t];
    wS[1][t] = w[kC + t];
    wS[2][t] = w[2 * kC + t];
  }
  __syncthreads();
  float a0 = d2b[0], a1 = d2b[1], a2 = d2b[2];
  const float* hb = h + (size_t)b * kC * kN + n;
  for (int c = 0; c < kC; ++c) {
    float z = hb[(size_t)c * kN] * aS[c] + cS[c];
    z = z > 0.f ? z : 0.2f * z;
    a0 += wS[0][c] * z;
    a1 += wS[1][c] * z;
    a2 += wS[2][c] * z;
  }
  tpre[((size_t)b * 3 + 0) * kN + n] = a0;
  tpre[((size_t)b * 3 + 1) * kN + n] = a1;
  tpre[((size_t)b * 3 + 2) * kN + n] = a2;
}

// ---------------------------------------------------------------------------
// Final: out[b,n,j] = tanh(g[j]*(tpre[b,j,n]-mean[j])*rsig[j] + b[j])
// ---------------------------------------------------------------------------
__global__ __launch_bounds__(256) void k_final(const float* __restrict__ tpre,
                                               const float* __restrict__ mean,
                                               const float* __restrict__ rsig,
                                               const float* __restrict__ g,
                                               const float* __restrict__ bb,
                                               float* __restrict__ out) {
  const int i = blockIdx.x * 256 + threadIdx.x;  // over B*N
  const int n = i & (kN - 1), b = i >> 11;
#pragma unroll
  for (int j = 0; j < 3; ++j) {
    const float v = tpre[((size_t)b * 3 + j) * kN + n];
    const float z = g[j] * (v - mean[j]) * rsig[j] + bb[j];
    out[(size_t)i * 3 + j] = tanhf(z);
  }
}

// ---------------------------------------------------------------------------
extern "C" void kernel_launch(void* const* d_in, const int* in_sizes, int n_in,
                              void* d_out, int out_size, void* d_ws, size_t ws_size,
                              hipStream_t stream) {
  const float* feature  = (const float*)d_in[0];
  const float* prior    = (const float*)d_in[1];
  const float* mlp_w    = (const float*)d_in[2];
  const float* mlp_b    = (const float*)d_in[3];
  const float* qk_w     = (const float*)d_in[4];
  const float* qk_b     = (const float*)d_in[5];
  const float* v_w      = (const float*)d_in[6];
  const float* v_b      = (const float*)d_in[7];
  const float* t_w      = (const float*)d_in[8];
  const float* t_b      = (const float*)d_in[9];
  const float* bn_g     = (const float*)d_in[10];
  const float* bn_b     = (const float*)d_in[11];
  const float* dc1_w    = (const float*)d_in[12];
  const float* dc1_bn_g = (const float*)d_in[13];
  const float* dc1_bn_b = (const float*)d_in[14];
  const float* dc2_w    = (const float*)d_in[15];
  const float* dc2_b    = (const float*)d_in[16];
  const float* dc2_bn_g = (const float*)d_in[17];
  const float* dc2_bn_b = (const float*)d_in[18];
  float* out = (float*)d_out;

  // Workspace carve. Total ~125 MiB.
  char* base = (char*)d_ws;
  size_t off = 0;
  auto carve = [&](size_t bytes) {
    char* p = base + off;
    off += (bytes + 255) & ~(size_t)255;
    return p;
  };
  const size_t ne = (size_t)kB * kN * kC;                 // 8,388,608
  ushort_t* psh  = (ushort_t*)carve(ne * 2);              // p hi   16 MiB
  ushort_t* psl  = (ushort_t*)carve(ne * 2);              // p lo   16 MiB
  ushort_t* ush  = (ushort_t*)carve(ne * 2);              // u hi   16 MiB
  ushort_t* usl  = (ushort_t*)carve(ne * 2);              // u lo   16 MiB
  float*    hacc = (float*)carve(ne * 4);                 // dc1    32 MiB
  ushort_t* Qhi  = (ushort_t*)carve((size_t)kB * kN * kH * 2);  // 4 MiB
  ushort_t* Qlo  = (ushort_t*)carve((size_t)kB * kN * kH * 2);  // 4 MiB
  bf16*     Vb   = (bf16*)carve(ne * 2);                  // V      16 MiB
  ushort_t* wfh  = (ushort_t*)carve((size_t)851968 * 2);  // 1.63 MiB
  ushort_t* wfl  = (ushort_t*)carve((size_t)851968 * 2);  // 1.63 MiB
  float*    part = (float*)carve((size_t)2 * 131072 * 4); // 1 MiB
  float*    rmx  = (float*)carve((size_t)kB * kN * 4);
  float*    rsn  = (float*)carve((size_t)kB * kN * 4);
  float*    fb   = (float*)carve((size_t)kB * kC * 4);
  float*    bnm  = (float*)carve(kC * 4);
  float*    bnr  = (float*)carve(kC * 4);
  float*    tpre = (float*)carve((size_t)kB * 3 * kN * 4);

  k_wsplit<<<416, 256, 0, stream>>>(qk_w, v_w, t_w, dc1_w, wfh, wfl);
  k_fb<<<kB * kC, 256, 0, stream>>>(feature, mlp_w, mlp_b, fb);
  k_p0<<<(int)(ne / 256), 256, 0, stream>>>(prior, mlp_w, fb, psh, psl);

  const dim3 gC(kN / 64, kB);
  for (int l = 0; l < 4; ++l) {
    const size_t qk_off  = (size_t)l * 16384;
    const size_t v_off   = 65536 + (size_t)l * 65536;
    const size_t t_off   = 327680 + (size_t)l * 65536;
    const size_t dc1_off = 589824 + (size_t)l * 65536;
    k_qv<<<gC, 256, 0, stream>>>(psh, psl, wfh + qk_off, wfl + qk_off,
                                 wfh + v_off, wfl + v_off,
                                 qk_b + l * kH, v_b + l * kC, Qhi, Qlo, Vb);
    k_rowstats<<<gC, 256, 0, stream>>>(Qhi, Qlo, rmx, rsn);
    k_colpass<<<gC, 256, 0, stream>>>(Qhi, Qlo, Vb, rmx, rsn, psh, psl, ush, usl);
    k_conv<256, 2><<<gC, 256, 0, stream>>>(ush, usl, wfh + t_off, wfl + t_off,
                                           t_b + l * kC, nullptr, nullptr, part,
                                           nullptr, nullptr, nullptr, nullptr, 0);
    k_bnred<<<kC, 128, 0, stream>>>(part, bnm, bnr);
    k_conv<256, 3><<<gC, 256, 0, stream>>>(ush, usl, wfh + t_off, wfl + t_off,
                                           t_b + l * kC, psh, psl, nullptr,
                                           bnm, bnr, bn_g + l * kC, bn_b + l * kC, 0);
    k_conv<256, 4><<<gC, 256, 0, stream>>>(psh, psl, wfh + dc1_off, wfl + dc1_off,
                                           nullptr, nullptr, nullptr, hacc,
                                           nullptr, nullptr, nullptr, nullptr, l == 0 ? 1 : 0);
  }

  k_bnstats<<<kC, 256, 0, stream>>>(hacc, kC, bnm, bnr);
  k_dc2<<<dim3(kN / 256, kB), 256, 0, stream>>>(hacc, bnm, bnr, dc1_bn_g, dc1_bn_b,
                                                dc2_w, dc2_b, tpre);
  k_bnstats<<<3, 256, 0, stream>>>(tpre, 3, bnm, bnr);
  k_final<<<(kB * kN) / 256, 256, 0, stream>>>(tpre, bnm, bnr, dc2_bn_g, dc2_bn_b, out);
}

// Round 12
// 1233.862 us; speedup vs baseline: 1.3060x; 1.3060x over previous
//
#include <hip/hip_runtime.h>
#include <hip/hip_bf16.h>

typedef __hip_bfloat16 bf16;
typedef unsigned short ushort_t;

// Problem constants
constexpr int kB = 16;    // batch
constexpr int kN = 2048;  // points
constexpr int kF = 1024;  // feat dims
constexpr int kC = 256;   // channels
constexpr int kH = 64;    // head dim

using f32x4 = __attribute__((ext_vector_type(4))) float;
using bf16x8 = __attribute__((ext_vector_type(8))) short;  // 8 bf16 (4 VGPRs)

__device__ __forceinline__ float us2f(unsigned short u) {
  union { unsigned int i; float f; } w;
  w.i = ((unsigned int)u) << 16;
  return w.f;
}
__device__ __forceinline__ unsigned short f2bu(float f) {
  union { bf16 h; unsigned short s; } u;
  u.h = __float2bfloat16(f);
  return u.s;
}

// ---------------------------------------------------------------------------
// fb[b,c] = mlp_b[c] + sum_f mlp_w[c,f] * feature[b,f]
// ---------------------------------------------------------------------------
__global__ __launch_bounds__(256) void k_fb(const float* __restrict__ feat,
                                            const float* __restrict__ mlp_w,
                                            const float* __restrict__ mlp_b,
                                            float* __restrict__ fb) {
  const int b = blockIdx.x >> 8;
  const int c = blockIdx.x & 255;
  const int t = threadIdx.x;
  const float* wr = mlp_w + (size_t)c * (kF + 3);
  const float* fr = feat + (size_t)b * kF;
  float s = 0.f;
  for (int f = t; f < kF; f += 256) s += wr[f] * fr[f];
  __shared__ float red[256];
  red[t] = s;
  __syncthreads();
  for (int k = 128; k > 0; k >>= 1) {
    if (t < k) red[t] += red[t + k];
    __syncthreads();
  }
  if (t == 0) fb[blockIdx.x] = red[0] + mlp_b[c];
}

// ---------------------------------------------------------------------------
// p[b,n,c] = fb[b,c] + sum_{j<3} mlp_w[c,1024+j] * prior[b,j,n]  (split bf16)
// ---------------------------------------------------------------------------
__global__ __launch_bounds__(256) void k_p0(const float* __restrict__ prior,
                                            const float* __restrict__ mlp_w,
                                            const float* __restrict__ fb,
                                            ushort_t* __restrict__ psh,
                                            ushort_t* __restrict__ psl) {
  const size_t i = (size_t)blockIdx.x * 256 + threadIdx.x;  // over B*N*C
  const int c = (int)(i & 255);
  const int n = (int)((i >> 8) & 2047);
  const int b = (int)(i >> 19);
  const float* wr = mlp_w + (size_t)c * (kF + 3) + kF;
  const float* pr = prior + (size_t)b * 3 * kN + n;
  const float v = fb[b * kC + c] + wr[0] * pr[0] + wr[1] * pr[kN] + wr[2] * pr[2 * kN];
  const ushort_t h = f2bu(v);
  psh[i] = h;
  psl[i] = f2bu(v - us2f(h));
}

// ---------------------------------------------------------------------------
// Pre-split weights into MFMA A-fragment order (hi/lo bf16).
// Regions (group = 8 elems): qk 4x2048 | v 4x8192 | t 4x8192 | dc1 4x8192
// ---------------------------------------------------------------------------
__global__ __launch_bounds__(256) void k_wsplit(const float* __restrict__ qk_w,
                                                const float* __restrict__ v_w,
                                                const float* __restrict__ t_w,
                                                const float* __restrict__ dc1_w,
                                                ushort_t* __restrict__ wfh,
                                                ushort_t* __restrict__ wfl) {
  const int idx = blockIdx.x * 256 + threadIdx.x;  // group index
  const float* src;
  int stride, OS_;
  size_t dstoff;
  int g;
  if (idx < 8192) {
    const int l = idx >> 11; g = idx & 2047;
    src = qk_w + (size_t)l * 64 * 256; stride = 256; OS_ = 4;
    dstoff = (size_t)l * 16384;
  } else if (idx < 40960) {
    const int i2 = idx - 8192; const int l = i2 >> 13; g = i2 & 8191;
    src = v_w + (size_t)l * 256 * 256; stride = 256; OS_ = 16;
    dstoff = 65536 + (size_t)l * 65536;
  } else if (idx < 73728) {
    const int i2 = idx - 40960; const int l = i2 >> 13; g = i2 & 8191;
    src = t_w + (size_t)l * 256 * 256; stride = 256; OS_ = 16;
    dstoff = 327680 + (size_t)l * 65536;
  } else {
    const int i2 = idx - 73728; const int l = i2 >> 13; g = i2 & 8191;
    src = dc1_w + (size_t)l * 256; stride = 1024; OS_ = 16;
    dstoff = 589824 + (size_t)l * 65536;
  }
  const int kk = g / (OS_ * 64);
  const int rem = g % (OS_ * 64);
  const int osub = rem >> 6;
  const int lane = rem & 63;
  const int o = osub * 16 + (lane & 15);
  const int c = kk * 32 + (lane >> 4) * 8;
  const float* sp = src + (size_t)o * stride + c;
  ushort_t h[8], l8[8];
#pragma unroll
  for (int j = 0; j < 8; ++j) {
    const float v = sp[j];
    h[j] = f2bu(v);
    l8[j] = f2bu(v - us2f(h[j]));
  }
  *(uint4*)(wfh + dstoff + (size_t)g * 8) = *(const uint4*)h;
  *(uint4*)(wfl + dstoff + (size_t)g * 8) = *(const uint4*)l8;
}

// ---------------------------------------------------------------------------
// Fused Q+V conv (split-bf16 MFMA, x read once). Block: 64 n, 4 waves.
// ---------------------------------------------------------------------------
__global__ __launch_bounds__(256) void k_qv(
    const ushort_t* __restrict__ xh, const ushort_t* __restrict__ xl,
    const ushort_t* __restrict__ wqh, const ushort_t* __restrict__ wql,
    const ushort_t* __restrict__ wvh, const ushort_t* __restrict__ wvl,
    const float* __restrict__ qbias, const float* __restrict__ vbias,
    ushort_t* __restrict__ Qh, ushort_t* __restrict__ Ql,
    bf16* __restrict__ Vo) {
  const int t = threadIdx.x;
  const int b = blockIdx.y;
  const int n0 = blockIdx.x * 64;
  const int lane = t & 63, wv = t >> 6;
  const int fr = lane & 15, fq = lane >> 4;
  const ushort_t* xbh = xh + ((size_t)b * kN + n0) * kC;
  const ushort_t* xbl = xl + ((size_t)b * kN + n0) * kC;
  f32x4 accq[4];
  f32x4 accv[4][4];
#pragma unroll
  for (int ns = 0; ns < 4; ++ns) {
    accq[ns] = (f32x4){0.f, 0.f, 0.f, 0.f};
#pragma unroll
    for (int s = 0; s < 4; ++s) accv[s][ns] = (f32x4){0.f, 0.f, 0.f, 0.f};
  }
  for (int kk = 0; kk < 8; ++kk) {
    bf16x8 bh[4], bl[4];
#pragma unroll
    for (int ns = 0; ns < 4; ++ns) {
      const size_t xi = (size_t)(ns * 16 + fr) * kC + kk * 32 + fq * 8;
      bh[ns] = *(const bf16x8*)(xbh + xi);
      bl[ns] = *(const bf16x8*)(xbl + xi);
    }
    {  // Q weights: region OS=4
      const size_t wi = (((size_t)kk * 4 + wv) * 64 + lane) * 8;
      const bf16x8 ah = *(const bf16x8*)(wqh + wi);
      const bf16x8 al = *(const bf16x8*)(wql + wi);
#pragma unroll
      for (int ns = 0; ns < 4; ++ns) {
        accq[ns] = __builtin_amdgcn_mfma_f32_16x16x32_bf16(ah, bh[ns], accq[ns], 0, 0, 0);
        accq[ns] = __builtin_amdgcn_mfma_f32_16x16x32_bf16(ah, bl[ns], accq[ns], 0, 0, 0);
        accq[ns] = __builtin_amdgcn_mfma_f32_16x16x32_bf16(al, bh[ns], accq[ns], 0, 0, 0);
      }
    }
#pragma unroll
    for (int s = 0; s < 4; ++s) {  // V weights: region OS=16
      const size_t wi = (((size_t)kk * 16 + wv * 4 + s) * 64 + lane) * 8;
      const bf16x8 ah = *(const bf16x8*)(wvh + wi);
      const bf16x8 al = *(const bf16x8*)(wvl + wi);
#pragma unroll
      for (int ns = 0; ns < 4; ++ns) {
        accv[s][ns] = __builtin_amdgcn_mfma_f32_16x16x32_bf16(ah, bh[ns], accv[s][ns], 0, 0, 0);
        accv[s][ns] = __builtin_amdgcn_mfma_f32_16x16x32_bf16(ah, bl[ns], accv[s][ns], 0, 0, 0);
        accv[s][ns] = __builtin_amdgcn_mfma_f32_16x16x32_bf16(al, bh[ns], accv[s][ns], 0, 0, 0);
      }
    }
  }
  {
    const int o0 = wv * 16 + fq * 4;
#pragma unroll
    for (int ns = 0; ns < 4; ++ns) {
      const int n = n0 + ns * 16 + fr;
      ushort_t h4[4], l4[4];
#pragma unroll
      for (int r = 0; r < 4; ++r) {
        const float v = accq[ns][r] + qbias[o0 + r];
        h4[r] = f2bu(v);
        l4[r] = f2bu(v - us2f(h4[r]));
      }
      *(ushort4*)(Qh + ((size_t)b * kN + n) * kH + o0) = *(const ushort4*)h4;
      *(ushort4*)(Ql + ((size_t)b * kN + n) * kH + o0) = *(const ushort4*)l4;
    }
  }
#pragma unroll
  for (int s = 0; s < 4; ++s) {
    const int o0 = (wv * 4 + s) * 16 + fq * 4;
#pragma unroll
    for (int ns = 0; ns < 4; ++ns) {
      const int n = n0 + ns * 16 + fr;
#pragma unroll
      for (int r = 0; r < 4; ++r)
        Vo[((size_t)b * kC + o0 + r) * kN + n] = __float2bfloat16(accv[s][ns][r] + vbias[o0 + r]);
    }
  }
}

// ---------------------------------------------------------------------------
// MFMA 1x1 conv (split-bf16). x: [b][n][256] split. Block: 64 n, 4 waves.
// MODE 2: T-conv -> Y split bf16 IN-PLACE over (o1,o2) + BN partials
// MODE 4: fp32 accumulate into hacc [b][o][N] (dc1; hacc pre-zeroed)
// ---------------------------------------------------------------------------
template <int O, int MODE>
__global__ __launch_bounds__(256) void k_conv(
    const ushort_t* __restrict__ xh, const ushort_t* __restrict__ xl,
    const ushort_t* __restrict__ wfh, const ushort_t* __restrict__ wfl,
    const float* __restrict__ bias,
    ushort_t* __restrict__ o1, ushort_t* __restrict__ o2,
    float* __restrict__ of) {
  constexpr int KK = 8;
  constexpr int OS = O / 16;
  constexpr int OSW = OS / 4;
  const int t = threadIdx.x;
  const int b = blockIdx.y;
  const int n0 = blockIdx.x * 64;
  const int lane = t & 63, wv = t >> 6;
  const int fr = lane & 15, fq = lane >> 4;
  const ushort_t* xbh = xh + ((size_t)b * kN + n0) * kC;
  const ushort_t* xbl = xl + ((size_t)b * kN + n0) * kC;
  f32x4 acc[OSW][4];
#pragma unroll
  for (int s = 0; s < OSW; ++s)
#pragma unroll
    for (int ns = 0; ns < 4; ++ns) acc[s][ns] = (f32x4){0.f, 0.f, 0.f, 0.f};
  for (int kk = 0; kk < KK; ++kk) {
    bf16x8 bh[4], bl[4];
#pragma unroll
    for (int ns = 0; ns < 4; ++ns) {
      const size_t xi = (size_t)(ns * 16 + fr) * kC + kk * 32 + fq * 8;
      bh[ns] = *(const bf16x8*)(xbh + xi);
      bl[ns] = *(const bf16x8*)(xbl + xi);
    }
#pragma unroll
    for (int s = 0; s < OSW; ++s) {
      const size_t wi = (((size_t)kk * OS + wv * OSW + s) * 64 + lane) * 8;
      const bf16x8 ah = *(const bf16x8*)(wfh + wi);
      const bf16x8 al = *(const bf16x8*)(wfl + wi);
#pragma unroll
      for (int ns = 0; ns < 4; ++ns) {
        acc[s][ns] = __builtin_amdgcn_mfma_f32_16x16x32_bf16(ah, bh[ns], acc[s][ns], 0, 0, 0);
        acc[s][ns] = __builtin_amdgcn_mfma_f32_16x16x32_bf16(ah, bl[ns], acc[s][ns], 0, 0, 0);
        acc[s][ns] = __builtin_amdgcn_mfma_f32_16x16x32_bf16(al, bh[ns], acc[s][ns], 0, 0, 0);
      }
    }
  }
  if (MODE == 2) {
    const int blk = blockIdx.y * gridDim.x + blockIdx.x;  // 0..511
#pragma unroll
    for (int s = 0; s < OSW; ++s) {
      const int o0 = (wv * OSW + s) * 16 + fq * 4;
      float yv[4][4];  // [ns][r]
#pragma unroll
      for (int ns = 0; ns < 4; ++ns) {
        const int n = n0 + ns * 16 + fr;
        const size_t idx = ((size_t)b * kN + n) * kC + o0;
        ushort_t h4[4], l4[4];
#pragma unroll
        for (int r = 0; r < 4; ++r) {
          const float y = acc[s][ns][r] + bias[o0 + r];
          yv[ns][r] = y;
          h4[r] = f2bu(y);
          l4[r] = f2bu(y - us2f(h4[r]));
        }
        *(ushort4*)(o1 + idx) = *(const ushort4*)h4;
        *(ushort4*)(o2 + idx) = *(const ushort4*)l4;
      }
#pragma unroll
      for (int r = 0; r < 4; ++r) {
        float s1 = yv[0][r] + yv[1][r] + yv[2][r] + yv[3][r];
        float s2 = yv[0][r] * yv[0][r] + yv[1][r] * yv[1][r] +
                   yv[2][r] * yv[2][r] + yv[3][r] * yv[3][r];
#pragma unroll
        for (int mask = 1; mask < 16; mask <<= 1) {
          s1 += __shfl_xor(s1, mask);
          s2 += __shfl_xor(s2, mask);
        }
        if (fr == 0) {
          of[(size_t)(o0 + r) * 512 + blk] = s1;
          of[131072 + (size_t)(o0 + r) * 512 + blk] = s2;
        }
      }
    }
  } else {  // MODE 4: accumulate into hacc
#pragma unroll
    for (int s = 0; s < OSW; ++s) {
      const int o0 = (wv * OSW + s) * 16 + fq * 4;
#pragma unroll
      for (int ns = 0; ns < 4; ++ns) {
        const int n = n0 + ns * 16 + fr;
#pragma unroll
        for (int r = 0; r < 4; ++r) {
          float* pp = of + ((size_t)b * kC + o0 + r) * kN + n;
          *pp = *pp + acc[s][ns][r];
        }
      }
    }
  }
}

// ---------------------------------------------------------------------------
// Reduce BN partials -> fused affine: af[c] = g*rsig, cf[c] = bb - af*mean
// ---------------------------------------------------------------------------
__global__ __launch_bounds__(128) void k_bnred(const float* __restrict__ part,
                                               const float* __restrict__ g,
                                               const float* __restrict__ bb,
                                               float* __restrict__ af,
                                               float* __restrict__ cf) {
  const int c = blockIdx.x, t = threadIdx.x;
  const float4 v1 = *(const float4*)&part[(size_t)c * 512 + t * 4];
  const float4 v2 = *(const float4*)&part[131072 + (size_t)c * 512 + t * 4];
  float s1 = v1.x + v1.y + v1.z + v1.w;
  float s2 = v2.x + v2.y + v2.z + v2.w;
  __shared__ float r1[128], r2[128];
  r1[t] = s1;
  r2[t] = s2;
  __syncthreads();
  for (int k = 64; k > 0; k >>= 1) {
    if (t < k) {
      r1[t] += r1[t + k];
      r2[t] += r2[t + k];
    }
    __syncthreads();
  }
  if (t == 0) {
    const float im = 1.f / (float)(kB * kN);
    const float m = r1[0] * im;
    const float var = r2[0] * im - m * m;
    const float a = g[c] * rsqrtf(var + 1e-5f);
    af[c] = a;
    cf[c] = bb[c] - a * m;
  }
}

// ---------------------------------------------------------------------------
// Elementwise: p += leaky(af[c]*Y + cf[c]); p, Y split bf16 [b][n][c].
// ---------------------------------------------------------------------------
__global__ __launch_bounds__(256) void k_bnapply2(const ushort_t* __restrict__ yh,
                                                  const ushort_t* __restrict__ yl,
                                                  ushort_t* __restrict__ ph,
                                                  ushort_t* __restrict__ pl,
                                                  const float* __restrict__ af,
                                                  const float* __restrict__ cf) {
  const size_t i = ((size_t)blockIdx.x * 256 + threadIdx.x) * 4;
  const int c0 = (int)(i & 255);
  const ushort4 yh4 = *(const ushort4*)(yh + i);
  const ushort4 yl4 = *(const ushort4*)(yl + i);
  const ushort4 ph4 = *(const ushort4*)(ph + i);
  const ushort4 pl4 = *(const ushort4*)(pl + i);
  const float4 a4 = *(const float4*)(af + c0);
  const float4 c4 = *(const float4*)(cf + c0);
  const float y0 = us2f(yh4.x) + us2f(yl4.x);
  const float y1 = us2f(yh4.y) + us2f(yl4.y);
  const float y2 = us2f(yh4.z) + us2f(yl4.z);
  const float y3 = us2f(yh4.w) + us2f(yl4.w);
  float z0 = a4.x * y0 + c4.x; z0 = z0 > 0.f ? z0 : 0.2f * z0;
  float z1 = a4.y * y1 + c4.y; z1 = z1 > 0.f ? z1 : 0.2f * z1;
  float z2 = a4.z * y2 + c4.z; z2 = z2 > 0.f ? z2 : 0.2f * z2;
  float z3 = a4.w * y3 + c4.w; z3 = z3 > 0.f ? z3 : 0.2f * z3;
  const float p0 = us2f(ph4.x) + us2f(pl4.x) + z0;
  const float p1 = us2f(ph4.y) + us2f(pl4.y) + z1;
  const float p2 = us2f(ph4.z) + us2f(pl4.z) + z2;
  const float p3 = us2f(ph4.w) + us2f(pl4.w) + z3;
  ushort4 nh, nl;
  nh.x = f2bu(p0); nl.x = f2bu(p0 - us2f(nh.x));
  nh.y = f2bu(p1); nl.y = f2bu(p1 - us2f(nh.y));
  nh.z = f2bu(p2); nl.z = f2bu(p2 - us2f(nh.z));
  nh.w = f2bu(p3); nl.w = f2bu(p3 - us2f(nh.w));
  *(ushort4*)(ph + i) = nh;
  *(ushort4*)(pl + i) = nl;
}

// ---------------------------------------------------------------------------
// Row softmax stats via split-bf16 MFMA (round-10 version).
// ---------------------------------------------------------------------------
__global__ __launch_bounds__(256) void k_rowstats(const ushort_t* __restrict__ Qhi,
                                                  const ushort_t* __restrict__ Qlo,
                                                  float* __restrict__ rmx,
                                                  float* __restrict__ rsn) {
  __shared__ __align__(16) ushort_t Bh[2][64][72];
  __shared__ __align__(16) ushort_t Bl[2][64][72];
  const int b = blockIdx.y, t = threadIdx.x;
  const int r0 = blockIdx.x * 64;
  const int lane = t & 63, w = t >> 6;
  const int fr = lane & 15, fq = lane >> 4;
  const size_t qbase = (size_t)b * kN * kH;
  bf16x8 ah0, ah1, al0, al1;
  {
    const ushort_t* qh = Qhi + qbase + (size_t)(r0 + w * 16 + fr) * kH;
    const ushort_t* ql = Qlo + qbase + (size_t)(r0 + w * 16 + fr) * kH;
    ah0 = *(const bf16x8*)(qh + fq * 8);
    ah1 = *(const bf16x8*)(qh + 32 + fq * 8);
    al0 = *(const bf16x8*)(ql + fq * 8);
    al1 = *(const bf16x8*)(ql + 32 + fq * 8);
  }
  float mx[4] = {-3.0e38f, -3.0e38f, -3.0e38f, -3.0e38f};
  float sm[4] = {0.f, 0.f, 0.f, 0.f};
  const int srow = t >> 2, scol = (t & 3) * 16;
  {
    const ushort_t* qh = Qhi + qbase + (size_t)srow * kH + scol;
    const ushort_t* ql = Qlo + qbase + (size_t)srow * kH + scol;
    *(uint4*)&Bh[0][srow][scol] = *(const uint4*)qh;
    *(uint4*)&Bh[0][srow][scol + 8] = *(const uint4*)(qh + 8);
    *(uint4*)&Bl[0][srow][scol] = *(const uint4*)ql;
    *(uint4*)&Bl[0][srow][scol + 8] = *(const uint4*)(ql + 8);
  }
  __syncthreads();
  int cur = 0;
  for (int m0 = 0; m0 < kN; m0 += 64) {
    uint4 rh0, rh1, rl0, rl1;
    const bool pf = (m0 + 64 < kN);
    if (pf) {
      const ushort_t* qh = Qhi + qbase + (size_t)(m0 + 64 + srow) * kH + scol;
      const ushort_t* ql = Qlo + qbase + (size_t)(m0 + 64 + srow) * kH + scol;
      rh0 = *(const uint4*)qh;
      rh1 = *(const uint4*)(qh + 8);
      rl0 = *(const uint4*)ql;
      rl1 = *(const uint4*)(ql + 8);
    }
    float ev[4][4];
#pragma unroll
    for (int cs = 0; cs < 4; ++cs) {
      const bf16x8 bh0 = *(const bf16x8*)&Bh[cur][cs * 16 + fr][fq * 8];
      const bf16x8 bh1 = *(const bf16x8*)&Bh[cur][cs * 16 + fr][32 + fq * 8];
      const bf16x8 bl0 = *(const bf16x8*)&Bl[cur][cs * 16 + fr][fq * 8];
      const bf16x8 bl1 = *(const bf16x8*)&Bl[cur][cs * 16 + fr][32 + fq * 8];
      f32x4 e = {0.f, 0.f, 0.f, 0.f};
      e = __builtin_amdgcn_mfma_f32_16x16x32_bf16(ah0, bh0, e, 0, 0, 0);
      e = __builtin_amdgcn_mfma_f32_16x16x32_bf16(ah1, bh1, e, 0, 0, 0);
      e = __builtin_amdgcn_mfma_f32_16x16x32_bf16(ah0, bl0, e, 0, 0, 0);
      e = __builtin_amdgcn_mfma_f32_16x16x32_bf16(ah1, bl1, e, 0, 0, 0);
      e = __builtin_amdgcn_mfma_f32_16x16x32_bf16(al0, bh0, e, 0, 0, 0);
      e = __builtin_amdgcn_mfma_f32_16x16x32_bf16(al1, bh1, e, 0, 0, 0);
      ev[cs][0] = e[0]; ev[cs][1] = e[1]; ev[cs][2] = e[2]; ev[cs][3] = e[3];
    }
#pragma unroll
    for (int r = 0; r < 4; ++r) {
      const float tmax = fmaxf(fmaxf(ev[0][r], ev[1][r]), fmaxf(ev[2][r], ev[3][r]));
      const float nm = fmaxf(mx[r], tmax);
      sm[r] = sm[r] * __expf(mx[r] - nm) + __expf(ev[0][r] - nm) + __expf(ev[1][r] - nm) +
              __expf(ev[2][r] - nm) + __expf(ev[3][r] - nm);
      mx[r] = nm;
    }
    if (pf) {
      *(uint4*)&Bh[cur ^ 1][srow][scol] = rh0;
      *(uint4*)&Bh[cur ^ 1][srow][scol + 8] = rh1;
      *(uint4*)&Bl[cur ^ 1][srow][scol] = rl0;
      *(uint4*)&Bl[cur ^ 1][srow][scol + 8] = rl1;
    }
    __syncthreads();
    cur ^= 1;
  }
#pragma unroll
  for (int mask = 1; mask < 16; mask <<= 1) {
#pragma unroll
    for (int r = 0; r < 4; ++r) {
      const float om = __shfl_xor(mx[r], mask);
      const float os = __shfl_xor(sm[r], mask);
      const float nm = fmaxf(mx[r], om);
      sm[r] = sm[r] * __expf(mx[r] - nm) + os * __expf(om - nm);
      mx[r] = nm;
    }
  }
  if (fr == 0) {
#pragma unroll
    for (int r = 0; r < 4; ++r) {
      const int row = r0 + w * 16 + fq * 4 + r;
      rmx[(size_t)b * kN + row] = mx[r];
      rsn[(size_t)b * kN + row] = 1.f / sm[r];
    }
  }
}

// ---------------------------------------------------------------------------
// Column pass, MT=64 (round-10 version — measured floor ~124 us).
// ---------------------------------------------------------------------------
__global__ __launch_bounds__(256) void k_colpass(const ushort_t* __restrict__ Qhi,
                                                 const ushort_t* __restrict__ Qlo,
                                                 const bf16* __restrict__ V,
                                                 const float* __restrict__ rmx,
                                                 const float* __restrict__ rsn,
                                                 const ushort_t* __restrict__ psh,
                                                 const ushort_t* __restrict__ psl,
                                                 ushort_t* __restrict__ ush,
                                                 ushort_t* __restrict__ usl) {
  constexpr int MT = 64, NT = 32;
  __shared__ __align__(16) ushort_t Anh[2][NT][72];
  __shared__ __align__(16) ushort_t Anl[2][NT][72];
  __shared__ __align__(16) ushort_t Vs[2][kC][40];
  __shared__ __align__(16) ushort_t Pl[MT][40];
  __shared__ float CsI[MT];
  const int t = threadIdx.x;
  const int b = blockIdx.y;
  const int mBase = blockIdx.x * MT;
  const size_t qbase = (size_t)b * kN * kH;
  const ushort_t* Vb_ = (const ushort_t*)V + (size_t)b * kC * kN;
  const int lane = t & 63, wv = t >> 6;
  const int fr = lane & 15, fq = lane >> 4;
  bf16x8 bmh0, bmh1, bml0, bml1;
  {
    const ushort_t* qh = Qhi + qbase + (size_t)(mBase + wv * 16 + fr) * kH;
    const ushort_t* ql = Qlo + qbase + (size_t)(mBase + wv * 16 + fr) * kH;
    bmh0 = *(const bf16x8*)(qh + fq * 8);
    bmh1 = *(const bf16x8*)(qh + 32 + fq * 8);
    bml0 = *(const bf16x8*)(ql + fq * 8);
    bml1 = *(const bf16x8*)(ql + 32 + fq * 8);
  }
  f32x4 acc[4][4];
#pragma unroll
  for (int i = 0; i < 4; ++i)
#pragma unroll
    for (int j = 0; j < 4; ++j) acc[i][j] = (f32x4){0.f, 0.f, 0.f, 0.f};
  float csloc = 0.f;
  const int arow = t >> 3, acol = (t & 7) * 8;
  const int vc = t >> 2, vq = t & 3;
  {
    *(uint4*)&Anh[0][arow][acol] = *(const uint4*)(Qhi + qbase + (size_t)arow * kH + acol);
    *(uint4*)&Anl[0][arow][acol] = *(const uint4*)(Qlo + qbase + (size_t)arow * kH + acol);
#pragma unroll
    for (int it = 0; it < 4; ++it) {
      const int c = it * 64 + vc;
      *(uint4*)&Vs[0][c][vq * 8] = *(const uint4*)(Vb_ + (size_t)c * kN + vq * 8);
    }
  }
  __syncthreads();
  int cur = 0;
  for (int n0 = 0; n0 < kN; n0 += NT) {
    uint4 rAh, rAl, rV0, rV1, rV2, rV3;
    const bool pf = (n0 + NT < kN);
    if (pf) {
      const int nn = n0 + NT;
      rAh = *(const uint4*)(Qhi + qbase + (size_t)(nn + arow) * kH + acol);
      rAl = *(const uint4*)(Qlo + qbase + (size_t)(nn + arow) * kH + acol);
      rV0 = *(const uint4*)(Vb_ + (size_t)(0 * 64 + vc) * kN + nn + vq * 8);
      rV1 = *(const uint4*)(Vb_ + (size_t)(1 * 64 + vc) * kN + nn + vq * 8);
      rV2 = *(const uint4*)(Vb_ + (size_t)(2 * 64 + vc) * kN + nn + vq * 8);
      rV3 = *(const uint4*)(Vb_ + (size_t)(3 * 64 + vc) * kN + nn + vq * 8);
    }
    const float4 rm0 = *(const float4*)&rmx[(size_t)b * kN + n0 + fq * 4];
    const float4 rm1 = *(const float4*)&rmx[(size_t)b * kN + n0 + 16 + fq * 4];
    const float4 rs0 = *(const float4*)&rsn[(size_t)b * kN + n0 + fq * 4];
    const float4 rs1 = *(const float4*)&rsn[(size_t)b * kN + n0 + 16 + fq * 4];
#pragma unroll
    for (int ns = 0; ns < 2; ++ns) {
      const bf16x8 ah0 = *(const bf16x8*)&Anh[cur][ns * 16 + fr][fq * 8];
      const bf16x8 ah1 = *(const bf16x8*)&Anh[cur][ns * 16 + fr][32 + fq * 8];
      const bf16x8 al0 = *(const bf16x8*)&Anl[cur][ns * 16 + fr][fq * 8];
      const bf16x8 al1 = *(const bf16x8*)&Anl[cur][ns * 16 + fr][32 + fq * 8];
      f32x4 e = {0.f, 0.f, 0.f, 0.f};
      e = __builtin_amdgcn_mfma_f32_16x16x32_bf16(ah0, bmh0, e, 0, 0, 0);
      e = __builtin_amdgcn_mfma_f32_16x16x32_bf16(ah1, bmh1, e, 0, 0, 0);
      e = __builtin_amdgcn_mfma_f32_16x16x32_bf16(ah0, bml0, e, 0, 0, 0);
      e = __builtin_amdgcn_mfma_f32_16x16x32_bf16(ah1, bml1, e, 0, 0, 0);
      e = __builtin_amdgcn_mfma_f32_16x16x32_bf16(al0, bmh0, e, 0, 0, 0);
      e = __builtin_amdgcn_mfma_f32_16x16x32_bf16(al1, bmh1, e, 0, 0, 0);
      const float4 rm = ns ? rm1 : rm0;
      const float4 rs = ns ? rs1 : rs0;
      ushort_t p4[4];
      {
        const float p0 = __expf(e[0] - rm.x) * rs.x;
        const float p1 = __expf(e[1] - rm.y) * rs.y;
        const float p2 = __expf(e[2] - rm.z) * rs.z;
        const float p3 = __expf(e[3] - rm.w) * rs.w;
        p4[0] = f2bu(p0); p4[1] = f2bu(p1); p4[2] = f2bu(p2); p4[3] = f2bu(p3);
        csloc += p0 + p1 + p2 + p3;
      }
      *(ushort4*)&Pl[wv * 16 + fr][ns * 16 + fq * 4] = *(const ushort4*)p4;
    }
    __syncthreads();
    bf16x8 am[4], bv[4];
#pragma unroll
    for (int ms = 0; ms < 4; ++ms)
      am[ms] = *(const bf16x8*)&Pl[ms * 16 + fr][fq * 8];
#pragma unroll
    for (int cs = 0; cs < 4; ++cs)
      bv[cs] = *(const bf16x8*)&Vs[cur][wv * 64 + cs * 16 + fr][fq * 8];
#pragma unroll
    for (int ms = 0; ms < 4; ++ms)
#pragma unroll
      for (int cs = 0; cs < 4; ++cs)
        acc[ms][cs] = __builtin_amdgcn_mfma_f32_16x16x32_bf16(am[ms], bv[cs], acc[ms][cs], 0, 0, 0);
    if (pf) {
      *(uint4*)&Anh[cur ^ 1][arow][acol] = rAh;
      *(uint4*)&Anl[cur ^ 1][arow][acol] = rAl;
      *(uint4*)&Vs[cur ^ 1][0 * 64 + vc][vq * 8] = rV0;
      *(uint4*)&Vs[cur ^ 1][1 * 64 + vc][vq * 8] = rV1;
      *(uint4*)&Vs[cur ^ 1][2 * 64 + vc][vq * 8] = rV2;
      *(uint4*)&Vs[cur ^ 1][3 * 64 + vc][vq * 8] = rV3;
    }
    __syncthreads();
    cur ^= 1;
  }
  csloc += __shfl_xor(csloc, 16);
  csloc += __shfl_xor(csloc, 32);
  if (fq == 0) CsI[wv * 16 + fr] = 1.f / (1e-9f + csloc);
  __syncthreads();
#pragma unroll
  for (int ms = 0; ms < 4; ++ms) {
#pragma unroll
    for (int r = 0; r < 4; ++r) {
      const int ml = ms * 16 + fq * 4 + r;
      const float inv = CsI[ml];
      const size_t row = ((size_t)b * kN + mBase + ml) * kC;
#pragma unroll
      for (int cs = 0; cs < 4; ++cs) {
        const int c = wv * 64 + cs * 16 + fr;
        const float xv = us2f(psh[row + c]) + us2f(psl[row + c]);
        const float u = xv - acc[ms][cs][r] * inv;
        const ushort_t h = f2bu(u);
        ush[row + c] = h;
        usl[row + c] = f2bu(u - us2f(h));
      }
    }
  }
}

// ---------------------------------------------------------------------------
// BN stats per channel over (B, N), fp32 [b][nch][N] input, biased var.
// ---------------------------------------------------------------------------
__global__ __launch_bounds__(256) void k_bnstats(const float* __restrict__ y, int nch,
                                                 float* __restrict__ mean,
                                                 float* __restrict__ rsig) {
  const int c = blockIdx.x, t = threadIdx.x;
  float s = 0.f, s2 = 0.f;
  for (int b = 0; b < kB; ++b) {
    const float* p = y + ((size_t)b * nch + c) * kN;
    for (int n = t; n < kN; n += 256) {
      const float v = p[n];
      s += v;
      s2 += v * v;
    }
  }
  __shared__ float r1[256], r2[256];
  r1[t] = s;
  r2[t] = s2;
  __syncthreads();
  for (int k = 128; k > 0; k >>= 1) {
    if (t < k) {
      r1[t] += r1[t + k];
      r2[t] += r2[t + k];
    }
    __syncthreads();
  }
  if (t == 0) {
    const float im = 1.f / (float)(kB * kN);
    const float m = r1[0] * im;
    const float var = r2[0] * im - m * m;
    mean[c] = m;
    rsig[c] = rsqrtf(var + 1e-5f);
  }
}

// ---------------------------------------------------------------------------
// dc2: tpre[b,j,n] = dc2_b[j] + sum_c dc2_w[j,c] * leaky(bn(h[b,c,n]))
// ---------------------------------------------------------------------------
__global__ __launch_bounds__(256) void k_dc2(const float* __restrict__ h,
                                             const float* __restrict__ mean,
                                             const float* __restrict__ rsig,
                                             const float* __restrict__ g,
                                             const float* __restrict__ bb,
                                             const float* __restrict__ w,
                                             const float* __restrict__ d2b,
                                             float* __restrict__ tpre) {
  __shared__ float wS[3][kC];
  __shared__ float aS[kC], cS[kC];
  const int t = threadIdx.x, b = blockIdx.y;
  const int n = blockIdx.x * 256 + t;
  {
    const float a = g[t] * rsig[t];
    aS[t] = a;
    cS[t] = bb[t] - a * mean[t];
    wS[0][t] = w[t];
    wS[1][t] = w[kC + t];
    wS[2][t] = w[2 * kC + t];
  }
  __syncthreads();
  float a0 = d2b[0], a1 = d2b[1], a2 = d2b[2];
  const float* hb = h + (size_t)b * kC * kN + n;
  for (int c = 0; c < kC; ++c) {
    float z = hb[(size_t)c * kN] * aS[c] + cS[c];
    z = z > 0.f ? z : 0.2f * z;
    a0 += wS[0][c] * z;
    a1 += wS[1][c] * z;
    a2 += wS[2][c] * z;
  }
  tpre[((size_t)b * 3 + 0) * kN + n] = a0;
  tpre[((size_t)b * 3 + 1) * kN + n] = a1;
  tpre[((size_t)b * 3 + 2) * kN + n] = a2;
}

// ---------------------------------------------------------------------------
// Final: out[b,n,j] = tanh(g[j]*(tpre[b,j,n]-mean[j])*rsig[j] + b[j])
// ---------------------------------------------------------------------------
__global__ __launch_bounds__(256) void k_final(const float* __restrict__ tpre,
                                               const float* __restrict__ mean,
                                               const float* __restrict__ rsig,
                                               const float* __restrict__ g,
                                               const float* __restrict__ bb,
                                               float* __restrict__ out) {
  const int i = blockIdx.x * 256 + threadIdx.x;  // over B*N
  const int n = i & (kN - 1), b = i >> 11;
#pragma unroll
  for (int j = 0; j < 3; ++j) {
    const float v = tpre[((size_t)b * 3 + j) * kN + n];
    const float z = g[j] * (v - mean[j]) * rsig[j] + bb[j];
    out[(size_t)i * 3 + j] = tanhf(z);
  }
}

// ---------------------------------------------------------------------------
extern "C" void kernel_launch(void* const* d_in, const int* in_sizes, int n_in,
                              void* d_out, int out_size, void* d_ws, size_t ws_size,
                              hipStream_t stream) {
  const float* feature  = (const float*)d_in[0];
  const float* prior    = (const float*)d_in[1];
  const float* mlp_w    = (const float*)d_in[2];
  const float* mlp_b    = (const float*)d_in[3];
  const float* qk_w     = (const float*)d_in[4];
  const float* qk_b     = (const float*)d_in[5];
  const float* v_w      = (const float*)d_in[6];
  const float* v_b      = (const float*)d_in[7];
  const float* t_w      = (const float*)d_in[8];
  const float* t_b      = (const float*)d_in[9];
  const float* bn_g     = (const float*)d_in[10];
  const float* bn_b     = (const float*)d_in[11];
  const float* dc1_w    = (const float*)d_in[12];
  const float* dc1_bn_g = (const float*)d_in[13];
  const float* dc1_bn_b = (const float*)d_in[14];
  const float* dc2_w    = (const float*)d_in[15];
  const float* dc2_b    = (const float*)d_in[16];
  const float* dc2_bn_g = (const float*)d_in[17];
  const float* dc2_bn_b = (const float*)d_in[18];
  float* out = (float*)d_out;

  // Workspace carve. Total ~125 MiB.
  char* base = (char*)d_ws;
  size_t off = 0;
  auto carve = [&](size_t bytes) {
    char* p = base + off;
    off += (bytes + 255) & ~(size_t)255;
    return p;
  };
  const size_t ne = (size_t)kB * kN * kC;                 // 8,388,608
  ushort_t* psh  = (ushort_t*)carve(ne * 2);              // p hi   16 MiB
  ushort_t* psl  = (ushort_t*)carve(ne * 2);              // p lo   16 MiB
  ushort_t* ush  = (ushort_t*)carve(ne * 2);              // u/Y hi 16 MiB
  ushort_t* usl  = (ushort_t*)carve(ne * 2);              // u/Y lo 16 MiB
  float*    hacc = (float*)carve(ne * 4);                 // dc1    32 MiB
  ushort_t* Qhi  = (ushort_t*)carve((size_t)kB * kN * kH * 2);  // 4 MiB
  ushort_t* Qlo  = (ushort_t*)carve((size_t)kB * kN * kH * 2);  // 4 MiB
  bf16*     Vb   = (bf16*)carve(ne * 2);                  // V      16 MiB
  ushort_t* wfh  = (ushort_t*)carve((size_t)851968 * 2);  // 1.63 MiB
  ushort_t* wfl  = (ushort_t*)carve((size_t)851968 * 2);  // 1.63 MiB
  float*    part = (float*)carve((size_t)2 * 131072 * 4); // 1 MiB
  float*    rmx  = (float*)carve((size_t)kB * kN * 4);
  float*    rsn  = (float*)carve((size_t)kB * kN * 4);
  float*    fb   = (float*)carve((size_t)kB * kC * 4);
  float*    bnm  = (float*)carve(kC * 4);
  float*    bnr  = (float*)carve(kC * 4);
  float*    tpre = (float*)carve((size_t)kB * 3 * kN * 4);

  hipMemsetAsync(hacc, 0, ne * 4, stream);  // MODE-4 accumulator init
  k_wsplit<<<416, 256, 0, stream>>>(qk_w, v_w, t_w, dc1_w, wfh, wfl);
  k_fb<<<kB * kC, 256, 0, stream>>>(feature, mlp_w, mlp_b, fb);
  k_p0<<<(int)(ne / 256), 256, 0, stream>>>(prior, mlp_w, fb, psh, psl);

  const dim3 gC(kN / 64, kB);
  for (int l = 0; l < 4; ++l) {
    const size_t qk_off  = (size_t)l * 16384;
    const size_t v_off   = 65536 + (size_t)l * 65536;
    const size_t t_off   = 327680 + (size_t)l * 65536;
    const size_t dc1_off = 589824 + (size_t)l * 65536;
    k_qv<<<gC, 256, 0, stream>>>(psh, psl, wfh + qk_off, wfl + qk_off,
                                 wfh + v_off, wfl + v_off,
                                 qk_b + l * kH, v_b + l * kC, Qhi, Qlo, Vb);
    k_rowstats<<<gC, 256, 0, stream>>>(Qhi, Qlo, rmx, rsn);
    k_colpass<<<gC, 256, 0, stream>>>(Qhi, Qlo, Vb, rmx, rsn, psh, psl, ush, usl);
    // T-conv once: Y split bf16 in-place over u + BN partials
    k_conv<256, 2><<<gC, 256, 0, stream>>>(ush, usl, wfh + t_off, wfl + t_off,
                                           t_b + l * kC, ush, usl, part);
    k_bnred<<<kC, 128, 0, stream>>>(part, bn_g + l * kC, bn_b + l * kC, bnm, bnr);
    // elementwise: p += leaky(a*Y + c)
    k_bnapply2<<<(int)(ne / 4 / 256), 256, 0, stream>>>(ush, usl, psh, psl, bnm, bnr);
    // dc1 accumulate
    k_conv<256, 4><<<gC, 256, 0, stream>>>(psh, psl, wfh + dc1_off, wfl + dc1_off,
                                           nullptr, nullptr, nullptr, hacc);
  }

  k_bnstats<<<kC, 256, 0, stream>>>(hacc, kC, bnm, bnr);
  k_dc2<<<dim3(kN / 256, kB), 256, 0, stream>>>(hacc, bnm, bnr, dc1_bn_g, dc1_bn_b,
                                                dc2_w, dc2_b, tpre);
  k_bnstats<<<3, 256, 0, stream>>>(tpre, 3, bnm, bnr);
  k_final<<<(kB * kN) / 256, 256, 0, stream>>>(tpre, bnm, bnr, dc2_bn_g, dc2_bn_b, out);
}

// Round 14
// 1182.659 us; speedup vs baseline: 1.3626x; 1.0433x over previous
//
#include <hip/hip_runtime.h>
#include <hip/hip_bf16.h>

typedef __hip_bfloat16 bf16;
typedef unsigned short ushort_t;

// Problem constants
constexpr int kB = 16;    // batch
constexpr int kN = 2048;  // points
constexpr int kF = 1024;  // feat dims
constexpr int kC = 256;   // channels
constexpr int kH = 64;    // head dim

using f32x4 = __attribute__((ext_vector_type(4))) float;
using bf16x8 = __attribute__((ext_vector_type(8))) short;  // 8 bf16 (4 VGPRs)

__device__ __forceinline__ float us2f(unsigned short u) {
  union { unsigned int i; float f; } w;
  w.i = ((unsigned int)u) << 16;
  return w.f;
}
__device__ __forceinline__ unsigned short f2bu(float f) {
  union { bf16 h; unsigned short s; } u;
  u.h = __float2bfloat16(f);
  return u.s;
}

// ---------------------------------------------------------------------------
// fb[b,c] = mlp_b[c] + sum_f mlp_w[c,f] * feature[b,f]
// ---------------------------------------------------------------------------
__global__ __launch_bounds__(256) void k_fb(const float* __restrict__ feat,
                                            const float* __restrict__ mlp_w,
                                            const float* __restrict__ mlp_b,
                                            float* __restrict__ fb) {
  const int b = blockIdx.x >> 8;
  const int c = blockIdx.x & 255;
  const int t = threadIdx.x;
  const float* wr = mlp_w + (size_t)c * (kF + 3);
  const float* fr = feat + (size_t)b * kF;
  float s = 0.f;
  for (int f = t; f < kF; f += 256) s += wr[f] * fr[f];
  __shared__ float red[256];
  red[t] = s;
  __syncthreads();
  for (int k = 128; k > 0; k >>= 1) {
    if (t < k) red[t] += red[t + k];
    __syncthreads();
  }
  if (t == 0) fb[blockIdx.x] = red[0] + mlp_b[c];
}

// ---------------------------------------------------------------------------
// p[b,n,c] = fb[b,c] + sum_{j<3} mlp_w[c,1024+j] * prior[b,j,n]  (split bf16)
// ---------------------------------------------------------------------------
__global__ __launch_bounds__(256) void k_p0(const float* __restrict__ prior,
                                            const float* __restrict__ mlp_w,
                                            const float* __restrict__ fb,
                                            ushort_t* __restrict__ psh,
                                            ushort_t* __restrict__ psl) {
  const size_t i = (size_t)blockIdx.x * 256 + threadIdx.x;  // over B*N*C
  const int c = (int)(i & 255);
  const int n = (int)((i >> 8) & 2047);
  const int b = (int)(i >> 19);
  const float* wr = mlp_w + (size_t)c * (kF + 3) + kF;
  const float* pr = prior + (size_t)b * 3 * kN + n;
  const float v = fb[b * kC + c] + wr[0] * pr[0] + wr[1] * pr[kN] + wr[2] * pr[2 * kN];
  const ushort_t h = f2bu(v);
  psh[i] = h;
  psl[i] = f2bu(v - us2f(h));
}

// ---------------------------------------------------------------------------
// Pre-split weights into MFMA A-fragment order (hi/lo bf16).
// Regions (group = 8 elems): qk 4x2048 | v 4x8192 | t 4x8192 | dc1 4x8192
// ---------------------------------------------------------------------------
__global__ __launch_bounds__(256) void k_wsplit(const float* __restrict__ qk_w,
                                                const float* __restrict__ v_w,
                                                const float* __restrict__ t_w,
                                                const float* __restrict__ dc1_w,
                                                ushort_t* __restrict__ wfh,
                                                ushort_t* __restrict__ wfl) {
  const int idx = blockIdx.x * 256 + threadIdx.x;  // group index
  const float* src;
  int stride, OS_;
  size_t dstoff;
  int g;
  if (idx < 8192) {
    const int l = idx >> 11; g = idx & 2047;
    src = qk_w + (size_t)l * 64 * 256; stride = 256; OS_ = 4;
    dstoff = (size_t)l * 16384;
  } else if (idx < 40960) {
    const int i2 = idx - 8192; const int l = i2 >> 13; g = i2 & 8191;
    src = v_w + (size_t)l * 256 * 256; stride = 256; OS_ = 16;
    dstoff = 65536 + (size_t)l * 65536;
  } else if (idx < 73728) {
    const int i2 = idx - 40960; const int l = i2 >> 13; g = i2 & 8191;
    src = t_w + (size_t)l * 256 * 256; stride = 256; OS_ = 16;
    dstoff = 327680 + (size_t)l * 65536;
  } else {
    const int i2 = idx - 73728; const int l = i2 >> 13; g = i2 & 8191;
    src = dc1_w + (size_t)l * 256; stride = 1024; OS_ = 16;
    dstoff = 589824 + (size_t)l * 65536;
  }
  const int kk = g / (OS_ * 64);
  const int rem = g % (OS_ * 64);
  const int osub = rem >> 6;
  const int lane = rem & 63;
  const int o = osub * 16 + (lane & 15);
  const int c = kk * 32 + (lane >> 4) * 8;
  const float* sp = src + (size_t)o * stride + c;
  ushort_t h[8], l8[8];
#pragma unroll
  for (int j = 0; j < 8; ++j) {
    const float v = sp[j];
    h[j] = f2bu(v);
    l8[j] = f2bu(v - us2f(h[j]));
  }
  *(uint4*)(wfh + dstoff + (size_t)g * 8) = *(const uint4*)h;
  *(uint4*)(wfl + dstoff + (size_t)g * 8) = *(const uint4*)l8;
}

// ---------------------------------------------------------------------------
// Fused Q+V conv for layer 0 (split-bf16 MFMA). Block: 64 n, 4 waves.
// ---------------------------------------------------------------------------
__global__ __launch_bounds__(256) void k_qv(
    const ushort_t* __restrict__ xh, const ushort_t* __restrict__ xl,
    const ushort_t* __restrict__ wqh, const ushort_t* __restrict__ wql,
    const ushort_t* __restrict__ wvh, const ushort_t* __restrict__ wvl,
    const float* __restrict__ qbias, const float* __restrict__ vbias,
    ushort_t* __restrict__ Qh, ushort_t* __restrict__ Ql,
    bf16* __restrict__ Vo) {
  const int t = threadIdx.x;
  const int b = blockIdx.y;
  const int n0 = blockIdx.x * 64;
  const int lane = t & 63, wv = t >> 6;
  const int fr = lane & 15, fq = lane >> 4;
  const ushort_t* xbh = xh + ((size_t)b * kN + n0) * kC;
  const ushort_t* xbl = xl + ((size_t)b * kN + n0) * kC;
  f32x4 accq[4];
  f32x4 accv[4][4];
#pragma unroll
  for (int ns = 0; ns < 4; ++ns) {
    accq[ns] = (f32x4){0.f, 0.f, 0.f, 0.f};
#pragma unroll
    for (int s = 0; s < 4; ++s) accv[s][ns] = (f32x4){0.f, 0.f, 0.f, 0.f};
  }
  for (int kk = 0; kk < 8; ++kk) {
    bf16x8 bh[4], bl[4];
#pragma unroll
    for (int ns = 0; ns < 4; ++ns) {
      const size_t xi = (size_t)(ns * 16 + fr) * kC + kk * 32 + fq * 8;
      bh[ns] = *(const bf16x8*)(xbh + xi);
      bl[ns] = *(const bf16x8*)(xbl + xi);
    }
    {  // Q weights: region OS=4
      const size_t wi = (((size_t)kk * 4 + wv) * 64 + lane) * 8;
      const bf16x8 ah = *(const bf16x8*)(wqh + wi);
      const bf16x8 al = *(const bf16x8*)(wql + wi);
#pragma unroll
      for (int ns = 0; ns < 4; ++ns) {
        accq[ns] = __builtin_amdgcn_mfma_f32_16x16x32_bf16(ah, bh[ns], accq[ns], 0, 0, 0);
        accq[ns] = __builtin_amdgcn_mfma_f32_16x16x32_bf16(ah, bl[ns], accq[ns], 0, 0, 0);
        accq[ns] = __builtin_amdgcn_mfma_f32_16x16x32_bf16(al, bh[ns], accq[ns], 0, 0, 0);
      }
    }
#pragma unroll
    for (int s = 0; s < 4; ++s) {  // V weights: region OS=16
      const size_t wi = (((size_t)kk * 16 + wv * 4 + s) * 64 + lane) * 8;
      const bf16x8 ah = *(const bf16x8*)(wvh + wi);
      const bf16x8 al = *(const bf16x8*)(wvl + wi);
#pragma unroll
      for (int ns = 0; ns < 4; ++ns) {
        accv[s][ns] = __builtin_amdgcn_mfma_f32_16x16x32_bf16(ah, bh[ns], accv[s][ns], 0, 0, 0);
        accv[s][ns] = __builtin_amdgcn_mfma_f32_16x16x32_bf16(ah, bl[ns], accv[s][ns], 0, 0, 0);
        accv[s][ns] = __builtin_amdgcn_mfma_f32_16x16x32_bf16(al, bh[ns], accv[s][ns], 0, 0, 0);
      }
    }
  }
  {
    const int o0 = wv * 16 + fq * 4;
#pragma unroll
    for (int ns = 0; ns < 4; ++ns) {
      const int n = n0 + ns * 16 + fr;
      ushort_t h4[4], l4[4];
#pragma unroll
      for (int r = 0; r < 4; ++r) {
        const float v = accq[ns][r] + qbias[o0 + r];
        h4[r] = f2bu(v);
        l4[r] = f2bu(v - us2f(h4[r]));
      }
      *(ushort4*)(Qh + ((size_t)b * kN + n) * kH + o0) = *(const ushort4*)h4;
      *(ushort4*)(Ql + ((size_t)b * kN + n) * kH + o0) = *(const ushort4*)l4;
    }
  }
#pragma unroll
  for (int s = 0; s < 4; ++s) {
    const int o0 = (wv * 4 + s) * 16 + fq * 4;
#pragma unroll
    for (int ns = 0; ns < 4; ++ns) {
      const int n = n0 + ns * 16 + fr;
#pragma unroll
      for (int r = 0; r < 4; ++r)
        Vo[((size_t)b * kC + o0 + r) * kN + n] = __float2bfloat16(accv[s][ns][r] + vbias[o0 + r]);
    }
  }
}

// ---------------------------------------------------------------------------
// Layer-boundary fusion: p' = p + leaky(af*Y + cf); per-kk all waves read
// p,Y and compute p' in regs, then __syncthreads, THEN wave 0 stores p'
// (fixes the r13 read/write race). MFMA with p'-fragments: Q_{l+1}, V_{l+1}
// (HASQV) and dc1 slice l.
// ---------------------------------------------------------------------------
template <int HASQV>
__global__ __launch_bounds__(256, 2) void k_fuse(
    const ushort_t* __restrict__ yh, const ushort_t* __restrict__ yl,
    ushort_t* __restrict__ ph, ushort_t* __restrict__ pl,
    const float* __restrict__ af, const float* __restrict__ cf,
    const ushort_t* __restrict__ wqh, const ushort_t* __restrict__ wql,
    const ushort_t* __restrict__ wvh, const ushort_t* __restrict__ wvl,
    const ushort_t* __restrict__ wdh, const ushort_t* __restrict__ wdl,
    const float* __restrict__ qbias, const float* __restrict__ vbias,
    ushort_t* __restrict__ Qh, ushort_t* __restrict__ Ql,
    bf16* __restrict__ Vo, float* __restrict__ hacc) {
  const int t = threadIdx.x;
  const int b = blockIdx.y;
  const int n0 = blockIdx.x * 64;
  const int lane = t & 63, wv = t >> 6;
  const int fr = lane & 15, fq = lane >> 4;
  const size_t rowbase = ((size_t)b * kN + n0) * kC;
  f32x4 accq[4];
  f32x4 accv[4][4];
  f32x4 accd[4][4];
#pragma unroll
  for (int ns = 0; ns < 4; ++ns) {
    accq[ns] = (f32x4){0.f, 0.f, 0.f, 0.f};
#pragma unroll
    for (int s = 0; s < 4; ++s) {
      accv[s][ns] = (f32x4){0.f, 0.f, 0.f, 0.f};
      accd[s][ns] = (f32x4){0.f, 0.f, 0.f, 0.f};
    }
  }
  for (int kk = 0; kk < 8; ++kk) {
    const int cbase = kk * 32 + fq * 8;
    const float4 a4a = *(const float4*)(af + cbase);
    const float4 a4b = *(const float4*)(af + cbase + 4);
    const float4 c4a = *(const float4*)(cf + cbase);
    const float4 c4b = *(const float4*)(cf + cbase + 4);
    const float av[8] = {a4a.x, a4a.y, a4a.z, a4a.w, a4b.x, a4b.y, a4b.z, a4b.w};
    const float cv[8] = {c4a.x, c4a.y, c4a.z, c4a.w, c4b.x, c4b.y, c4b.z, c4b.w};
    bf16x8 bh[4], bl[4];
    // phase A: ALL waves read old p and Y, compute p' fragments in registers
#pragma unroll
    for (int ns = 0; ns < 4; ++ns) {
      const size_t idx = rowbase + (size_t)(ns * 16 + fr) * kC + cbase;
      ushort_t yh8[8], yl8[8], p8h[8], p8l[8], nh8[8], nl8[8];
      *(uint4*)yh8 = *(const uint4*)(yh + idx);
      *(uint4*)yl8 = *(const uint4*)(yl + idx);
      *(uint4*)p8h = *(const uint4*)(ph + idx);
      *(uint4*)p8l = *(const uint4*)(pl + idx);
#pragma unroll
      for (int j = 0; j < 8; ++j) {
        const float yv = us2f(yh8[j]) + us2f(yl8[j]);
        float z = av[j] * yv + cv[j];
        z = z > 0.f ? z : 0.2f * z;
        const float pv = us2f(p8h[j]) + us2f(p8l[j]) + z;
        nh8[j] = f2bu(pv);
        nl8[j] = f2bu(pv - us2f(nh8[j]));
      }
      bh[ns] = *(const bf16x8*)nh8;
      bl[ns] = *(const bf16x8*)nl8;
    }
    // phase B: barrier ensures every wave has READ old p for this kk's
    // columns before anyone overwrites them (fixes r13 race)
    __syncthreads();
    if (wv == 0) {  // all waves hold identical p'; store once
#pragma unroll
      for (int ns = 0; ns < 4; ++ns) {
        const size_t idx = rowbase + (size_t)(ns * 16 + fr) * kC + cbase;
        *(uint4*)(ph + idx) = *(const uint4*)&bh[ns];
        *(uint4*)(pl + idx) = *(const uint4*)&bl[ns];
      }
    }
    // phase C: MFMAs on p' fragments
    if (HASQV) {
      const size_t wi = (((size_t)kk * 4 + wv) * 64 + lane) * 8;
      const bf16x8 ah = *(const bf16x8*)(wqh + wi);
      const bf16x8 al = *(const bf16x8*)(wql + wi);
#pragma unroll
      for (int ns = 0; ns < 4; ++ns) {
        accq[ns] = __builtin_amdgcn_mfma_f32_16x16x32_bf16(ah, bh[ns], accq[ns], 0, 0, 0);
        accq[ns] = __builtin_amdgcn_mfma_f32_16x16x32_bf16(ah, bl[ns], accq[ns], 0, 0, 0);
        accq[ns] = __builtin_amdgcn_mfma_f32_16x16x32_bf16(al, bh[ns], accq[ns], 0, 0, 0);
      }
#pragma unroll
      for (int s = 0; s < 4; ++s) {
        const size_t wi2 = (((size_t)kk * 16 + wv * 4 + s) * 64 + lane) * 8;
        const bf16x8 vh = *(const bf16x8*)(wvh + wi2);
        const bf16x8 vl = *(const bf16x8*)(wvl + wi2);
#pragma unroll
        for (int ns = 0; ns < 4; ++ns) {
          accv[s][ns] = __builtin_amdgcn_mfma_f32_16x16x32_bf16(vh, bh[ns], accv[s][ns], 0, 0, 0);
          accv[s][ns] = __builtin_amdgcn_mfma_f32_16x16x32_bf16(vh, bl[ns], accv[s][ns], 0, 0, 0);
          accv[s][ns] = __builtin_amdgcn_mfma_f32_16x16x32_bf16(vl, bh[ns], accv[s][ns], 0, 0, 0);
        }
      }
    }
#pragma unroll
    for (int s = 0; s < 4; ++s) {
      const size_t wi3 = (((size_t)kk * 16 + wv * 4 + s) * 64 + lane) * 8;
      const bf16x8 dh = *(const bf16x8*)(wdh + wi3);
      const bf16x8 dl = *(const bf16x8*)(wdl + wi3);
#pragma unroll
      for (int ns = 0; ns < 4; ++ns) {
        accd[s][ns] = __builtin_amdgcn_mfma_f32_16x16x32_bf16(dh, bh[ns], accd[s][ns], 0, 0, 0);
        accd[s][ns] = __builtin_amdgcn_mfma_f32_16x16x32_bf16(dh, bl[ns], accd[s][ns], 0, 0, 0);
        accd[s][ns] = __builtin_amdgcn_mfma_f32_16x16x32_bf16(dl, bh[ns], accd[s][ns], 0, 0, 0);
      }
    }
  }
  // epilogues
  if (HASQV) {
    const int o0 = wv * 16 + fq * 4;
#pragma unroll
    for (int ns = 0; ns < 4; ++ns) {
      const int n = n0 + ns * 16 + fr;
      ushort_t h4[4], l4[4];
#pragma unroll
      for (int r = 0; r < 4; ++r) {
        const float v = accq[ns][r] + qbias[o0 + r];
        h4[r] = f2bu(v);
        l4[r] = f2bu(v - us2f(h4[r]));
      }
      *(ushort4*)(Qh + ((size_t)b * kN + n) * kH + o0) = *(const ushort4*)h4;
      *(ushort4*)(Ql + ((size_t)b * kN + n) * kH + o0) = *(const ushort4*)l4;
    }
#pragma unroll
    for (int s = 0; s < 4; ++s) {
      const int oV = (wv * 4 + s) * 16 + fq * 4;
#pragma unroll
      for (int ns = 0; ns < 4; ++ns) {
        const int n = n0 + ns * 16 + fr;
#pragma unroll
        for (int r = 0; r < 4; ++r)
          Vo[((size_t)b * kC + oV + r) * kN + n] =
              __float2bfloat16(accv[s][ns][r] + vbias[oV + r]);
      }
    }
  }
#pragma unroll
  for (int s = 0; s < 4; ++s) {
    const int oD = (wv * 4 + s) * 16 + fq * 4;
#pragma unroll
    for (int ns = 0; ns < 4; ++ns) {
      const int n = n0 + ns * 16 + fr;
#pragma unroll
      for (int r = 0; r < 4; ++r) {
        float* pp = hacc + ((size_t)b * kC + oD + r) * kN + n;
        *pp = *pp + accd[s][ns][r];
      }
    }
  }
}

// ---------------------------------------------------------------------------
// T-conv (split-bf16 MFMA): Y split bf16 IN-PLACE over (o1,o2) + BN partials
// (in-place safe: block reads all its own rows before storing them)
// ---------------------------------------------------------------------------
__global__ __launch_bounds__(256) void k_tconv(
    const ushort_t* __restrict__ xh, const ushort_t* __restrict__ xl,
    const ushort_t* __restrict__ wfh, const ushort_t* __restrict__ wfl,
    const float* __restrict__ bias,
    ushort_t* __restrict__ o1, ushort_t* __restrict__ o2,
    float* __restrict__ of) {
  const int t = threadIdx.x;
  const int b = blockIdx.y;
  const int n0 = blockIdx.x * 64;
  const int lane = t & 63, wv = t >> 6;
  const int fr = lane & 15, fq = lane >> 4;
  const ushort_t* xbh = xh + ((size_t)b * kN + n0) * kC;
  const ushort_t* xbl = xl + ((size_t)b * kN + n0) * kC;
  f32x4 acc[4][4];
#pragma unroll
  for (int s = 0; s < 4; ++s)
#pragma unroll
    for (int ns = 0; ns < 4; ++ns) acc[s][ns] = (f32x4){0.f, 0.f, 0.f, 0.f};
  for (int kk = 0; kk < 8; ++kk) {
    bf16x8 bh[4], bl[4];
#pragma unroll
    for (int ns = 0; ns < 4; ++ns) {
      const size_t xi = (size_t)(ns * 16 + fr) * kC + kk * 32 + fq * 8;
      bh[ns] = *(const bf16x8*)(xbh + xi);
      bl[ns] = *(const bf16x8*)(xbl + xi);
    }
#pragma unroll
    for (int s = 0; s < 4; ++s) {
      const size_t wi = (((size_t)kk * 16 + wv * 4 + s) * 64 + lane) * 8;
      const bf16x8 ah = *(const bf16x8*)(wfh + wi);
      const bf16x8 al = *(const bf16x8*)(wfl + wi);
#pragma unroll
      for (int ns = 0; ns < 4; ++ns) {
        acc[s][ns] = __builtin_amdgcn_mfma_f32_16x16x32_bf16(ah, bh[ns], acc[s][ns], 0, 0, 0);
        acc[s][ns] = __builtin_amdgcn_mfma_f32_16x16x32_bf16(ah, bl[ns], acc[s][ns], 0, 0, 0);
        acc[s][ns] = __builtin_amdgcn_mfma_f32_16x16x32_bf16(al, bh[ns], acc[s][ns], 0, 0, 0);
      }
    }
  }
  __syncthreads();  // all reads of x (aliased with o1/o2) complete block-wide
  const int blk = blockIdx.y * gridDim.x + blockIdx.x;  // 0..511
#pragma unroll
  for (int s = 0; s < 4; ++s) {
    const int o0 = (wv * 4 + s) * 16 + fq * 4;
    float yv[4][4];  // [ns][r]
#pragma unroll
    for (int ns = 0; ns < 4; ++ns) {
      const int n = n0 + ns * 16 + fr;
      const size_t idx = ((size_t)b * kN + n) * kC + o0;
      ushort_t h4[4], l4[4];
#pragma unroll
      for (int r = 0; r < 4; ++r) {
        const float y = acc[s][ns][r] + bias[o0 + r];
        yv[ns][r] = y;
        h4[r] = f2bu(y);
        l4[r] = f2bu(y - us2f(h4[r]));
      }
      *(ushort4*)(o1 + idx) = *(const ushort4*)h4;
      *(ushort4*)(o2 + idx) = *(const ushort4*)l4;
    }
#pragma unroll
    for (int r = 0; r < 4; ++r) {
      float s1 = yv[0][r] + yv[1][r] + yv[2][r] + yv[3][r];
      float s2 = yv[0][r] * yv[0][r] + yv[1][r] * yv[1][r] +
                 yv[2][r] * yv[2][r] + yv[3][r] * yv[3][r];
#pragma unroll
      for (int mask = 1; mask < 16; mask <<= 1) {
        s1 += __shfl_xor(s1, mask);
        s2 += __shfl_xor(s2, mask);
      }
      if (fr == 0) {
        of[(size_t)(o0 + r) * 512 + blk] = s1;
        of[131072 + (size_t)(o0 + r) * 512 + blk] = s2;
      }
    }
  }
}

// ---------------------------------------------------------------------------
// Reduce BN partials -> fused affine: af[c] = g*rsig, cf[c] = bb - af*mean
// ---------------------------------------------------------------------------
__global__ __launch_bounds__(128) void k_bnred(const float* __restrict__ part,
                                               const float* __restrict__ g,
                                               const float* __restrict__ bb,
                                               float* __restrict__ af,
                                               float* __restrict__ cf) {
  const int c = blockIdx.x, t = threadIdx.x;
  const float4 v1 = *(const float4*)&part[(size_t)c * 512 + t * 4];
  const float4 v2 = *(const float4*)&part[131072 + (size_t)c * 512 + t * 4];
  float s1 = v1.x + v1.y + v1.z + v1.w;
  float s2 = v2.x + v2.y + v2.z + v2.w;
  __shared__ float r1[128], r2[128];
  r1[t] = s1;
  r2[t] = s2;
  __syncthreads();
  for (int k = 64; k > 0; k >>= 1) {
    if (t < k) {
      r1[t] += r1[t + k];
      r2[t] += r2[t + k];
    }
    __syncthreads();
  }
  if (t == 0) {
    const float im = 1.f / (float)(kB * kN);
    const float m = r1[0] * im;
    const float var = r2[0] * im - m * m;
    const float a = g[c] * rsqrtf(var + 1e-5f);
    af[c] = a;
    cf[c] = bb[c] - a * m;
  }
}

// ---------------------------------------------------------------------------
// Row softmax stats via split-bf16 MFMA (round-10 version).
// ---------------------------------------------------------------------------
__global__ __launch_bounds__(256) void k_rowstats(const ushort_t* __restrict__ Qhi,
                                                  const ushort_t* __restrict__ Qlo,
                                                  float* __restrict__ rmx,
                                                  float* __restrict__ rsn) {
  __shared__ __align__(16) ushort_t Bh[2][64][72];
  __shared__ __align__(16) ushort_t Bl[2][64][72];
  const int b = blockIdx.y, t = threadIdx.x;
  const int r0 = blockIdx.x * 64;
  const int lane = t & 63, w = t >> 6;
  const int fr = lane & 15, fq = lane >> 4;
  const size_t qbase = (size_t)b * kN * kH;
  bf16x8 ah0, ah1, al0, al1;
  {
    const ushort_t* qh = Qhi + qbase + (size_t)(r0 + w * 16 + fr) * kH;
    const ushort_t* ql = Qlo + qbase + (size_t)(r0 + w * 16 + fr) * kH;
    ah0 = *(const bf16x8*)(qh + fq * 8);
    ah1 = *(const bf16x8*)(qh + 32 + fq * 8);
    al0 = *(const bf16x8*)(ql + fq * 8);
    al1 = *(const bf16x8*)(ql + 32 + fq * 8);
  }
  float mx[4] = {-3.0e38f, -3.0e38f, -3.0e38f, -3.0e38f};
  float sm[4] = {0.f, 0.f, 0.f, 0.f};
  const int srow = t >> 2, scol = (t & 3) * 16;
  {
    const ushort_t* qh = Qhi + qbase + (size_t)srow * kH + scol;
    const ushort_t* ql = Qlo + qbase + (size_t)srow * kH + scol;
    *(uint4*)&Bh[0][srow][scol] = *(const uint4*)qh;
    *(uint4*)&Bh[0][srow][scol + 8] = *(const uint4*)(qh + 8);
    *(uint4*)&Bl[0][srow][scol] = *(const uint4*)ql;
    *(uint4*)&Bl[0][srow][scol + 8] = *(const uint4*)(ql + 8);
  }
  __syncthreads();
  int cur = 0;
  for (int m0 = 0; m0 < kN; m0 += 64) {
    uint4 rh0, rh1, rl0, rl1;
    const bool pf = (m0 + 64 < kN);
    if (pf) {
      const ushort_t* qh = Qhi + qbase + (size_t)(m0 + 64 + srow) * kH + scol;
      const ushort_t* ql = Qlo + qbase + (size_t)(m0 + 64 + srow) * kH + scol;
      rh0 = *(const uint4*)qh;
      rh1 = *(const uint4*)(qh + 8);
      rl0 = *(const uint4*)ql;
      rl1 = *(const uint4*)(ql + 8);
    }
    float ev[4][4];
#pragma unroll
    for (int cs = 0; cs < 4; ++cs) {
      const bf16x8 bh0 = *(const bf16x8*)&Bh[cur][cs * 16 + fr][fq * 8];
      const bf16x8 bh1 = *(const bf16x8*)&Bh[cur][cs * 16 + fr][32 + fq * 8];
      const bf16x8 bl0 = *(const bf16x8*)&Bl[cur][cs * 16 + fr][fq * 8];
      const bf16x8 bl1 = *(const bf16x8*)&Bl[cur][cs * 16 + fr][32 + fq * 8];
      f32x4 e = {0.f, 0.f, 0.f, 0.f};
      e = __builtin_amdgcn_mfma_f32_16x16x32_bf16(ah0, bh0, e, 0, 0, 0);
      e = __builtin_amdgcn_mfma_f32_16x16x32_bf16(ah1, bh1, e, 0, 0, 0);
      e = __builtin_amdgcn_mfma_f32_16x16x32_bf16(ah0, bl0, e, 0, 0, 0);
      e = __builtin_amdgcn_mfma_f32_16x16x32_bf16(ah1, bl1, e, 0, 0, 0);
      e = __builtin_amdgcn_mfma_f32_16x16x32_bf16(al0, bh0, e, 0, 0, 0);
      e = __builtin_amdgcn_mfma_f32_16x16x32_bf16(al1, bh1, e, 0, 0, 0);
      ev[cs][0] = e[0]; ev[cs][1] = e[1]; ev[cs][2] = e[2]; ev[cs][3] = e[3];
    }
#pragma unroll
    for (int r = 0; r < 4; ++r) {
      const float tmax = fmaxf(fmaxf(ev[0][r], ev[1][r]), fmaxf(ev[2][r], ev[3][r]));
      const float nm = fmaxf(mx[r], tmax);
      sm[r] = sm[r] * __expf(mx[r] - nm) + __expf(ev[0][r] - nm) + __expf(ev[1][r] - nm) +
              __expf(ev[2][r] - nm) + __expf(ev[3][r] - nm);
      mx[r] = nm;
    }
    if (pf) {
      *(uint4*)&Bh[cur ^ 1][srow][scol] = rh0;
      *(uint4*)&Bh[cur ^ 1][srow][scol + 8] = rh1;
      *(uint4*)&Bl[cur ^ 1][srow][scol] = rl0;
      *(uint4*)&Bl[cur ^ 1][srow][scol + 8] = rl1;
    }
    __syncthreads();
    cur ^= 1;
  }
#pragma unroll
  for (int mask = 1; mask < 16; mask <<= 1) {
#pragma unroll
    for (int r = 0; r < 4; ++r) {
      const float om = __shfl_xor(mx[r], mask);
      const float os = __shfl_xor(sm[r], mask);
      const float nm = fmaxf(mx[r], om);
      sm[r] = sm[r] * __expf(mx[r] - nm) + os * __expf(om - nm);
      mx[r] = nm;
    }
  }
  if (fr == 0) {
#pragma unroll
    for (int r = 0; r < 4; ++r) {
      const int row = r0 + w * 16 + fq * 4 + r;
      rmx[(size_t)b * kN + row] = mx[r];
      rsn[(size_t)b * kN + row] = 1.f / sm[r];
    }
  }
}

// ---------------------------------------------------------------------------
// Column pass, MT=64 (round-10 version — measured floor ~124 us).
// ---------------------------------------------------------------------------
__global__ __launch_bounds__(256) void k_colpass(const ushort_t* __restrict__ Qhi,
                                                 const ushort_t* __restrict__ Qlo,
                                                 const bf16* __restrict__ V,
                                                 const float* __restrict__ rmx,
                                                 const float* __restrict__ rsn,
                                                 const ushort_t* __restrict__ psh,
                                                 const ushort_t* __restrict__ psl,
                                                 ushort_t* __restrict__ ush,
                                                 ushort_t* __restrict__ usl) {
  constexpr int MT = 64, NT = 32;
  __shared__ __align__(16) ushort_t Anh[2][NT][72];
  __shared__ __align__(16) ushort_t Anl[2][NT][72];
  __shared__ __align__(16) ushort_t Vs[2][kC][40];
  __shared__ __align__(16) ushort_t Pl[MT][40];
  __shared__ float CsI[MT];
  const int t = threadIdx.x;
  const int b = blockIdx.y;
  const int mBase = blockIdx.x * MT;
  const size_t qbase = (size_t)b * kN * kH;
  const ushort_t* Vb_ = (const ushort_t*)V + (size_t)b * kC * kN;
  const int lane = t & 63, wv = t >> 6;
  const int fr = lane & 15, fq = lane >> 4;
  bf16x8 bmh0, bmh1, bml0, bml1;
  {
    const ushort_t* qh = Qhi + qbase + (size_t)(mBase + wv * 16 + fr) * kH;
    const ushort_t* ql = Qlo + qbase + (size_t)(mBase + wv * 16 + fr) * kH;
    bmh0 = *(const bf16x8*)(qh + fq * 8);
    bmh1 = *(const bf16x8*)(qh + 32 + fq * 8);
    bml0 = *(const bf16x8*)(ql + fq * 8);
    bml1 = *(const bf16x8*)(ql + 32 + fq * 8);
  }
  f32x4 acc[4][4];
#pragma unroll
  for (int i = 0; i < 4; ++i)
#pragma unroll
    for (int j = 0; j < 4; ++j) acc[i][j] = (f32x4){0.f, 0.f, 0.f, 0.f};
  float csloc = 0.f;
  const int arow = t >> 3, acol = (t & 7) * 8;
  const int vc = t >> 2, vq = t & 3;
  {
    *(uint4*)&Anh[0][arow][acol] = *(const uint4*)(Qhi + qbase + (size_t)arow * kH + acol);
    *(uint4*)&Anl[0][arow][acol] = *(const uint4*)(Qlo + qbase + (size_t)arow * kH + acol);
#pragma unroll
    for (int it = 0; it < 4; ++it) {
      const int c = it * 64 + vc;
      *(uint4*)&Vs[0][c][vq * 8] = *(const uint4*)(Vb_ + (size_t)c * kN + vq * 8);
    }
  }
  __syncthreads();
  int cur = 0;
  for (int n0 = 0; n0 < kN; n0 += NT) {
    uint4 rAh, rAl, rV0, rV1, rV2, rV3;
    const bool pf = (n0 + NT < kN);
    if (pf) {
      const int nn = n0 + NT;
      rAh = *(const uint4*)(Qhi + qbase + (size_t)(nn + arow) * kH + acol);
      rAl = *(const uint4*)(Qlo + qbase + (size_t)(nn + arow) * kH + acol);
      rV0 = *(const uint4*)(Vb_ + (size_t)(0 * 64 + vc) * kN + nn + vq * 8);
      rV1 = *(const uint4*)(Vb_ + (size_t)(1 * 64 + vc) * kN + nn + vq * 8);
      rV2 = *(const uint4*)(Vb_ + (size_t)(2 * 64 + vc) * kN + nn + vq * 8);
      rV3 = *(const uint4*)(Vb_ + (size_t)(3 * 64 + vc) * kN + nn + vq * 8);
    }
    const float4 rm0 = *(const float4*)&rmx[(size_t)b * kN + n0 + fq * 4];
    const float4 rm1 = *(const float4*)&rmx[(size_t)b * kN + n0 + 16 + fq * 4];
    const float4 rs0 = *(const float4*)&rsn[(size_t)b * kN + n0 + fq * 4];
    const float4 rs1 = *(const float4*)&rsn[(size_t)b * kN + n0 + 16 + fq * 4];
#pragma unroll
    for (int ns = 0; ns < 2; ++ns) {
      const bf16x8 ah0 = *(const bf16x8*)&Anh[cur][ns * 16 + fr][fq * 8];
      const bf16x8 ah1 = *(const bf16x8*)&Anh[cur][ns * 16 + fr][32 + fq * 8];
      const bf16x8 al0 = *(const bf16x8*)&Anl[cur][ns * 16 + fr][fq * 8];
      const bf16x8 al1 = *(const bf16x8*)&Anl[cur][ns * 16 + fr][32 + fq * 8];
      f32x4 e = {0.f, 0.f, 0.f, 0.f};
      e = __builtin_amdgcn_mfma_f32_16x16x32_bf16(ah0, bmh0, e, 0, 0, 0);
      e = __builtin_amdgcn_mfma_f32_16x16x32_bf16(ah1, bmh1, e, 0, 0, 0);
      e = __builtin_amdgcn_mfma_f32_16x16x32_bf16(ah0, bml0, e, 0, 0, 0);
      e = __builtin_amdgcn_mfma_f32_16x16x32_bf16(ah1, bml1, e, 0, 0, 0);
      e = __builtin_amdgcn_mfma_f32_16x16x32_bf16(al0, bmh0, e, 0, 0, 0);
      e = __builtin_amdgcn_mfma_f32_16x16x32_bf16(al1, bmh1, e, 0, 0, 0);
      const float4 rm = ns ? rm1 : rm0;
      const float4 rs = ns ? rs1 : rs0;
      ushort_t p4[4];
      {
        const float p0 = __expf(e[0] - rm.x) * rs.x;
        const float p1 = __expf(e[1] - rm.y) * rs.y;
        const float p2 = __expf(e[2] - rm.z) * rs.z;
        const float p3 = __expf(e[3] - rm.w) * rs.w;
        p4[0] = f2bu(p0); p4[1] = f2bu(p1); p4[2] = f2bu(p2); p4[3] = f2bu(p3);
        csloc += p0 + p1 + p2 + p3;
      }
      *(ushort4*)&Pl[wv * 16 + fr][ns * 16 + fq * 4] = *(const ushort4*)p4;
    }
    __syncthreads();
    bf16x8 am[4], bv[4];
#pragma unroll
    for (int ms = 0; ms < 4; ++ms)
      am[ms] = *(const bf16x8*)&Pl[ms * 16 + fr][fq * 8];
#pragma unroll
    for (int cs = 0; cs < 4; ++cs)
      bv[cs] = *(const bf16x8*)&Vs[cur][wv * 64 + cs * 16 + fr][fq * 8];
#pragma unroll
    for (int ms = 0; ms < 4; ++ms)
#pragma unroll
      for (int cs = 0; cs < 4; ++cs)
        acc[ms][cs] = __builtin_amdgcn_mfma_f32_16x16x32_bf16(am[ms], bv[cs], acc[ms][cs], 0, 0, 0);
    if (pf) {
      *(uint4*)&Anh[cur ^ 1][arow][acol] = rAh;
      *(uint4*)&Anl[cur ^ 1][arow][acol] = rAl;
      *(uint4*)&Vs[cur ^ 1][0 * 64 + vc][vq * 8] = rV0;
      *(uint4*)&Vs[cur ^ 1][1 * 64 + vc][vq * 8] = rV1;
      *(uint4*)&Vs[cur ^ 1][2 * 64 + vc][vq * 8] = rV2;
      *(uint4*)&Vs[cur ^ 1][3 * 64 + vc][vq * 8] = rV3;
    }
    __syncthreads();
    cur ^= 1;
  }
  csloc += __shfl_xor(csloc, 16);
  csloc += __shfl_xor(csloc, 32);
  if (fq == 0) CsI[wv * 16 + fr] = 1.f / (1e-9f + csloc);
  __syncthreads();
#pragma unroll
  for (int ms = 0; ms < 4; ++ms) {
#pragma unroll
    for (int r = 0; r < 4; ++r) {
      const int ml = ms * 16 + fq * 4 + r;
      const float inv = CsI[ml];
      const size_t row = ((size_t)b * kN + mBase + ml) * kC;
#pragma unroll
      for (int cs = 0; cs < 4; ++cs) {
        const int c = wv * 64 + cs * 16 + fr;
        const float xv = us2f(psh[row + c]) + us2f(psl[row + c]);
        const float u = xv - acc[ms][cs][r] * inv;
        const ushort_t h = f2bu(u);
        ush[row + c] = h;
        usl[row + c] = f2bu(u - us2f(h));
      }
    }
  }
}

// ---------------------------------------------------------------------------
// BN stats per channel over (B, N), fp32 [b][nch][N] input, biased var.
// ---------------------------------------------------------------------------
__global__ __launch_bounds__(256) void k_bnstats(const float* __restrict__ y, int nch,
                                                 float* __restrict__ mean,
                                                 float* __restrict__ rsig) {
  const int c = blockIdx.x, t = threadIdx.x;
  float s = 0.f, s2 = 0.f;
  for (int b = 0; b < kB; ++b) {
    const float* p = y + ((size_t)b * nch + c) * kN;
    for (int n = t; n < kN; n += 256) {
      const float v = p[n];
      s += v;
      s2 += v * v;
    }
  }
  __shared__ float r1[256], r2[256];
  r1[t] = s;
  r2[t] = s2;
  __syncthreads();
  for (int k = 128; k > 0; k >>= 1) {
    if (t < k) {
      r1[t] += r1[t + k];
      r2[t] += r2[t + k];
    }
    __syncthreads();
  }
  if (t == 0) {
    const float im = 1.f / (float)(kB * kN);
    const float m = r1[0] * im;
    const float var = r2[0] * im - m * m;
    mean[c] = m;
    rsig[c] = rsqrtf(var + 1e-5f);
  }
}

// ---------------------------------------------------------------------------
// dc2: tpre[b,j,n] = dc2_b[j] + sum_c dc2_w[j,c] * leaky(bn(h[b,c,n]))
// ---------------------------------------------------------------------------
__global__ __launch_bounds__(256) void k_dc2(const float* __restrict__ h,
                                             const float* __restrict__ mean,
                                             const float* __restrict__ rsig,
                                             const float* __restrict__ g,
                                             const float* __restrict__ bb,
                                             const float* __restrict__ w,
                                             const float* __restrict__ d2b,
                                             float* __restrict__ tpre) {
  __shared__ float wS[3][kC];
  __shared__ float aS[kC], cS[kC];
  const int t = threadIdx.x, b = blockIdx.y;
  const int n = blockIdx.x * 256 + t;
  {
    const float a = g[t] * rsig[t];
    aS[t] = a;
    cS[t] = bb[t] - a * mean[t];
    wS[0][t] = w[t];
    wS[1][t] = w[kC + t];
    wS[2][t] = w[2 * kC + t];
  }
  __syncthreads();
  float a0 = d2b[0], a1 = d2b[1], a2 = d2b[2];
  const float* hb = h + (size_t)b * kC * kN + n;
  for (int c = 0; c < kC; ++c) {
    float z = hb[(size_t)c * kN] * aS[c] + cS[c];
    z = z > 0.f ? z : 0.2f * z;
    a0 += wS[0][c] * z;
    a1 += wS[1][c] * z;
    a2 += wS[2][c] * z;
  }
  tpre[((size_t)b * 3 + 0) * kN + n] = a0;
  tpre[((size_t)b * 3 + 1) * kN + n] = a1;
  tpre[((size_t)b * 3 + 2) * kN + n] = a2;
}

// ---------------------------------------------------------------------------
// Final: out[b,n,j] = tanh(g[j]*(tpre[b,j,n]-mean[j])*rsig[j] + b[j])
// ---------------------------------------------------------------------------
__global__ __launch_bounds__(256) void k_final(const float* __restrict__ tpre,
                                               const float* __restrict__ mean,
                                               const float* __restrict__ rsig,
                                               const float* __restrict__ g,
                                               const float* __restrict__ bb,
                                               float* __restrict__ out) {
  const int i = blockIdx.x * 256 + threadIdx.x;  // over B*N
  const int n = i & (kN - 1), b = i >> 11;
#pragma unroll
  for (int j = 0; j < 3; ++j) {
    const float v = tpre[((size_t)b * 3 + j) * kN + n];
    const float z = g[j] * (v - mean[j]) * rsig[j] + bb[j];
    out[(size_t)i * 3 + j] = tanhf(z);
  }
}

// ---------------------------------------------------------------------------
extern "C" void kernel_launch(void* const* d_in, const int* in_sizes, int n_in,
                              void* d_out, int out_size, void* d_ws, size_t ws_size,
                              hipStream_t stream) {
  const float* feature  = (const float*)d_in[0];
  const float* prior    = (const float*)d_in[1];
  const float* mlp_w    = (const float*)d_in[2];
  const float* mlp_b    = (const float*)d_in[3];
  const float* qk_w     = (const float*)d_in[4];
  const float* qk_b     = (const float*)d_in[5];
  const float* v_w      = (const float*)d_in[6];
  const float* v_b      = (const float*)d_in[7];
  const float* t_w      = (const float*)d_in[8];
  const float* t_b      = (const float*)d_in[9];
  const float* bn_g     = (const float*)d_in[10];
  const float* bn_b     = (const float*)d_in[11];
  const float* dc1_w    = (const float*)d_in[12];
  const float* dc1_bn_g = (const float*)d_in[13];
  const float* dc1_bn_b = (const float*)d_in[14];
  const float* dc2_w    = (const float*)d_in[15];
  const float* dc2_b    = (const float*)d_in[16];
  const float* dc2_bn_g = (const float*)d_in[17];
  const float* dc2_bn_b = (const float*)d_in[18];
  float* out = (float*)d_out;

  // Workspace carve. Total ~125 MiB.
  char* base = (char*)d_ws;
  size_t off = 0;
  auto carve = [&](size_t bytes) {
    char* p = base + off;
    off += (bytes + 255) & ~(size_t)255;
    return p;
  };
  const size_t ne = (size_t)kB * kN * kC;                 // 8,388,608
  ushort_t* psh  = (ushort_t*)carve(ne * 2);              // p hi   16 MiB
  ushort_t* psl  = (ushort_t*)carve(ne * 2);              // p lo   16 MiB
  ushort_t* ush  = (ushort_t*)carve(ne * 2);              // u/Y hi 16 MiB
  ushort_t* usl  = (ushort_t*)carve(ne * 2);              // u/Y lo 16 MiB
  float*    hacc = (float*)carve(ne * 4);                 // dc1    32 MiB
  ushort_t* Qhi  = (ushort_t*)carve((size_t)kB * kN * kH * 2);  // 4 MiB
  ushort_t* Qlo  = (ushort_t*)carve((size_t)kB * kN * kH * 2);  // 4 MiB
  bf16*     Vb   = (bf16*)carve(ne * 2);                  // V      16 MiB
  ushort_t* wfh  = (ushort_t*)carve((size_t)851968 * 2);  // 1.63 MiB
  ushort_t* wfl  = (ushort_t*)carve((size_t)851968 * 2);  // 1.63 MiB
  float*    part = (float*)carve((size_t)2 * 131072 * 4); // 1 MiB
  float*    rmx  = (float*)carve((size_t)kB * kN * 4);
  float*    rsn  = (float*)carve((size_t)kB * kN * 4);
  float*    fb   = (float*)carve((size_t)kB * kC * 4);
  float*    bnm  = (float*)carve(kC * 4);
  float*    bnr  = (float*)carve(kC * 4);
  float*    tpre = (float*)carve((size_t)kB * 3 * kN * 4);

  hipMemsetAsync(hacc, 0, ne * 4, stream);  // dc1 accumulator init
  k_wsplit<<<416, 256, 0, stream>>>(qk_w, v_w, t_w, dc1_w, wfh, wfl);
  k_fb<<<kB * kC, 256, 0, stream>>>(feature, mlp_w, mlp_b, fb);
  k_p0<<<(int)(ne / 256), 256, 0, stream>>>(prior, mlp_w, fb, psh, psl);

  const dim3 gC(kN / 64, kB);
  // layer-0 Q/V
  k_qv<<<gC, 256, 0, stream>>>(psh, psl, wfh, wfl, wfh + 65536, wfl + 65536,
                               qk_b, v_b, Qhi, Qlo, Vb);
  for (int l = 0; l < 4; ++l) {
    const size_t t_off   = 327680 + (size_t)l * 65536;
    const size_t dc1_off = 589824 + (size_t)l * 65536;
    k_rowstats<<<gC, 256, 0, stream>>>(Qhi, Qlo, rmx, rsn);
    k_colpass<<<gC, 256, 0, stream>>>(Qhi, Qlo, Vb, rmx, rsn, psh, psl, ush, usl);
    k_tconv<<<gC, 256, 0, stream>>>(ush, usl, wfh + t_off, wfl + t_off,
                                    t_b + l * kC, ush, usl, part);
    k_bnred<<<kC, 128, 0, stream>>>(part, bn_g + l * kC, bn_b + l * kC, bnm, bnr);
    if (l < 3) {
      const size_t qk_n = (size_t)(l + 1) * 16384;
      const size_t v_n  = 65536 + (size_t)(l + 1) * 65536;
      k_fuse<1><<<gC, 256, 0, stream>>>(ush, usl, psh, psl, bnm, bnr,
                                        wfh + qk_n, wfl + qk_n,
                                        wfh + v_n, wfl + v_n,
                                        wfh + dc1_off, wfl + dc1_off,
                                        qk_b + (l + 1) * kH, v_b + (l + 1) * kC,
                                        Qhi, Qlo, Vb, hacc);
    } else {
      k_fuse<0><<<gC, 256, 0, stream>>>(ush, usl, psh, psl, bnm, bnr,
                                        nullptr, nullptr, nullptr, nullptr,
                                        wfh + dc1_off, wfl + dc1_off,
                                        nullptr, nullptr,
                                        nullptr, nullptr, nullptr, hacc);
    }
  }

  k_bnstats<<<kC, 256, 0, stream>>>(hacc, kC, bnm, bnr);
  k_dc2<<<dim3(kN / 256, kB), 256, 0, stream>>>(hacc, bnm, bnr, dc1_bn_g, dc1_bn_b,
                                                dc2_w, dc2_b, tpre);
  k_bnstats<<<3, 256, 0, stream>>>(tpre, 3, bnm, bnr);
  k_final<<<(kB * kN) / 256, 256, 0, stream>>>(tpre, bnm, bnr, dc2_bn_g, dc2_bn_b, out);
}

// Round 15
// 1175.607 us; speedup vs baseline: 1.3707x; 1.0060x over previous
//
#include <hip/hip_runtime.h>
#include <hip/hip_bf16.h>

typedef __hip_bfloat16 bf16;
typedef unsigned short ushort_t;

// Problem constants
constexpr int kB = 16;    // batch
constexpr int kN = 2048;  // points
constexpr int kF = 1024;  // feat dims
constexpr int kC = 256;   // channels
constexpr int kH = 64;    // head dim

using f32x4 = __attribute__((ext_vector_type(4))) float;
using bf16x8 = __attribute__((ext_vector_type(8))) short;  // 8 bf16 (4 VGPRs)

__device__ __forceinline__ float us2f(unsigned short u) {
  union { unsigned int i; float f; } w;
  w.i = ((unsigned int)u) << 16;
  return w.f;
}
__device__ __forceinline__ unsigned short f2bu(float f) {
  union { bf16 h; unsigned short s; } u;
  u.h = __float2bfloat16(f);
  return u.s;
}

// ---------------------------------------------------------------------------
// fb[b,c] = mlp_b[c] + sum_f mlp_w[c,f] * feature[b,f]
// ---------------------------------------------------------------------------
__global__ __launch_bounds__(256) void k_fb(const float* __restrict__ feat,
                                            const float* __restrict__ mlp_w,
                                            const float* __restrict__ mlp_b,
                                            float* __restrict__ fb) {
  const int b = blockIdx.x >> 8;
  const int c = blockIdx.x & 255;
  const int t = threadIdx.x;
  const float* wr = mlp_w + (size_t)c * (kF + 3);
  const float* fr = feat + (size_t)b * kF;
  float s = 0.f;
  for (int f = t; f < kF; f += 256) s += wr[f] * fr[f];
  __shared__ float red[256];
  red[t] = s;
  __syncthreads();
  for (int k = 128; k > 0; k >>= 1) {
    if (t < k) red[t] += red[t + k];
    __syncthreads();
  }
  if (t == 0) fb[blockIdx.x] = red[0] + mlp_b[c];
}

// ---------------------------------------------------------------------------
// p[b,n,c] = fb[b,c] + sum_{j<3} mlp_w[c,1024+j] * prior[b,j,n]  (split bf16)
// ---------------------------------------------------------------------------
__global__ __launch_bounds__(256) void k_p0(const float* __restrict__ prior,
                                            const float* __restrict__ mlp_w,
                                            const float* __restrict__ fb,
                                            ushort_t* __restrict__ psh,
                                            ushort_t* __restrict__ psl) {
  const size_t i = (size_t)blockIdx.x * 256 + threadIdx.x;  // over B*N*C
  const int c = (int)(i & 255);
  const int n = (int)((i >> 8) & 2047);
  const int b = (int)(i >> 19);
  const float* wr = mlp_w + (size_t)c * (kF + 3) + kF;
  const float* pr = prior + (size_t)b * 3 * kN + n;
  const float v = fb[b * kC + c] + wr[0] * pr[0] + wr[1] * pr[kN] + wr[2] * pr[2 * kN];
  const ushort_t h = f2bu(v);
  psh[i] = h;
  psl[i] = f2bu(v - us2f(h));
}

// ---------------------------------------------------------------------------
// Pre-split weights into MFMA A-fragment order (hi/lo bf16).
// Regions (group = 8 elems): qk 4x2048 | v 4x8192 | t 4x8192 | dc1 4x8192
// ---------------------------------------------------------------------------
__global__ __launch_bounds__(256) void k_wsplit(const float* __restrict__ qk_w,
                                                const float* __restrict__ v_w,
                                                const float* __restrict__ t_w,
                                                const float* __restrict__ dc1_w,
                                                ushort_t* __restrict__ wfh,
                                                ushort_t* __restrict__ wfl) {
  const int idx = blockIdx.x * 256 + threadIdx.x;  // group index
  const float* src;
  int stride, OS_;
  size_t dstoff;
  int g;
  if (idx < 8192) {
    const int l = idx >> 11; g = idx & 2047;
    src = qk_w + (size_t)l * 64 * 256; stride = 256; OS_ = 4;
    dstoff = (size_t)l * 16384;
  } else if (idx < 40960) {
    const int i2 = idx - 8192; const int l = i2 >> 13; g = i2 & 8191;
    src = v_w + (size_t)l * 256 * 256; stride = 256; OS_ = 16;
    dstoff = 65536 + (size_t)l * 65536;
  } else if (idx < 73728) {
    const int i2 = idx - 40960; const int l = i2 >> 13; g = i2 & 8191;
    src = t_w + (size_t)l * 256 * 256; stride = 256; OS_ = 16;
    dstoff = 327680 + (size_t)l * 65536;
  } else {
    const int i2 = idx - 73728; const int l = i2 >> 13; g = i2 & 8191;
    src = dc1_w + (size_t)l * 256; stride = 1024; OS_ = 16;
    dstoff = 589824 + (size_t)l * 65536;
  }
  const int kk = g / (OS_ * 64);
  const int rem = g % (OS_ * 64);
  const int osub = rem >> 6;
  const int lane = rem & 63;
  const int o = osub * 16 + (lane & 15);
  const int c = kk * 32 + (lane >> 4) * 8;
  const float* sp = src + (size_t)o * stride + c;
  ushort_t h[8], l8[8];
#pragma unroll
  for (int j = 0; j < 8; ++j) {
    const float v = sp[j];
    h[j] = f2bu(v);
    l8[j] = f2bu(v - us2f(h[j]));
  }
  *(uint4*)(wfh + dstoff + (size_t)g * 8) = *(const uint4*)h;
  *(uint4*)(wfl + dstoff + (size_t)g * 8) = *(const uint4*)l8;
}

// ---------------------------------------------------------------------------
// Fused Q+V conv for layer 0 (split-bf16 MFMA). Block: 64 n, 4 waves.
// ---------------------------------------------------------------------------
__global__ __launch_bounds__(256) void k_qv(
    const ushort_t* __restrict__ xh, const ushort_t* __restrict__ xl,
    const ushort_t* __restrict__ wqh, const ushort_t* __restrict__ wql,
    const ushort_t* __restrict__ wvh, const ushort_t* __restrict__ wvl,
    const float* __restrict__ qbias, const float* __restrict__ vbias,
    ushort_t* __restrict__ Qh, ushort_t* __restrict__ Ql,
    bf16* __restrict__ Vo) {
  const int t = threadIdx.x;
  const int b = blockIdx.y;
  const int n0 = blockIdx.x * 64;
  const int lane = t & 63, wv = t >> 6;
  const int fr = lane & 15, fq = lane >> 4;
  const ushort_t* xbh = xh + ((size_t)b * kN + n0) * kC;
  const ushort_t* xbl = xl + ((size_t)b * kN + n0) * kC;
  f32x4 accq[4];
  f32x4 accv[4][4];
#pragma unroll
  for (int ns = 0; ns < 4; ++ns) {
    accq[ns] = (f32x4){0.f, 0.f, 0.f, 0.f};
#pragma unroll
    for (int s = 0; s < 4; ++s) accv[s][ns] = (f32x4){0.f, 0.f, 0.f, 0.f};
  }
  for (int kk = 0; kk < 8; ++kk) {
    bf16x8 bh[4], bl[4];
#pragma unroll
    for (int ns = 0; ns < 4; ++ns) {
      const size_t xi = (size_t)(ns * 16 + fr) * kC + kk * 32 + fq * 8;
      bh[ns] = *(const bf16x8*)(xbh + xi);
      bl[ns] = *(const bf16x8*)(xbl + xi);
    }
    {  // Q weights: region OS=4
      const size_t wi = (((size_t)kk * 4 + wv) * 64 + lane) * 8;
      const bf16x8 ah = *(const bf16x8*)(wqh + wi);
      const bf16x8 al = *(const bf16x8*)(wql + wi);
#pragma unroll
      for (int ns = 0; ns < 4; ++ns) {
        accq[ns] = __builtin_amdgcn_mfma_f32_16x16x32_bf16(ah, bh[ns], accq[ns], 0, 0, 0);
        accq[ns] = __builtin_amdgcn_mfma_f32_16x16x32_bf16(ah, bl[ns], accq[ns], 0, 0, 0);
        accq[ns] = __builtin_amdgcn_mfma_f32_16x16x32_bf16(al, bh[ns], accq[ns], 0, 0, 0);
      }
    }
#pragma unroll
    for (int s = 0; s < 4; ++s) {  // V weights: region OS=16
      const size_t wi = (((size_t)kk * 16 + wv * 4 + s) * 64 + lane) * 8;
      const bf16x8 ah = *(const bf16x8*)(wvh + wi);
      const bf16x8 al = *(const bf16x8*)(wvl + wi);
#pragma unroll
      for (int ns = 0; ns < 4; ++ns) {
        accv[s][ns] = __builtin_amdgcn_mfma_f32_16x16x32_bf16(ah, bh[ns], accv[s][ns], 0, 0, 0);
        accv[s][ns] = __builtin_amdgcn_mfma_f32_16x16x32_bf16(ah, bl[ns], accv[s][ns], 0, 0, 0);
        accv[s][ns] = __builtin_amdgcn_mfma_f32_16x16x32_bf16(al, bh[ns], accv[s][ns], 0, 0, 0);
      }
    }
  }
  {
    const int o0 = wv * 16 + fq * 4;
#pragma unroll
    for (int ns = 0; ns < 4; ++ns) {
      const int n = n0 + ns * 16 + fr;
      ushort_t h4[4], l4[4];
#pragma unroll
      for (int r = 0; r < 4; ++r) {
        const float v = accq[ns][r] + qbias[o0 + r];
        h4[r] = f2bu(v);
        l4[r] = f2bu(v - us2f(h4[r]));
      }
      *(ushort4*)(Qh + ((size_t)b * kN + n) * kH + o0) = *(const ushort4*)h4;
      *(ushort4*)(Ql + ((size_t)b * kN + n) * kH + o0) = *(const ushort4*)l4;
    }
  }
#pragma unroll
  for (int s = 0; s < 4; ++s) {
    const int o0 = (wv * 4 + s) * 16 + fq * 4;
#pragma unroll
    for (int ns = 0; ns < 4; ++ns) {
      const int n = n0 + ns * 16 + fr;
#pragma unroll
      for (int r = 0; r < 4; ++r)
        Vo[((size_t)b * kC + o0 + r) * kN + n] = __float2bfloat16(accv[s][ns][r] + vbias[o0 + r]);
    }
  }
}

// ---------------------------------------------------------------------------
// Layer-boundary fusion, wave-split version: each wave OWNS 2 of the 8 kk
// column-groups (one per half). Owner computes p' = p + leaky(af*Y+cf) for
// its 32-c slice, stores to global AND a [64n][128c] split-bf16 LDS tile;
// barrier; all waves run Q/V/dc1 MFMAs for the half's 4 kks from LDS.
// No global p race (single owner per address). 4 barriers total.
// ---------------------------------------------------------------------------
template <int HASQV>
__global__ __launch_bounds__(256, 2) void k_fuse(
    const ushort_t* __restrict__ yh, const ushort_t* __restrict__ yl,
    ushort_t* __restrict__ ph, ushort_t* __restrict__ pl,
    const float* __restrict__ af, const float* __restrict__ cf,
    const ushort_t* __restrict__ wqh, const ushort_t* __restrict__ wql,
    const ushort_t* __restrict__ wvh, const ushort_t* __restrict__ wvl,
    const ushort_t* __restrict__ wdh, const ushort_t* __restrict__ wdl,
    const float* __restrict__ qbias, const float* __restrict__ vbias,
    ushort_t* __restrict__ Qh, ushort_t* __restrict__ Ql,
    bf16* __restrict__ Vo, float* __restrict__ hacc) {
  __shared__ __align__(16) ushort_t Sh[64][140];  // p' hi, half tile [n][c128]
  __shared__ __align__(16) ushort_t Sl[64][140];  // p' lo
  const int t = threadIdx.x;
  const int b = blockIdx.y;
  const int n0 = blockIdx.x * 64;
  const int lane = t & 63, wv = t >> 6;
  const int fr = lane & 15, fq = lane >> 4;
  const size_t rowbase = ((size_t)b * kN + n0) * kC;
  f32x4 accq[4];
  f32x4 accv[4][4];
  f32x4 accd[4][4];
#pragma unroll
  for (int ns = 0; ns < 4; ++ns) {
    accq[ns] = (f32x4){0.f, 0.f, 0.f, 0.f};
#pragma unroll
    for (int s = 0; s < 4; ++s) {
      accv[s][ns] = (f32x4){0.f, 0.f, 0.f, 0.f};
      accd[s][ns] = (f32x4){0.f, 0.f, 0.f, 0.f};
    }
  }
  for (int half = 0; half < 2; ++half) {
    // phase A: owner wave computes p' for its kk = half*4 + wv
    {
      const int kkw = half * 4 + wv;
      const int cbase = kkw * 32 + fq * 8;
      const float4 a4a = *(const float4*)(af + cbase);
      const float4 a4b = *(const float4*)(af + cbase + 4);
      const float4 c4a = *(const float4*)(cf + cbase);
      const float4 c4b = *(const float4*)(cf + cbase + 4);
      const float av[8] = {a4a.x, a4a.y, a4a.z, a4a.w, a4b.x, a4b.y, a4b.z, a4b.w};
      const float cv[8] = {c4a.x, c4a.y, c4a.z, c4a.w, c4b.x, c4b.y, c4b.z, c4b.w};
      const int lcol = wv * 32 + fq * 8;  // column within the half tile
#pragma unroll
      for (int ns = 0; ns < 4; ++ns) {
        const size_t idx = rowbase + (size_t)(ns * 16 + fr) * kC + cbase;
        ushort_t yh8[8], yl8[8], p8h[8], p8l[8], nh8[8], nl8[8];
        *(uint4*)yh8 = *(const uint4*)(yh + idx);
        *(uint4*)yl8 = *(const uint4*)(yl + idx);
        *(uint4*)p8h = *(const uint4*)(ph + idx);
        *(uint4*)p8l = *(const uint4*)(pl + idx);
#pragma unroll
        for (int j = 0; j < 8; ++j) {
          const float yv = us2f(yh8[j]) + us2f(yl8[j]);
          float z = av[j] * yv + cv[j];
          z = z > 0.f ? z : 0.2f * z;
          const float pv = us2f(p8h[j]) + us2f(p8l[j]) + z;
          nh8[j] = f2bu(pv);
          nl8[j] = f2bu(pv - us2f(nh8[j]));
        }
        *(uint4*)(ph + idx) = *(const uint4*)nh8;   // single owner: no race
        *(uint4*)(pl + idx) = *(const uint4*)nl8;
        *(uint4*)&Sh[ns * 16 + fr][lcol] = *(const uint4*)nh8;
        *(uint4*)&Sl[ns * 16 + fr][lcol] = *(const uint4*)nl8;
      }
    }
    __syncthreads();  // p' half-tile visible in LDS
    // phase B: MFMAs for the half's 4 kks, B-fragments from LDS
#pragma unroll
    for (int kkl = 0; kkl < 4; ++kkl) {
      const int kk = half * 4 + kkl;
      bf16x8 bh[4], bl[4];
#pragma unroll
      for (int ns = 0; ns < 4; ++ns) {
        bh[ns] = *(const bf16x8*)&Sh[ns * 16 + fr][kkl * 32 + fq * 8];
        bl[ns] = *(const bf16x8*)&Sl[ns * 16 + fr][kkl * 32 + fq * 8];
      }
      if (HASQV) {
        const size_t wi = (((size_t)kk * 4 + wv) * 64 + lane) * 8;
        const bf16x8 ah = *(const bf16x8*)(wqh + wi);
        const bf16x8 al = *(const bf16x8*)(wql + wi);
#pragma unroll
        for (int ns = 0; ns < 4; ++ns) {
          accq[ns] = __builtin_amdgcn_mfma_f32_16x16x32_bf16(ah, bh[ns], accq[ns], 0, 0, 0);
          accq[ns] = __builtin_amdgcn_mfma_f32_16x16x32_bf16(ah, bl[ns], accq[ns], 0, 0, 0);
          accq[ns] = __builtin_amdgcn_mfma_f32_16x16x32_bf16(al, bh[ns], accq[ns], 0, 0, 0);
        }
#pragma unroll
        for (int s = 0; s < 4; ++s) {
          const size_t wi2 = (((size_t)kk * 16 + wv * 4 + s) * 64 + lane) * 8;
          const bf16x8 vh = *(const bf16x8*)(wvh + wi2);
          const bf16x8 vl = *(const bf16x8*)(wvl + wi2);
#pragma unroll
          for (int ns = 0; ns < 4; ++ns) {
            accv[s][ns] = __builtin_amdgcn_mfma_f32_16x16x32_bf16(vh, bh[ns], accv[s][ns], 0, 0, 0);
            accv[s][ns] = __builtin_amdgcn_mfma_f32_16x16x32_bf16(vh, bl[ns], accv[s][ns], 0, 0, 0);
            accv[s][ns] = __builtin_amdgcn_mfma_f32_16x16x32_bf16(vl, bh[ns], accv[s][ns], 0, 0, 0);
          }
        }
      }
#pragma unroll
      for (int s = 0; s < 4; ++s) {
        const size_t wi3 = (((size_t)kk * 16 + wv * 4 + s) * 64 + lane) * 8;
        const bf16x8 dh = *(const bf16x8*)(wdh + wi3);
        const bf16x8 dl = *(const bf16x8*)(wdl + wi3);
#pragma unroll
        for (int ns = 0; ns < 4; ++ns) {
          accd[s][ns] = __builtin_amdgcn_mfma_f32_16x16x32_bf16(dh, bh[ns], accd[s][ns], 0, 0, 0);
          accd[s][ns] = __builtin_amdgcn_mfma_f32_16x16x32_bf16(dh, bl[ns], accd[s][ns], 0, 0, 0);
          accd[s][ns] = __builtin_amdgcn_mfma_f32_16x16x32_bf16(dl, bh[ns], accd[s][ns], 0, 0, 0);
        }
      }
    }
    __syncthreads();  // LDS reads done before next half's phase A overwrites
  }
  // epilogues
  if (HASQV) {
    const int o0 = wv * 16 + fq * 4;
#pragma unroll
    for (int ns = 0; ns < 4; ++ns) {
      const int n = n0 + ns * 16 + fr;
      ushort_t h4[4], l4[4];
#pragma unroll
      for (int r = 0; r < 4; ++r) {
        const float v = accq[ns][r] + qbias[o0 + r];
        h4[r] = f2bu(v);
        l4[r] = f2bu(v - us2f(h4[r]));
      }
      *(ushort4*)(Qh + ((size_t)b * kN + n) * kH + o0) = *(const ushort4*)h4;
      *(ushort4*)(Ql + ((size_t)b * kN + n) * kH + o0) = *(const ushort4*)l4;
    }
#pragma unroll
    for (int s = 0; s < 4; ++s) {
      const int oV = (wv * 4 + s) * 16 + fq * 4;
#pragma unroll
      for (int ns = 0; ns < 4; ++ns) {
        const int n = n0 + ns * 16 + fr;
#pragma unroll
        for (int r = 0; r < 4; ++r)
          Vo[((size_t)b * kC + oV + r) * kN + n] =
              __float2bfloat16(accv[s][ns][r] + vbias[oV + r]);
      }
    }
  }
#pragma unroll
  for (int s = 0; s < 4; ++s) {
    const int oD = (wv * 4 + s) * 16 + fq * 4;
#pragma unroll
    for (int ns = 0; ns < 4; ++ns) {
      const int n = n0 + ns * 16 + fr;
#pragma unroll
      for (int r = 0; r < 4; ++r) {
        float* pp = hacc + ((size_t)b * kC + oD + r) * kN + n;
        *pp = *pp + accd[s][ns][r];
      }
    }
  }
}

// ---------------------------------------------------------------------------
// T-conv (split-bf16 MFMA): Y split bf16 IN-PLACE over (o1,o2) + BN partials
// (in-place safe: block reads all its own rows before storing them)
// ---------------------------------------------------------------------------
__global__ __launch_bounds__(256) void k_tconv(
    const ushort_t* __restrict__ xh, const ushort_t* __restrict__ xl,
    const ushort_t* __restrict__ wfh, const ushort_t* __restrict__ wfl,
    const float* __restrict__ bias,
    ushort_t* __restrict__ o1, ushort_t* __restrict__ o2,
    float* __restrict__ of) {
  const int t = threadIdx.x;
  const int b = blockIdx.y;
  const int n0 = blockIdx.x * 64;
  const int lane = t & 63, wv = t >> 6;
  const int fr = lane & 15, fq = lane >> 4;
  const ushort_t* xbh = xh + ((size_t)b * kN + n0) * kC;
  const ushort_t* xbl = xl + ((size_t)b * kN + n0) * kC;
  f32x4 acc[4][4];
#pragma unroll
  for (int s = 0; s < 4; ++s)
#pragma unroll
    for (int ns = 0; ns < 4; ++ns) acc[s][ns] = (f32x4){0.f, 0.f, 0.f, 0.f};
  for (int kk = 0; kk < 8; ++kk) {
    bf16x8 bh[4], bl[4];
#pragma unroll
    for (int ns = 0; ns < 4; ++ns) {
      const size_t xi = (size_t)(ns * 16 + fr) * kC + kk * 32 + fq * 8;
      bh[ns] = *(const bf16x8*)(xbh + xi);
      bl[ns] = *(const bf16x8*)(xbl + xi);
    }
#pragma unroll
    for (int s = 0; s < 4; ++s) {
      const size_t wi = (((size_t)kk * 16 + wv * 4 + s) * 64 + lane) * 8;
      const bf16x8 ah = *(const bf16x8*)(wfh + wi);
      const bf16x8 al = *(const bf16x8*)(wfl + wi);
#pragma unroll
      for (int ns = 0; ns < 4; ++ns) {
        acc[s][ns] = __builtin_amdgcn_mfma_f32_16x16x32_bf16(ah, bh[ns], acc[s][ns], 0, 0, 0);
        acc[s][ns] = __builtin_amdgcn_mfma_f32_16x16x32_bf16(ah, bl[ns], acc[s][ns], 0, 0, 0);
        acc[s][ns] = __builtin_amdgcn_mfma_f32_16x16x32_bf16(al, bh[ns], acc[s][ns], 0, 0, 0);
      }
    }
  }
  __syncthreads();  // all reads of x (aliased with o1/o2) complete block-wide
  const int blk = blockIdx.y * gridDim.x + blockIdx.x;  // 0..511
#pragma unroll
  for (int s = 0; s < 4; ++s) {
    const int o0 = (wv * 4 + s) * 16 + fq * 4;
    float yv[4][4];  // [ns][r]
#pragma unroll
    for (int ns = 0; ns < 4; ++ns) {
      const int n = n0 + ns * 16 + fr;
      const size_t idx = ((size_t)b * kN + n) * kC + o0;
      ushort_t h4[4], l4[4];
#pragma unroll
      for (int r = 0; r < 4; ++r) {
        const float y = acc[s][ns][r] + bias[o0 + r];
        yv[ns][r] = y;
        h4[r] = f2bu(y);
        l4[r] = f2bu(y - us2f(h4[r]));
      }
      *(ushort4*)(o1 + idx) = *(const ushort4*)h4;
      *(ushort4*)(o2 + idx) = *(const ushort4*)l4;
    }
#pragma unroll
    for (int r = 0; r < 4; ++r) {
      float s1 = yv[0][r] + yv[1][r] + yv[2][r] + yv[3][r];
      float s2 = yv[0][r] * yv[0][r] + yv[1][r] * yv[1][r] +
                 yv[2][r] * yv[2][r] + yv[3][r] * yv[3][r];
#pragma unroll
      for (int mask = 1; mask < 16; mask <<= 1) {
        s1 += __shfl_xor(s1, mask);
        s2 += __shfl_xor(s2, mask);
      }
      if (fr == 0) {
        of[(size_t)(o0 + r) * 512 + blk] = s1;
        of[131072 + (size_t)(o0 + r) * 512 + blk] = s2;
      }
    }
  }
}

// ---------------------------------------------------------------------------
// Reduce BN partials -> fused affine: af[c] = g*rsig, cf[c] = bb - af*mean
// ---------------------------------------------------------------------------
__global__ __launch_bounds__(128) void k_bnred(const float* __restrict__ part,
                                               const float* __restrict__ g,
                                               const float* __restrict__ bb,
                                               float* __restrict__ af,
                                               float* __restrict__ cf) {
  const int c = blockIdx.x, t = threadIdx.x;
  const float4 v1 = *(const float4*)&part[(size_t)c * 512 + t * 4];
  const float4 v2 = *(const float4*)&part[131072 + (size_t)c * 512 + t * 4];
  float s1 = v1.x + v1.y + v1.z + v1.w;
  float s2 = v2.x + v2.y + v2.z + v2.w;
  __shared__ float r1[128], r2[128];
  r1[t] = s1;
  r2[t] = s2;
  __syncthreads();
  for (int k = 64; k > 0; k >>= 1) {
    if (t < k) {
      r1[t] += r1[t + k];
      r2[t] += r2[t + k];
    }
    __syncthreads();
  }
  if (t == 0) {
    const float im = 1.f / (float)(kB * kN);
    const float m = r1[0] * im;
    const float var = r2[0] * im - m * m;
    const float a = g[c] * rsqrtf(var + 1e-5f);
    af[c] = a;
    cf[c] = bb[c] - a * m;
  }
}

// ---------------------------------------------------------------------------
// Row softmax stats via split-bf16 MFMA (round-10 version).
// ---------------------------------------------------------------------------
__global__ __launch_bounds__(256) void k_rowstats(const ushort_t* __restrict__ Qhi,
                                                  const ushort_t* __restrict__ Qlo,
                                                  float* __restrict__ rmx,
                                                  float* __restrict__ rsn) {
  __shared__ __align__(16) ushort_t Bh[2][64][72];
  __shared__ __align__(16) ushort_t Bl[2][64][72];
  const int b = blockIdx.y, t = threadIdx.x;
  const int r0 = blockIdx.x * 64;
  const int lane = t & 63, w = t >> 6;
  const int fr = lane & 15, fq = lane >> 4;
  const size_t qbase = (size_t)b * kN * kH;
  bf16x8 ah0, ah1, al0, al1;
  {
    const ushort_t* qh = Qhi + qbase + (size_t)(r0 + w * 16 + fr) * kH;
    const ushort_t* ql = Qlo + qbase + (size_t)(r0 + w * 16 + fr) * kH;
    ah0 = *(const bf16x8*)(qh + fq * 8);
    ah1 = *(const bf16x8*)(qh + 32 + fq * 8);
    al0 = *(const bf16x8*)(ql + fq * 8);
    al1 = *(const bf16x8*)(ql + 32 + fq * 8);
  }
  float mx[4] = {-3.0e38f, -3.0e38f, -3.0e38f, -3.0e38f};
  float sm[4] = {0.f, 0.f, 0.f, 0.f};
  const int srow = t >> 2, scol = (t & 3) * 16;
  {
    const ushort_t* qh = Qhi + qbase + (size_t)srow * kH + scol;
    const ushort_t* ql = Qlo + qbase + (size_t)srow * kH + scol;
    *(uint4*)&Bh[0][srow][scol] = *(const uint4*)qh;
    *(uint4*)&Bh[0][srow][scol + 8] = *(const uint4*)(qh + 8);
    *(uint4*)&Bl[0][srow][scol] = *(const uint4*)ql;
    *(uint4*)&Bl[0][srow][scol + 8] = *(const uint4*)(ql + 8);
  }
  __syncthreads();
  int cur = 0;
  for (int m0 = 0; m0 < kN; m0 += 64) {
    uint4 rh0, rh1, rl0, rl1;
    const bool pf = (m0 + 64 < kN);
    if (pf) {
      const ushort_t* qh = Qhi + qbase + (size_t)(m0 + 64 + srow) * kH + scol;
      const ushort_t* ql = Qlo + qbase + (size_t)(m0 + 64 + srow) * kH + scol;
      rh0 = *(const uint4*)qh;
      rh1 = *(const uint4*)(qh + 8);
      rl0 = *(const uint4*)ql;
      rl1 = *(const uint4*)(ql + 8);
    }
    float ev[4][4];
#pragma unroll
    for (int cs = 0; cs < 4; ++cs) {
      const bf16x8 bh0 = *(const bf16x8*)&Bh[cur][cs * 16 + fr][fq * 8];
      const bf16x8 bh1 = *(const bf16x8*)&Bh[cur][cs * 16 + fr][32 + fq * 8];
      const bf16x8 bl0 = *(const bf16x8*)&Bl[cur][cs * 16 + fr][fq * 8];
      const bf16x8 bl1 = *(const bf16x8*)&Bl[cur][cs * 16 + fr][32 + fq * 8];
      f32x4 e = {0.f, 0.f, 0.f, 0.f};
      e = __builtin_amdgcn_mfma_f32_16x16x32_bf16(ah0, bh0, e, 0, 0, 0);
      e = __builtin_amdgcn_mfma_f32_16x16x32_bf16(ah1, bh1, e, 0, 0, 0);
      e = __builtin_amdgcn_mfma_f32_16x16x32_bf16(ah0, bl0, e, 0, 0, 0);
      e = __builtin_amdgcn_mfma_f32_16x16x32_bf16(ah1, bl1, e, 0, 0, 0);
      e = __builtin_amdgcn_mfma_f32_16x16x32_bf16(al0, bh0, e, 0, 0, 0);
      e = __builtin_amdgcn_mfma_f32_16x16x32_bf16(al1, bh1, e, 0, 0, 0);
      ev[cs][0] = e[0]; ev[cs][1] = e[1]; ev[cs][2] = e[2]; ev[cs][3] = e[3];
    }
#pragma unroll
    for (int r = 0; r < 4; ++r) {
      const float tmax = fmaxf(fmaxf(ev[0][r], ev[1][r]), fmaxf(ev[2][r], ev[3][r]));
      const float nm = fmaxf(mx[r], tmax);
      sm[r] = sm[r] * __expf(mx[r] - nm) + __expf(ev[0][r] - nm) + __expf(ev[1][r] - nm) +
              __expf(ev[2][r] - nm) + __expf(ev[3][r] - nm);
      mx[r] = nm;
    }
    if (pf) {
      *(uint4*)&Bh[cur ^ 1][srow][scol] = rh0;
      *(uint4*)&Bh[cur ^ 1][srow][scol + 8] = rh1;
      *(uint4*)&Bl[cur ^ 1][srow][scol] = rl0;
      *(uint4*)&Bl[cur ^ 1][srow][scol + 8] = rl1;
    }
    __syncthreads();
    cur ^= 1;
  }
#pragma unroll
  for (int mask = 1; mask < 16; mask <<= 1) {
#pragma unroll
    for (int r = 0; r < 4; ++r) {
      const float om = __shfl_xor(mx[r], mask);
      const float os = __shfl_xor(sm[r], mask);
      const float nm = fmaxf(mx[r], om);
      sm[r] = sm[r] * __expf(mx[r] - nm) + os * __expf(om - nm);
      mx[r] = nm;
    }
  }
  if (fr == 0) {
#pragma unroll
    for (int r = 0; r < 4; ++r) {
      const int row = r0 + w * 16 + fq * 4 + r;
      rmx[(size_t)b * kN + row] = mx[r];
      rsn[(size_t)b * kN + row] = 1.f / sm[r];
    }
  }
}

// ---------------------------------------------------------------------------
// Column pass, MT=64 (round-10 version — measured floor ~124 us).
// ---------------------------------------------------------------------------
__global__ __launch_bounds__(256) void k_colpass(const ushort_t* __restrict__ Qhi,
                                                 const ushort_t* __restrict__ Qlo,
                                                 const bf16* __restrict__ V,
                                                 const float* __restrict__ rmx,
                                                 const float* __restrict__ rsn,
                                                 const ushort_t* __restrict__ psh,
                                                 const ushort_t* __restrict__ psl,
                                                 ushort_t* __restrict__ ush,
                                                 ushort_t* __restrict__ usl) {
  constexpr int MT = 64, NT = 32;
  __shared__ __align__(16) ushort_t Anh[2][NT][72];
  __shared__ __align__(16) ushort_t Anl[2][NT][72];
  __shared__ __align__(16) ushort_t Vs[2][kC][40];
  __shared__ __align__(16) ushort_t Pl[MT][40];
  __shared__ float CsI[MT];
  const int t = threadIdx.x;
  const int b = blockIdx.y;
  const int mBase = blockIdx.x * MT;
  const size_t qbase = (size_t)b * kN * kH;
  const ushort_t* Vb_ = (const ushort_t*)V + (size_t)b * kC * kN;
  const int lane = t & 63, wv = t >> 6;
  const int fr = lane & 15, fq = lane >> 4;
  bf16x8 bmh0, bmh1, bml0, bml1;
  {
    const ushort_t* qh = Qhi + qbase + (size_t)(mBase + wv * 16 + fr) * kH;
    const ushort_t* ql = Qlo + qbase + (size_t)(mBase + wv * 16 + fr) * kH;
    bmh0 = *(const bf16x8*)(qh + fq * 8);
    bmh1 = *(const bf16x8*)(qh + 32 + fq * 8);
    bml0 = *(const bf16x8*)(ql + fq * 8);
    bml1 = *(const bf16x8*)(ql + 32 + fq * 8);
  }
  f32x4 acc[4][4];
#pragma unroll
  for (int i = 0; i < 4; ++i)
#pragma unroll
    for (int j = 0; j < 4; ++j) acc[i][j] = (f32x4){0.f, 0.f, 0.f, 0.f};
  float csloc = 0.f;
  const int arow = t >> 3, acol = (t & 7) * 8;
  const int vc = t >> 2, vq = t & 3;
  {
    *(uint4*)&Anh[0][arow][acol] = *(const uint4*)(Qhi + qbase + (size_t)arow * kH + acol);
    *(uint4*)&Anl[0][arow][acol] = *(const uint4*)(Qlo + qbase + (size_t)arow * kH + acol);
#pragma unroll
    for (int it = 0; it < 4; ++it) {
      const int c = it * 64 + vc;
      *(uint4*)&Vs[0][c][vq * 8] = *(const uint4*)(Vb_ + (size_t)c * kN + vq * 8);
    }
  }
  __syncthreads();
  int cur = 0;
  for (int n0 = 0; n0 < kN; n0 += NT) {
    uint4 rAh, rAl, rV0, rV1, rV2, rV3;
    const bool pf = (n0 + NT < kN);
    if (pf) {
      const int nn = n0 + NT;
      rAh = *(const uint4*)(Qhi + qbase + (size_t)(nn + arow) * kH + acol);
      rAl = *(const uint4*)(Qlo + qbase + (size_t)(nn + arow) * kH + acol);
      rV0 = *(const uint4*)(Vb_ + (size_t)(0 * 64 + vc) * kN + nn + vq * 8);
      rV1 = *(const uint4*)(Vb_ + (size_t)(1 * 64 + vc) * kN + nn + vq * 8);
      rV2 = *(const uint4*)(Vb_ + (size_t)(2 * 64 + vc) * kN + nn + vq * 8);
      rV3 = *(const uint4*)(Vb_ + (size_t)(3 * 64 + vc) * kN + nn + vq * 8);
    }
    const float4 rm0 = *(const float4*)&rmx[(size_t)b * kN + n0 + fq * 4];
    const float4 rm1 = *(const float4*)&rmx[(size_t)b * kN + n0 + 16 + fq * 4];
    const float4 rs0 = *(const float4*)&rsn[(size_t)b * kN + n0 + fq * 4];
    const float4 rs1 = *(const float4*)&rsn[(size_t)b * kN + n0 + 16 + fq * 4];
#pragma unroll
    for (int ns = 0; ns < 2; ++ns) {
      const bf16x8 ah0 = *(const bf16x8*)&Anh[cur][ns * 16 + fr][fq * 8];
      const bf16x8 ah1 = *(const bf16x8*)&Anh[cur][ns * 16 + fr][32 + fq * 8];
      const bf16x8 al0 = *(const bf16x8*)&Anl[cur][ns * 16 + fr][fq * 8];
      const bf16x8 al1 = *(const bf16x8*)&Anl[cur][ns * 16 + fr][32 + fq * 8];
      f32x4 e = {0.f, 0.f, 0.f, 0.f};
      e = __builtin_amdgcn_mfma_f32_16x16x32_bf16(ah0, bmh0, e, 0, 0, 0);
      e = __builtin_amdgcn_mfma_f32_16x16x32_bf16(ah1, bmh1, e, 0, 0, 0);
      e = __builtin_amdgcn_mfma_f32_16x16x32_bf16(ah0, bml0, e, 0, 0, 0);
      e = __builtin_amdgcn_mfma_f32_16x16x32_bf16(ah1, bml1, e, 0, 0, 0);
      e = __builtin_amdgcn_mfma_f32_16x16x32_bf16(al0, bmh0, e, 0, 0, 0);
      e = __builtin_amdgcn_mfma_f32_16x16x32_bf16(al1, bmh1, e, 0, 0, 0);
      const float4 rm = ns ? rm1 : rm0;
      const float4 rs = ns ? rs1 : rs0;
      ushort_t p4[4];
      {
        const float p0 = __expf(e[0] - rm.x) * rs.x;
        const float p1 = __expf(e[1] - rm.y) * rs.y;
        const float p2 = __expf(e[2] - rm.z) * rs.z;
        const float p3 = __expf(e[3] - rm.w) * rs.w;
        p4[0] = f2bu(p0); p4[1] = f2bu(p1); p4[2] = f2bu(p2); p4[3] = f2bu(p3);
        csloc += p0 + p1 + p2 + p3;
      }
      *(ushort4*)&Pl[wv * 16 + fr][ns * 16 + fq * 4] = *(const ushort4*)p4;
    }
    __syncthreads();
    bf16x8 am[4], bv[4];
#pragma unroll
    for (int ms = 0; ms < 4; ++ms)
      am[ms] = *(const bf16x8*)&Pl[ms * 16 + fr][fq * 8];
#pragma unroll
    for (int cs = 0; cs < 4; ++cs)
      bv[cs] = *(const bf16x8*)&Vs[cur][wv * 64 + cs * 16 + fr][fq * 8];
#pragma unroll
    for (int ms = 0; ms < 4; ++ms)
#pragma unroll
      for (int cs = 0; cs < 4; ++cs)
        acc[ms][cs] = __builtin_amdgcn_mfma_f32_16x16x32_bf16(am[ms], bv[cs], acc[ms][cs], 0, 0, 0);
    if (pf) {
      *(uint4*)&Anh[cur ^ 1][arow][acol] = rAh;
      *(uint4*)&Anl[cur ^ 1][arow][acol] = rAl;
      *(uint4*)&Vs[cur ^ 1][0 * 64 + vc][vq * 8] = rV0;
      *(uint4*)&Vs[cur ^ 1][1 * 64 + vc][vq * 8] = rV1;
      *(uint4*)&Vs[cur ^ 1][2 * 64 + vc][vq * 8] = rV2;
      *(uint4*)&Vs[cur ^ 1][3 * 64 + vc][vq * 8] = rV3;
    }
    __syncthreads();
    cur ^= 1;
  }
  csloc += __shfl_xor(csloc, 16);
  csloc += __shfl_xor(csloc, 32);
  if (fq == 0) CsI[wv * 16 + fr] = 1.f / (1e-9f + csloc);
  __syncthreads();
#pragma unroll
  for (int ms = 0; ms < 4; ++ms) {
#pragma unroll
    for (int r = 0; r < 4; ++r) {
      const int ml = ms * 16 + fq * 4 + r;
      const float inv = CsI[ml];
      const size_t row = ((size_t)b * kN + mBase + ml) * kC;
#pragma unroll
      for (int cs = 0; cs < 4; ++cs) {
        const int c = wv * 64 + cs * 16 + fr;
        const float xv = us2f(psh[row + c]) + us2f(psl[row + c]);
        const float u = xv - acc[ms][cs][r] * inv;
        const ushort_t h = f2bu(u);
        ush[row + c] = h;
        usl[row + c] = f2bu(u - us2f(h));
      }
    }
  }
}

// ---------------------------------------------------------------------------
// BN stats per channel over (B, N), fp32 [b][nch][N] input, biased var.
// ---------------------------------------------------------------------------
__global__ __launch_bounds__(256) void k_bnstats(const float* __restrict__ y, int nch,
                                                 float* __restrict__ mean,
                                                 float* __restrict__ rsig) {
  const int c = blockIdx.x, t = threadIdx.x;
  float s = 0.f, s2 = 0.f;
  for (int b = 0; b < kB; ++b) {
    const float* p = y + ((size_t)b * nch + c) * kN;
    for (int n = t; n < kN; n += 256) {
      const float v = p[n];
      s += v;
      s2 += v * v;
    }
  }
  __shared__ float r1[256], r2[256];
  r1[t] = s;
  r2[t] = s2;
  __syncthreads();
  for (int k = 128; k > 0; k >>= 1) {
    if (t < k) {
      r1[t] += r1[t + k];
      r2[t] += r2[t + k];
    }
    __syncthreads();
  }
  if (t == 0) {
    const float im = 1.f / (float)(kB * kN);
    const float m = r1[0] * im;
    const float var = r2[0] * im - m * m;
    mean[c] = m;
    rsig[c] = rsqrtf(var + 1e-5f);
  }
}

// ---------------------------------------------------------------------------
// dc2: tpre[b,j,n] = dc2_b[j] + sum_c dc2_w[j,c] * leaky(bn(h[b,c,n]))
// ---------------------------------------------------------------------------
__global__ __launch_bounds__(256) void k_dc2(const float* __restrict__ h,
                                             const float* __restrict__ mean,
                                             const float* __restrict__ rsig,
                                             const float* __restrict__ g,
                                             const float* __restrict__ bb,
                                             const float* __restrict__ w,
                                             const float* __restrict__ d2b,
                                             float* __restrict__ tpre) {
  __shared__ float wS[3][kC];
  __shared__ float aS[kC], cS[kC];
  const int t = threadIdx.x, b = blockIdx.y;
  const int n = blockIdx.x * 256 + t;
  {
    const float a = g[t] * rsig[t];
    aS[t] = a;
    cS[t] = bb[t] - a * mean[t];
    wS[0][t] = w[t];
    wS[1][t] = w[kC + t];
    wS[2][t] = w[2 * kC + t];
  }
  __syncthreads();
  float a0 = d2b[0], a1 = d2b[1], a2 = d2b[2];
  const float* hb = h + (size_t)b * kC * kN + n;
  for (int c = 0; c < kC; ++c) {
    float z = hb[(size_t)c * kN] * aS[c] + cS[c];
    z = z > 0.f ? z : 0.2f * z;
    a0 += wS[0][c] * z;
    a1 += wS[1][c] * z;
    a2 += wS[2][c] * z;
  }
  tpre[((size_t)b * 3 + 0) * kN + n] = a0;
  tpre[((size_t)b * 3 + 1) * kN + n] = a1;
  tpre[((size_t)b * 3 + 2) * kN + n] = a2;
}

// ---------------------------------------------------------------------------
// Final: out[b,n,j] = tanh(g[j]*(tpre[b,j,n]-mean[j])*rsig[j] + b[j])
// ---------------------------------------------------------------------------
__global__ __launch_bounds__(256) void k_final(const float* __restrict__ tpre,
                                               const float* __restrict__ mean,
                                               const float* __restrict__ rsig,
                                               const float* __restrict__ g,
                                               const float* __restrict__ bb,
                                               float* __restrict__ out) {
  const int i = blockIdx.x * 256 + threadIdx.x;  // over B*N
  const int n = i & (kN - 1), b = i >> 11;
#pragma unroll
  for (int j = 0; j < 3; ++j) {
    const float v = tpre[((size_t)b * 3 + j) * kN + n];
    const float z = g[j] * (v - mean[j]) * rsig[j] + bb[j];
    out[(size_t)i * 3 + j] = tanhf(z);
  }
}

// ---------------------------------------------------------------------------
extern "C" void kernel_launch(void* const* d_in, const int* in_sizes, int n_in,
                              void* d_out, int out_size, void* d_ws, size_t ws_size,
                              hipStream_t stream) {
  const float* feature  = (const float*)d_in[0];
  const float* prior    = (const float*)d_in[1];
  const float* mlp_w    = (const float*)d_in[2];
  const float* mlp_b    = (const float*)d_in[3];
  const float* qk_w     = (const float*)d_in[4];
  const float* qk_b     = (const float*)d_in[5];
  const float* v_w      = (const float*)d_in[6];
  const float* v_b      = (const float*)d_in[7];
  const float* t_w      = (const float*)d_in[8];
  const float* t_b      = (const float*)d_in[9];
  const float* bn_g     = (const float*)d_in[10];
  const float* bn_b     = (const float*)d_in[11];
  const float* dc1_w    = (const float*)d_in[12];
  const float* dc1_bn_g = (const float*)d_in[13];
  const float* dc1_bn_b = (const float*)d_in[14];
  const float* dc2_w    = (const float*)d_in[15];
  const float* dc2_b    = (const float*)d_in[16];
  const float* dc2_bn_g = (const float*)d_in[17];
  const float* dc2_bn_b = (const float*)d_in[18];
  float* out = (float*)d_out;

  // Workspace carve. Total ~125 MiB.
  char* base = (char*)d_ws;
  size_t off = 0;
  auto carve = [&](size_t bytes) {
    char* p = base + off;
    off += (bytes + 255) & ~(size_t)255;
    return p;
  };
  const size_t ne = (size_t)kB * kN * kC;                 // 8,388,608
  ushort_t* psh  = (ushort_t*)carve(ne * 2);              // p hi   16 MiB
  ushort_t* psl  = (ushort_t*)carve(ne * 2);              // p lo   16 MiB
  ushort_t* ush  = (ushort_t*)carve(ne * 2);              // u/Y hi 16 MiB
  ushort_t* usl  = (ushort_t*)carve(ne * 2);              // u/Y lo 16 MiB
  float*    hacc = (float*)carve(ne * 4);                 // dc1    32 MiB
  ushort_t* Qhi  = (ushort_t*)carve((size_t)kB * kN * kH * 2);  // 4 MiB
  ushort_t* Qlo  = (ushort_t*)carve((size_t)kB * kN * kH * 2);  // 4 MiB
  bf16*     Vb   = (bf16*)carve(ne * 2);                  // V      16 MiB
  ushort_t* wfh  = (ushort_t*)carve((size_t)851968 * 2);  // 1.63 MiB
  ushort_t* wfl  = (ushort_t*)carve((size_t)851968 * 2);  // 1.63 MiB
  float*    part = (float*)carve((size_t)2 * 131072 * 4); // 1 MiB
  float*    rmx  = (float*)carve((size_t)kB * kN * 4);
  float*    rsn  = (float*)carve((size_t)kB * kN * 4);
  float*    fb   = (float*)carve((size_t)kB * kC * 4);
  float*    bnm  = (float*)carve(kC * 4);
  float*    bnr  = (float*)carve(kC * 4);
  float*    tpre = (float*)carve((size_t)kB * 3 * kN * 4);

  hipMemsetAsync(hacc, 0, ne * 4, stream);  // dc1 accumulator init
  k_wsplit<<<416, 256, 0, stream>>>(qk_w, v_w, t_w, dc1_w, wfh, wfl);
  k_fb<<<kB * kC, 256, 0, stream>>>(feature, mlp_w, mlp_b, fb);
  k_p0<<<(int)(ne / 256), 256, 0, stream>>>(prior, mlp_w, fb, psh, psl);

  const dim3 gC(kN / 64, kB);
  // layer-0 Q/V
  k_qv<<<gC, 256, 0, stream>>>(psh, psl, wfh, wfl, wfh + 65536, wfl + 65536,
                               qk_b, v_b, Qhi, Qlo, Vb);
  for (int l = 0; l < 4; ++l) {
    const size_t t_off   = 327680 + (size_t)l * 65536;
    const size_t dc1_off = 589824 + (size_t)l * 65536;
    k_rowstats<<<gC, 256, 0, stream>>>(Qhi, Qlo, rmx, rsn);
    k_colpass<<<gC, 256, 0, stream>>>(Qhi, Qlo, Vb, rmx, rsn, psh, psl, ush, usl);
    k_tconv<<<gC, 256, 0, stream>>>(ush, usl, wfh + t_off, wfl + t_off,
                                    t_b + l * kC, ush, usl, part);
    k_bnred<<<kC, 128, 0, stream>>>(part, bn_g + l * kC, bn_b + l * kC, bnm, bnr);
    if (l < 3) {
      const size_t qk_n = (size_t)(l + 1) * 16384;
      const size_t v_n  = 65536 + (size_t)(l + 1) * 65536;
      k_fuse<1><<<gC, 256, 0, stream>>>(ush, usl, psh, psl, bnm, bnr,
                                        wfh + qk_n, wfl + qk_n,
                                        wfh + v_n, wfl + v_n,
                                        wfh + dc1_off, wfl + dc1_off,
                                        qk_b + (l + 1) * kH, v_b + (l + 1) * kC,
                                        Qhi, Qlo, Vb, hacc);
    } else {
      k_fuse<0><<<gC, 256, 0, stream>>>(ush, usl, psh, psl, bnm, bnr,
                                        nullptr, nullptr, nullptr, nullptr,
                                        wfh + dc1_off, wfl + dc1_off,
                                        nullptr, nullptr,
                                        nullptr, nullptr, nullptr, hacc);
    }
  }

  k_bnstats<<<kC, 256, 0, stream>>>(hacc, kC, bnm, bnr);
  k_dc2<<<dim3(kN / 256, kB), 256, 0, stream>>>(hacc, bnm, bnr, dc1_bn_g, dc1_bn_b,
                                                dc2_w, dc2_b, tpre);
  k_bnstats<<<3, 256, 0, stream>>>(tpre, 3, bnm, bnr);
  k_final<<<(kB * kN) / 256, 256, 0, stream>>>(tpre, bnm, bnr, dc2_bn_g, dc2_bn_b, out);
}

// Round 16
// 1078.399 us; speedup vs baseline: 1.4943x; 1.0901x over previous
//
#include <hip/hip_runtime.h>
#include <hip/hip_bf16.h>

typedef __hip_bfloat16 bf16;
typedef unsigned short ushort_t;

// Problem constants
constexpr int kB = 16;    // batch
constexpr int kN = 2048;  // points
constexpr int kF = 1024;  // feat dims
constexpr int kC = 256;   // channels
constexpr int kH = 64;    // head dim

using f32x4 = __attribute__((ext_vector_type(4))) float;
using bf16x8 = __attribute__((ext_vector_type(8))) short;  // 8 bf16 (4 VGPRs)

__device__ __forceinline__ float us2f(unsigned short u) {
  union { unsigned int i; float f; } w;
  w.i = ((unsigned int)u) << 16;
  return w.f;
}
__device__ __forceinline__ unsigned short f2bu(float f) {
  union { bf16 h; unsigned short s; } u;
  u.h = __float2bfloat16(f);
  return u.s;
}

// ---------------------------------------------------------------------------
// fb[b,c] = mlp_b[c] + sum_f mlp_w[c,f] * feature[b,f]
// ---------------------------------------------------------------------------
__global__ __launch_bounds__(256) void k_fb(const float* __restrict__ feat,
                                            const float* __restrict__ mlp_w,
                                            const float* __restrict__ mlp_b,
                                            float* __restrict__ fb) {
  const int b = blockIdx.x >> 8;
  const int c = blockIdx.x & 255;
  const int t = threadIdx.x;
  const float* wr = mlp_w + (size_t)c * (kF + 3);
  const float* fr = feat + (size_t)b * kF;
  float s = 0.f;
  for (int f = t; f < kF; f += 256) s += wr[f] * fr[f];
  __shared__ float red[256];
  red[t] = s;
  __syncthreads();
  for (int k = 128; k > 0; k >>= 1) {
    if (t < k) red[t] += red[t + k];
    __syncthreads();
  }
  if (t == 0) fb[blockIdx.x] = red[0] + mlp_b[c];
}

// ---------------------------------------------------------------------------
// p[b,n,c] = fb[b,c] + sum_{j<3} mlp_w[c,1024+j] * prior[b,j,n]  (split bf16)
// ---------------------------------------------------------------------------
__global__ __launch_bounds__(256) void k_p0(const float* __restrict__ prior,
                                            const float* __restrict__ mlp_w,
                                            const float* __restrict__ fb,
                                            ushort_t* __restrict__ psh,
                                            ushort_t* __restrict__ psl) {
  const size_t i = (size_t)blockIdx.x * 256 + threadIdx.x;  // over B*N*C
  const int c = (int)(i & 255);
  const int n = (int)((i >> 8) & 2047);
  const int b = (int)(i >> 19);
  const float* wr = mlp_w + (size_t)c * (kF + 3) + kF;
  const float* pr = prior + (size_t)b * 3 * kN + n;
  const float v = fb[b * kC + c] + wr[0] * pr[0] + wr[1] * pr[kN] + wr[2] * pr[2 * kN];
  const ushort_t h = f2bu(v);
  psh[i] = h;
  psl[i] = f2bu(v - us2f(h));
}

// ---------------------------------------------------------------------------
// Pre-split weights into MFMA A-fragment order (hi/lo bf16).
// Regions (group = 8 elems): qk 4x2048 | v 4x8192 | t 4x8192 | dc1 4x8192
// ---------------------------------------------------------------------------
__global__ __launch_bounds__(256) void k_wsplit(const float* __restrict__ qk_w,
                                                const float* __restrict__ v_w,
                                                const float* __restrict__ t_w,
                                                const float* __restrict__ dc1_w,
                                                ushort_t* __restrict__ wfh,
                                                ushort_t* __restrict__ wfl) {
  const int idx = blockIdx.x * 256 + threadIdx.x;  // group index
  const float* src;
  int stride, OS_;
  size_t dstoff;
  int g;
  if (idx < 8192) {
    const int l = idx >> 11; g = idx & 2047;
    src = qk_w + (size_t)l * 64 * 256; stride = 256; OS_ = 4;
    dstoff = (size_t)l * 16384;
  } else if (idx < 40960) {
    const int i2 = idx - 8192; const int l = i2 >> 13; g = i2 & 8191;
    src = v_w + (size_t)l * 256 * 256; stride = 256; OS_ = 16;
    dstoff = 65536 + (size_t)l * 65536;
  } else if (idx < 73728) {
    const int i2 = idx - 40960; const int l = i2 >> 13; g = i2 & 8191;
    src = t_w + (size_t)l * 256 * 256; stride = 256; OS_ = 16;
    dstoff = 327680 + (size_t)l * 65536;
  } else {
    const int i2 = idx - 73728; const int l = i2 >> 13; g = i2 & 8191;
    src = dc1_w + (size_t)l * 256; stride = 1024; OS_ = 16;
    dstoff = 589824 + (size_t)l * 65536;
  }
  const int kk = g / (OS_ * 64);
  const int rem = g % (OS_ * 64);
  const int osub = rem >> 6;
  const int lane = rem & 63;
  const int o = osub * 16 + (lane & 15);
  const int c = kk * 32 + (lane >> 4) * 8;
  const float* sp = src + (size_t)o * stride + c;
  ushort_t h[8], l8[8];
#pragma unroll
  for (int j = 0; j < 8; ++j) {
    const float v = sp[j];
    h[j] = f2bu(v);
    l8[j] = f2bu(v - us2f(h[j]));
  }
  *(uint4*)(wfh + dstoff + (size_t)g * 8) = *(const uint4*)h;
  *(uint4*)(wfl + dstoff + (size_t)g * 8) = *(const uint4*)l8;
}

// ---------------------------------------------------------------------------
// Fused Q+V conv for layer 0 (split-bf16 MFMA). Block: 64 n, 4 waves.
// ---------------------------------------------------------------------------
__global__ __launch_bounds__(256) void k_qv(
    const ushort_t* __restrict__ xh, const ushort_t* __restrict__ xl,
    const ushort_t* __restrict__ wqh, const ushort_t* __restrict__ wql,
    const ushort_t* __restrict__ wvh, const ushort_t* __restrict__ wvl,
    const float* __restrict__ qbias, const float* __restrict__ vbias,
    ushort_t* __restrict__ Qh, ushort_t* __restrict__ Ql,
    bf16* __restrict__ Vo) {
  const int t = threadIdx.x;
  const int b = blockIdx.y;
  const int n0 = blockIdx.x * 64;
  const int lane = t & 63, wv = t >> 6;
  const int fr = lane & 15, fq = lane >> 4;
  const ushort_t* xbh = xh + ((size_t)b * kN + n0) * kC;
  const ushort_t* xbl = xl + ((size_t)b * kN + n0) * kC;
  f32x4 accq[4];
  f32x4 accv[4][4];
#pragma unroll
  for (int ns = 0; ns < 4; ++ns) {
    accq[ns] = (f32x4){0.f, 0.f, 0.f, 0.f};
#pragma unroll
    for (int s = 0; s < 4; ++s) accv[s][ns] = (f32x4){0.f, 0.f, 0.f, 0.f};
  }
  for (int kk = 0; kk < 8; ++kk) {
    bf16x8 bh[4], bl[4];
#pragma unroll
    for (int ns = 0; ns < 4; ++ns) {
      const size_t xi = (size_t)(ns * 16 + fr) * kC + kk * 32 + fq * 8;
      bh[ns] = *(const bf16x8*)(xbh + xi);
      bl[ns] = *(const bf16x8*)(xbl + xi);
    }
    {  // Q weights: region OS=4
      const size_t wi = (((size_t)kk * 4 + wv) * 64 + lane) * 8;
      const bf16x8 ah = *(const bf16x8*)(wqh + wi);
      const bf16x8 al = *(const bf16x8*)(wql + wi);
#pragma unroll
      for (int ns = 0; ns < 4; ++ns) {
        accq[ns] = __builtin_amdgcn_mfma_f32_16x16x32_bf16(ah, bh[ns], accq[ns], 0, 0, 0);
        accq[ns] = __builtin_amdgcn_mfma_f32_16x16x32_bf16(ah, bl[ns], accq[ns], 0, 0, 0);
        accq[ns] = __builtin_amdgcn_mfma_f32_16x16x32_bf16(al, bh[ns], accq[ns], 0, 0, 0);
      }
    }
#pragma unroll
    for (int s = 0; s < 4; ++s) {  // V weights: region OS=16
      const size_t wi = (((size_t)kk * 16 + wv * 4 + s) * 64 + lane) * 8;
      const bf16x8 ah = *(const bf16x8*)(wvh + wi);
      const bf16x8 al = *(const bf16x8*)(wvl + wi);
#pragma unroll
      for (int ns = 0; ns < 4; ++ns) {
        accv[s][ns] = __builtin_amdgcn_mfma_f32_16x16x32_bf16(ah, bh[ns], accv[s][ns], 0, 0, 0);
        accv[s][ns] = __builtin_amdgcn_mfma_f32_16x16x32_bf16(ah, bl[ns], accv[s][ns], 0, 0, 0);
        accv[s][ns] = __builtin_amdgcn_mfma_f32_16x16x32_bf16(al, bh[ns], accv[s][ns], 0, 0, 0);
      }
    }
  }
  {
    const int o0 = wv * 16 + fq * 4;
#pragma unroll
    for (int ns = 0; ns < 4; ++ns) {
      const int n = n0 + ns * 16 + fr;
      ushort_t h4[4], l4[4];
#pragma unroll
      for (int r = 0; r < 4; ++r) {
        const float v = accq[ns][r] + qbias[o0 + r];
        h4[r] = f2bu(v);
        l4[r] = f2bu(v - us2f(h4[r]));
      }
      *(ushort4*)(Qh + ((size_t)b * kN + n) * kH + o0) = *(const ushort4*)h4;
      *(ushort4*)(Ql + ((size_t)b * kN + n) * kH + o0) = *(const ushort4*)l4;
    }
  }
#pragma unroll
  for (int s = 0; s < 4; ++s) {
    const int o0 = (wv * 4 + s) * 16 + fq * 4;
#pragma unroll
    for (int ns = 0; ns < 4; ++ns) {
      const int n = n0 + ns * 16 + fr;
#pragma unroll
      for (int r = 0; r < 4; ++r)
        Vo[((size_t)b * kC + o0 + r) * kN + n] = __float2bfloat16(accv[s][ns][r] + vbias[o0 + r]);
    }
  }
}

// ---------------------------------------------------------------------------
// Layer-boundary fusion (round-15 wave-split version + FIRST for hacc).
// ---------------------------------------------------------------------------
template <int HASQV, int FIRST>
__global__ __launch_bounds__(256, 2) void k_fuse(
    const ushort_t* __restrict__ yh, const ushort_t* __restrict__ yl,
    ushort_t* __restrict__ ph, ushort_t* __restrict__ pl,
    const float* __restrict__ af, const float* __restrict__ cf,
    const ushort_t* __restrict__ wqh, const ushort_t* __restrict__ wql,
    const ushort_t* __restrict__ wvh, const ushort_t* __restrict__ wvl,
    const ushort_t* __restrict__ wdh, const ushort_t* __restrict__ wdl,
    const float* __restrict__ qbias, const float* __restrict__ vbias,
    ushort_t* __restrict__ Qh, ushort_t* __restrict__ Ql,
    bf16* __restrict__ Vo, float* __restrict__ hacc) {
  __shared__ __align__(16) ushort_t Sh[64][140];  // p' hi, half tile [n][c128]
  __shared__ __align__(16) ushort_t Sl[64][140];  // p' lo
  const int t = threadIdx.x;
  const int b = blockIdx.y;
  const int n0 = blockIdx.x * 64;
  const int lane = t & 63, wv = t >> 6;
  const int fr = lane & 15, fq = lane >> 4;
  const size_t rowbase = ((size_t)b * kN + n0) * kC;
  f32x4 accq[4];
  f32x4 accv[4][4];
  f32x4 accd[4][4];
#pragma unroll
  for (int ns = 0; ns < 4; ++ns) {
    accq[ns] = (f32x4){0.f, 0.f, 0.f, 0.f};
#pragma unroll
    for (int s = 0; s < 4; ++s) {
      accv[s][ns] = (f32x4){0.f, 0.f, 0.f, 0.f};
      accd[s][ns] = (f32x4){0.f, 0.f, 0.f, 0.f};
    }
  }
  for (int half = 0; half < 2; ++half) {
    // phase A: owner wave computes p' for its kk = half*4 + wv
    {
      const int kkw = half * 4 + wv;
      const int cbase = kkw * 32 + fq * 8;
      const float4 a4a = *(const float4*)(af + cbase);
      const float4 a4b = *(const float4*)(af + cbase + 4);
      const float4 c4a = *(const float4*)(cf + cbase);
      const float4 c4b = *(const float4*)(cf + cbase + 4);
      const float av[8] = {a4a.x, a4a.y, a4a.z, a4a.w, a4b.x, a4b.y, a4b.z, a4b.w};
      const float cv[8] = {c4a.x, c4a.y, c4a.z, c4a.w, c4b.x, c4b.y, c4b.z, c4b.w};
      const int lcol = wv * 32 + fq * 8;  // column within the half tile
#pragma unroll
      for (int ns = 0; ns < 4; ++ns) {
        const size_t idx = rowbase + (size_t)(ns * 16 + fr) * kC + cbase;
        ushort_t yh8[8], yl8[8], p8h[8], p8l[8], nh8[8], nl8[8];
        *(uint4*)yh8 = *(const uint4*)(yh + idx);
        *(uint4*)yl8 = *(const uint4*)(yl + idx);
        *(uint4*)p8h = *(const uint4*)(ph + idx);
        *(uint4*)p8l = *(const uint4*)(pl + idx);
#pragma unroll
        for (int j = 0; j < 8; ++j) {
          const float yv = us2f(yh8[j]) + us2f(yl8[j]);
          float z = av[j] * yv + cv[j];
          z = z > 0.f ? z : 0.2f * z;
          const float pv = us2f(p8h[j]) + us2f(p8l[j]) + z;
          nh8[j] = f2bu(pv);
          nl8[j] = f2bu(pv - us2f(nh8[j]));
        }
        *(uint4*)(ph + idx) = *(const uint4*)nh8;   // single owner: no race
        *(uint4*)(pl + idx) = *(const uint4*)nl8;
        *(uint4*)&Sh[ns * 16 + fr][lcol] = *(const uint4*)nh8;
        *(uint4*)&Sl[ns * 16 + fr][lcol] = *(const uint4*)nl8;
      }
    }
    __syncthreads();  // p' half-tile visible in LDS
    // phase B: MFMAs for the half's 4 kks, B-fragments from LDS
#pragma unroll
    for (int kkl = 0; kkl < 4; ++kkl) {
      const int kk = half * 4 + kkl;
      bf16x8 bh[4], bl[4];
#pragma unroll
      for (int ns = 0; ns < 4; ++ns) {
        bh[ns] = *(const bf16x8*)&Sh[ns * 16 + fr][kkl * 32 + fq * 8];
        bl[ns] = *(const bf16x8*)&Sl[ns * 16 + fr][kkl * 32 + fq * 8];
      }
      if (HASQV) {
        const size_t wi = (((size_t)kk * 4 + wv) * 64 + lane) * 8;
        const bf16x8 ah = *(const bf16x8*)(wqh + wi);
        const bf16x8 al = *(const bf16x8*)(wql + wi);
#pragma unroll
        for (int ns = 0; ns < 4; ++ns) {
          accq[ns] = __builtin_amdgcn_mfma_f32_16x16x32_bf16(ah, bh[ns], accq[ns], 0, 0, 0);
          accq[ns] = __builtin_amdgcn_mfma_f32_16x16x32_bf16(ah, bl[ns], accq[ns], 0, 0, 0);
          accq[ns] = __builtin_amdgcn_mfma_f32_16x16x32_bf16(al, bh[ns], accq[ns], 0, 0, 0);
        }
#pragma unroll
        for (int s = 0; s < 4; ++s) {
          const size_t wi2 = (((size_t)kk * 16 + wv * 4 + s) * 64 + lane) * 8;
          const bf16x8 vh = *(const bf16x8*)(wvh + wi2);
          const bf16x8 vl = *(const bf16x8*)(wvl + wi2);
#pragma unroll
          for (int ns = 0; ns < 4; ++ns) {
            accv[s][ns] = __builtin_amdgcn_mfma_f32_16x16x32_bf16(vh, bh[ns], accv[s][ns], 0, 0, 0);
            accv[s][ns] = __builtin_amdgcn_mfma_f32_16x16x32_bf16(vh, bl[ns], accv[s][ns], 0, 0, 0);
            accv[s][ns] = __builtin_amdgcn_mfma_f32_16x16x32_bf16(vl, bh[ns], accv[s][ns], 0, 0, 0);
          }
        }
      }
#pragma unroll
      for (int s = 0; s < 4; ++s) {
        const size_t wi3 = (((size_t)kk * 16 + wv * 4 + s) * 64 + lane) * 8;
        const bf16x8 dh = *(const bf16x8*)(wdh + wi3);
        const bf16x8 dl = *(const bf16x8*)(wdl + wi3);
#pragma unroll
        for (int ns = 0; ns < 4; ++ns) {
          accd[s][ns] = __builtin_amdgcn_mfma_f32_16x16x32_bf16(dh, bh[ns], accd[s][ns], 0, 0, 0);
          accd[s][ns] = __builtin_amdgcn_mfma_f32_16x16x32_bf16(dh, bl[ns], accd[s][ns], 0, 0, 0);
          accd[s][ns] = __builtin_amdgcn_mfma_f32_16x16x32_bf16(dl, bh[ns], accd[s][ns], 0, 0, 0);
        }
      }
    }
    __syncthreads();  // LDS reads done before next half's phase A overwrites
  }
  // epilogues
  if (HASQV) {
    const int o0 = wv * 16 + fq * 4;
#pragma unroll
    for (int ns = 0; ns < 4; ++ns) {
      const int n = n0 + ns * 16 + fr;
      ushort_t h4[4], l4[4];
#pragma unroll
      for (int r = 0; r < 4; ++r) {
        const float v = accq[ns][r] + qbias[o0 + r];
        h4[r] = f2bu(v);
        l4[r] = f2bu(v - us2f(h4[r]));
      }
      *(ushort4*)(Qh + ((size_t)b * kN + n) * kH + o0) = *(const ushort4*)h4;
      *(ushort4*)(Ql + ((size_t)b * kN + n) * kH + o0) = *(const ushort4*)l4;
    }
#pragma unroll
    for (int s = 0; s < 4; ++s) {
      const int oV = (wv * 4 + s) * 16 + fq * 4;
#pragma unroll
      for (int ns = 0; ns < 4; ++ns) {
        const int n = n0 + ns * 16 + fr;
#pragma unroll
        for (int r = 0; r < 4; ++r)
          Vo[((size_t)b * kC + oV + r) * kN + n] =
              __float2bfloat16(accv[s][ns][r] + vbias[oV + r]);
      }
    }
  }
#pragma unroll
  for (int s = 0; s < 4; ++s) {
    const int oD = (wv * 4 + s) * 16 + fq * 4;
#pragma unroll
    for (int ns = 0; ns < 4; ++ns) {
      const int n = n0 + ns * 16 + fr;
#pragma unroll
      for (int r = 0; r < 4; ++r) {
        float* pp = hacc + ((size_t)b * kC + oD + r) * kN + n;
        *pp = (FIRST ? 0.f : *pp) + accd[s][ns][r];
      }
    }
  }
}

// ---------------------------------------------------------------------------
// Reduce BN partials -> fused affine: af[c] = g*rsig, cf[c] = bb - af*mean
// ---------------------------------------------------------------------------
__global__ __launch_bounds__(128) void k_bnred(const float* __restrict__ part,
                                               const float* __restrict__ g,
                                               const float* __restrict__ bb,
                                               float* __restrict__ af,
                                               float* __restrict__ cf) {
  const int c = blockIdx.x, t = threadIdx.x;
  const float4 v1 = *(const float4*)&part[(size_t)c * 512 + t * 4];
  const float4 v2 = *(const float4*)&part[131072 + (size_t)c * 512 + t * 4];
  float s1 = v1.x + v1.y + v1.z + v1.w;
  float s2 = v2.x + v2.y + v2.z + v2.w;
  __shared__ float r1[128], r2[128];
  r1[t] = s1;
  r2[t] = s2;
  __syncthreads();
  for (int k = 64; k > 0; k >>= 1) {
    if (t < k) {
      r1[t] += r1[t + k];
      r2[t] += r2[t + k];
    }
    __syncthreads();
  }
  if (t == 0) {
    const float im = 1.f / (float)(kB * kN);
    const float m = r1[0] * im;
    const float var = r2[0] * im - m * m;
    const float a = g[c] * rsqrtf(var + 1e-5f);
    af[c] = a;
    cf[c] = bb[c] - a * m;
  }
}

// ---------------------------------------------------------------------------
// Row softmax stats via split-bf16 MFMA (round-10 version).
// ---------------------------------------------------------------------------
__global__ __launch_bounds__(256) void k_rowstats(const ushort_t* __restrict__ Qhi,
                                                  const ushort_t* __restrict__ Qlo,
                                                  float* __restrict__ rmx,
                                                  float* __restrict__ rsn) {
  __shared__ __align__(16) ushort_t Bh[2][64][72];
  __shared__ __align__(16) ushort_t Bl[2][64][72];
  const int b = blockIdx.y, t = threadIdx.x;
  const int r0 = blockIdx.x * 64;
  const int lane = t & 63, w = t >> 6;
  const int fr = lane & 15, fq = lane >> 4;
  const size_t qbase = (size_t)b * kN * kH;
  bf16x8 ah0, ah1, al0, al1;
  {
    const ushort_t* qh = Qhi + qbase + (size_t)(r0 + w * 16 + fr) * kH;
    const ushort_t* ql = Qlo + qbase + (size_t)(r0 + w * 16 + fr) * kH;
    ah0 = *(const bf16x8*)(qh + fq * 8);
    ah1 = *(const bf16x8*)(qh + 32 + fq * 8);
    al0 = *(const bf16x8*)(ql + fq * 8);
    al1 = *(const bf16x8*)(ql + 32 + fq * 8);
  }
  float mx[4] = {-3.0e38f, -3.0e38f, -3.0e38f, -3.0e38f};
  float sm[4] = {0.f, 0.f, 0.f, 0.f};
  const int srow = t >> 2, scol = (t & 3) * 16;
  {
    const ushort_t* qh = Qhi + qbase + (size_t)srow * kH + scol;
    const ushort_t* ql = Qlo + qbase + (size_t)srow * kH + scol;
    *(uint4*)&Bh[0][srow][scol] = *(const uint4*)qh;
    *(uint4*)&Bh[0][srow][scol + 8] = *(const uint4*)(qh + 8);
    *(uint4*)&Bl[0][srow][scol] = *(const uint4*)ql;
    *(uint4*)&Bl[0][srow][scol + 8] = *(const uint4*)(ql + 8);
  }
  __syncthreads();
  int cur = 0;
  for (int m0 = 0; m0 < kN; m0 += 64) {
    uint4 rh0, rh1, rl0, rl1;
    const bool pf = (m0 + 64 < kN);
    if (pf) {
      const ushort_t* qh = Qhi + qbase + (size_t)(m0 + 64 + srow) * kH + scol;
      const ushort_t* ql = Qlo + qbase + (size_t)(m0 + 64 + srow) * kH + scol;
      rh0 = *(const uint4*)qh;
      rh1 = *(const uint4*)(qh + 8);
      rl0 = *(const uint4*)ql;
      rl1 = *(const uint4*)(ql + 8);
    }
    float ev[4][4];
#pragma unroll
    for (int cs = 0; cs < 4; ++cs) {
      const bf16x8 bh0 = *(const bf16x8*)&Bh[cur][cs * 16 + fr][fq * 8];
      const bf16x8 bh1 = *(const bf16x8*)&Bh[cur][cs * 16 + fr][32 + fq * 8];
      const bf16x8 bl0 = *(const bf16x8*)&Bl[cur][cs * 16 + fr][fq * 8];
      const bf16x8 bl1 = *(const bf16x8*)&Bl[cur][cs * 16 + fr][32 + fq * 8];
      f32x4 e = {0.f, 0.f, 0.f, 0.f};
      e = __builtin_amdgcn_mfma_f32_16x16x32_bf16(ah0, bh0, e, 0, 0, 0);
      e = __builtin_amdgcn_mfma_f32_16x16x32_bf16(ah1, bh1, e, 0, 0, 0);
      e = __builtin_amdgcn_mfma_f32_16x16x32_bf16(ah0, bl0, e, 0, 0, 0);
      e = __builtin_amdgcn_mfma_f32_16x16x32_bf16(ah1, bl1, e, 0, 0, 0);
      e = __builtin_amdgcn_mfma_f32_16x16x32_bf16(al0, bh0, e, 0, 0, 0);
      e = __builtin_amdgcn_mfma_f32_16x16x32_bf16(al1, bh1, e, 0, 0, 0);
      ev[cs][0] = e[0]; ev[cs][1] = e[1]; ev[cs][2] = e[2]; ev[cs][3] = e[3];
    }
#pragma unroll
    for (int r = 0; r < 4; ++r) {
      const float tmax = fmaxf(fmaxf(ev[0][r], ev[1][r]), fmaxf(ev[2][r], ev[3][r]));
      const float nm = fmaxf(mx[r], tmax);
      sm[r] = sm[r] * __expf(mx[r] - nm) + __expf(ev[0][r] - nm) + __expf(ev[1][r] - nm) +
              __expf(ev[2][r] - nm) + __expf(ev[3][r] - nm);
      mx[r] = nm;
    }
    if (pf) {
      *(uint4*)&Bh[cur ^ 1][srow][scol] = rh0;
      *(uint4*)&Bh[cur ^ 1][srow][scol + 8] = rh1;
      *(uint4*)&Bl[cur ^ 1][srow][scol] = rl0;
      *(uint4*)&Bl[cur ^ 1][srow][scol + 8] = rl1;
    }
    __syncthreads();
    cur ^= 1;
  }
#pragma unroll
  for (int mask = 1; mask < 16; mask <<= 1) {
#pragma unroll
    for (int r = 0; r < 4; ++r) {
      const float om = __shfl_xor(mx[r], mask);
      const float os = __shfl_xor(sm[r], mask);
      const float nm = fmaxf(mx[r], om);
      sm[r] = sm[r] * __expf(mx[r] - nm) + os * __expf(om - nm);
      mx[r] = nm;
    }
  }
  if (fr == 0) {
#pragma unroll
    for (int r = 0; r < 4; ++r) {
      const int row = r0 + w * 16 + fq * 4 + r;
      rmx[(size_t)b * kN + row] = mx[r];
      rsn[(size_t)b * kN + row] = 1.f / sm[r];
    }
  }
}

// ---------------------------------------------------------------------------
// Column pass + fused T-conv (k_colt). K-loop identical to round-10 colpass;
// epilogue writes split-bf16 u into an LDS overlay (reusing the dead
// An/Vs/Pl region), then runs the T-conv MFMAs from LDS and emits Y
// (split bf16 to ush/usl) + BN partials. u never touches global.
// LDS overlay: K-loop {Anh,Anl,Vs,Pl} 64.5KB  |  epilogue {Uh,Ul} 68KB.
// u rows XOR-swizzled (byte ^ ((row&7)<<3 on ushort index) both sides.
// ---------------------------------------------------------------------------
__global__ __launch_bounds__(256) void k_colt(const ushort_t* __restrict__ Qhi,
                                              const ushort_t* __restrict__ Qlo,
                                              const bf16* __restrict__ V,
                                              const float* __restrict__ rmx,
                                              const float* __restrict__ rsn,
                                              const ushort_t* __restrict__ psh,
                                              const ushort_t* __restrict__ psl,
                                              const ushort_t* __restrict__ wth,
                                              const ushort_t* __restrict__ wtl,
                                              const float* __restrict__ tbias,
                                              ushort_t* __restrict__ ush,   // Y out
                                              ushort_t* __restrict__ usl,
                                              float* __restrict__ part) {
  constexpr int MT = 64, NT = 32;
  // ---- LDS overlay ----
  __shared__ __align__(16) char smem[69888];
  ushort_t (*Anh)[NT][72] = (ushort_t(*)[NT][72])(smem);            //  9216 B
  ushort_t (*Anl)[NT][72] = (ushort_t(*)[NT][72])(smem + 9216);     //  9216 B
  ushort_t (*Vs)[kC][40]  = (ushort_t(*)[kC][40])(smem + 18432);    // 40960 B
  ushort_t (*Pl)[40]      = (ushort_t(*)[40])(smem + 59392);        //  5120 B
  ushort_t (*Uh)[272]     = (ushort_t(*)[272])(smem);               // 34816 B
  ushort_t (*Ul)[272]     = (ushort_t(*)[272])(smem + 34816);       // 34816 B
  float* CsI = (float*)(smem + 69632);                              //   256 B
  const int t = threadIdx.x;
  const int b = blockIdx.y;
  const int mBase = blockIdx.x * MT;
  const size_t qbase = (size_t)b * kN * kH;
  const ushort_t* Vb_ = (const ushort_t*)V + (size_t)b * kC * kN;
  const int lane = t & 63, wv = t >> 6;
  const int fr = lane & 15, fq = lane >> 4;
  bf16x8 bmh0, bmh1, bml0, bml1;
  {
    const ushort_t* qh = Qhi + qbase + (size_t)(mBase + wv * 16 + fr) * kH;
    const ushort_t* ql = Qlo + qbase + (size_t)(mBase + wv * 16 + fr) * kH;
    bmh0 = *(const bf16x8*)(qh + fq * 8);
    bmh1 = *(const bf16x8*)(qh + 32 + fq * 8);
    bml0 = *(const bf16x8*)(ql + fq * 8);
    bml1 = *(const bf16x8*)(ql + 32 + fq * 8);
  }
  f32x4 acc[4][4];
#pragma unroll
  for (int i = 0; i < 4; ++i)
#pragma unroll
    for (int j = 0; j < 4; ++j) acc[i][j] = (f32x4){0.f, 0.f, 0.f, 0.f};
  float csloc = 0.f;
  const int arow = t >> 3, acol = (t & 7) * 8;
  const int vc = t >> 2, vq = t & 3;
  {
    *(uint4*)&Anh[0][arow][acol] = *(const uint4*)(Qhi + qbase + (size_t)arow * kH + acol);
    *(uint4*)&Anl[0][arow][acol] = *(const uint4*)(Qlo + qbase + (size_t)arow * kH + acol);
#pragma unroll
    for (int it = 0; it < 4; ++it) {
      const int c = it * 64 + vc;
      *(uint4*)&Vs[0][c][vq * 8] = *(const uint4*)(Vb_ + (size_t)c * kN + vq * 8);
    }
  }
  __syncthreads();
  int cur = 0;
  for (int n0 = 0; n0 < kN; n0 += NT) {
    uint4 rAh, rAl, rV0, rV1, rV2, rV3;
    const bool pf = (n0 + NT < kN);
    if (pf) {
      const int nn = n0 + NT;
      rAh = *(const uint4*)(Qhi + qbase + (size_t)(nn + arow) * kH + acol);
      rAl = *(const uint4*)(Qlo + qbase + (size_t)(nn + arow) * kH + acol);
      rV0 = *(const uint4*)(Vb_ + (size_t)(0 * 64 + vc) * kN + nn + vq * 8);
      rV1 = *(const uint4*)(Vb_ + (size_t)(1 * 64 + vc) * kN + nn + vq * 8);
      rV2 = *(const uint4*)(Vb_ + (size_t)(2 * 64 + vc) * kN + nn + vq * 8);
      rV3 = *(const uint4*)(Vb_ + (size_t)(3 * 64 + vc) * kN + nn + vq * 8);
    }
    const float4 rm0 = *(const float4*)&rmx[(size_t)b * kN + n0 + fq * 4];
    const float4 rm1 = *(const float4*)&rmx[(size_t)b * kN + n0 + 16 + fq * 4];
    const float4 rs0 = *(const float4*)&rsn[(size_t)b * kN + n0 + fq * 4];
    const float4 rs1 = *(const float4*)&rsn[(size_t)b * kN + n0 + 16 + fq * 4];
#pragma unroll
    for (int ns = 0; ns < 2; ++ns) {
      const bf16x8 ah0 = *(const bf16x8*)&Anh[cur][ns * 16 + fr][fq * 8];
      const bf16x8 ah1 = *(const bf16x8*)&Anh[cur][ns * 16 + fr][32 + fq * 8];
      const bf16x8 al0 = *(const bf16x8*)&Anl[cur][ns * 16 + fr][fq * 8];
      const bf16x8 al1 = *(const bf16x8*)&Anl[cur][ns * 16 + fr][32 + fq * 8];
      f32x4 e = {0.f, 0.f, 0.f, 0.f};
      e = __builtin_amdgcn_mfma_f32_16x16x32_bf16(ah0, bmh0, e, 0, 0, 0);
      e = __builtin_amdgcn_mfma_f32_16x16x32_bf16(ah1, bmh1, e, 0, 0, 0);
      e = __builtin_amdgcn_mfma_f32_16x16x32_bf16(ah0, bml0, e, 0, 0, 0);
      e = __builtin_amdgcn_mfma_f32_16x16x32_bf16(ah1, bml1, e, 0, 0, 0);
      e = __builtin_amdgcn_mfma_f32_16x16x32_bf16(al0, bmh0, e, 0, 0, 0);
      e = __builtin_amdgcn_mfma_f32_16x16x32_bf16(al1, bmh1, e, 0, 0, 0);
      const float4 rm = ns ? rm1 : rm0;
      const float4 rs = ns ? rs1 : rs0;
      ushort_t p4[4];
      {
        const float p0 = __expf(e[0] - rm.x) * rs.x;
        const float p1 = __expf(e[1] - rm.y) * rs.y;
        const float p2 = __expf(e[2] - rm.z) * rs.z;
        const float p3 = __expf(e[3] - rm.w) * rs.w;
        p4[0] = f2bu(p0); p4[1] = f2bu(p1); p4[2] = f2bu(p2); p4[3] = f2bu(p3);
        csloc += p0 + p1 + p2 + p3;
      }
      *(ushort4*)&Pl[wv * 16 + fr][ns * 16 + fq * 4] = *(const ushort4*)p4;
    }
    __syncthreads();
    bf16x8 am[4], bv[4];
#pragma unroll
    for (int ms = 0; ms < 4; ++ms)
      am[ms] = *(const bf16x8*)&Pl[ms * 16 + fr][fq * 8];
#pragma unroll
    for (int cs = 0; cs < 4; ++cs)
      bv[cs] = *(const bf16x8*)&Vs[cur][wv * 64 + cs * 16 + fr][fq * 8];
#pragma unroll
    for (int ms = 0; ms < 4; ++ms)
#pragma unroll
      for (int cs = 0; cs < 4; ++cs)
        acc[ms][cs] = __builtin_amdgcn_mfma_f32_16x16x32_bf16(am[ms], bv[cs], acc[ms][cs], 0, 0, 0);
    if (pf) {
      *(uint4*)&Anh[cur ^ 1][arow][acol] = rAh;
      *(uint4*)&Anl[cur ^ 1][arow][acol] = rAl;
      *(uint4*)&Vs[cur ^ 1][0 * 64 + vc][vq * 8] = rV0;
      *(uint4*)&Vs[cur ^ 1][1 * 64 + vc][vq * 8] = rV1;
      *(uint4*)&Vs[cur ^ 1][2 * 64 + vc][vq * 8] = rV2;
      *(uint4*)&Vs[cur ^ 1][3 * 64 + vc][vq * 8] = rV3;
    }
    __syncthreads();
    cur ^= 1;
  }
  csloc += __shfl_xor(csloc, 16);
  csloc += __shfl_xor(csloc, 32);
  if (fq == 0) CsI[wv * 16 + fr] = 1.f / (1e-9f + csloc);
  __syncthreads();  // CsI visible; all K-loop LDS reads complete
  // ---- epilogue 1: compute u (split bf16, identical rounding) into LDS ----
#pragma unroll
  for (int ms = 0; ms < 4; ++ms) {
#pragma unroll
    for (int r = 0; r < 4; ++r) {
      const int ml = ms * 16 + fq * 4 + r;
      const float inv = CsI[ml];
      const size_t row = ((size_t)b * kN + mBase + ml) * kC;
      const int sw = (ml & 7) << 3;  // row XOR swizzle (multiple of 8)
#pragma unroll
      for (int cs = 0; cs < 4; ++cs) {
        const int c = wv * 64 + cs * 16 + fr;
        const float xv = us2f(psh[row + c]) + us2f(psl[row + c]);
        const float u = xv - acc[ms][cs][r] * inv;
        const ushort_t h = f2bu(u);
        Uh[ml][c ^ sw] = h;
        Ul[ml][c ^ sw] = f2bu(u - us2f(h));
      }
    }
  }
  __syncthreads();  // u tile complete in LDS
  // ---- T-conv phase: Y = T @ u + bias, B-fragments from LDS ----
  f32x4 acct[4][4];
#pragma unroll
  for (int s = 0; s < 4; ++s)
#pragma unroll
    for (int ns = 0; ns < 4; ++ns) acct[s][ns] = (f32x4){0.f, 0.f, 0.f, 0.f};
  for (int kk = 0; kk < 8; ++kk) {
    bf16x8 bh[4], bl[4];
#pragma unroll
    for (int ns = 0; ns < 4; ++ns) {
      const int urow = ns * 16 + fr;
      const int ucol = (kk * 32 + fq * 8) ^ ((urow & 7) << 3);
      bh[ns] = *(const bf16x8*)&Uh[urow][ucol];
      bl[ns] = *(const bf16x8*)&Ul[urow][ucol];
    }
#pragma unroll
    for (int s = 0; s < 4; ++s) {
      const size_t wi = (((size_t)kk * 16 + wv * 4 + s) * 64 + lane) * 8;
      const bf16x8 ah = *(const bf16x8*)(wth + wi);
      const bf16x8 al = *(const bf16x8*)(wtl + wi);
#pragma unroll
      for (int ns = 0; ns < 4; ++ns) {
        acct[s][ns] = __builtin_amdgcn_mfma_f32_16x16x32_bf16(ah, bh[ns], acct[s][ns], 0, 0, 0);
        acct[s][ns] = __builtin_amdgcn_mfma_f32_16x16x32_bf16(ah, bl[ns], acct[s][ns], 0, 0, 0);
        acct[s][ns] = __builtin_amdgcn_mfma_f32_16x16x32_bf16(al, bh[ns], acct[s][ns], 0, 0, 0);
      }
    }
  }
  // ---- Y epilogue + BN partials (identical to old k_tconv) ----
  const int blk = blockIdx.y * gridDim.x + blockIdx.x;  // 0..511
#pragma unroll
  for (int s = 0; s < 4; ++s) {
    const int o0 = (wv * 4 + s) * 16 + fq * 4;
    float yv[4][4];  // [ns][r]
#pragma unroll
    for (int ns = 0; ns < 4; ++ns) {
      const int n = mBase + ns * 16 + fr;
      const size_t idx = ((size_t)b * kN + n) * kC + o0;
      ushort_t h4[4], l4[4];
#pragma unroll
      for (int r = 0; r < 4; ++r) {
        const float y = acct[s][ns][r] + tbias[o0 + r];
        yv[ns][r] = y;
        h4[r] = f2bu(y);
        l4[r] = f2bu(y - us2f(h4[r]));
      }
      *(ushort4*)(ush + idx) = *(const ushort4*)h4;
      *(ushort4*)(usl + idx) = *(const ushort4*)l4;
    }
#pragma unroll
    for (int r = 0; r < 4; ++r) {
      float s1 = yv[0][r] + yv[1][r] + yv[2][r] + yv[3][r];
      float s2 = yv[0][r] * yv[0][r] + yv[1][r] * yv[1][r] +
                 yv[2][r] * yv[2][r] + yv[3][r] * yv[3][r];
#pragma unroll
      for (int mask = 1; mask < 16; mask <<= 1) {
        s1 += __shfl_xor(s1, mask);
        s2 += __shfl_xor(s2, mask);
      }
      if (fr == 0) {
        part[(size_t)(o0 + r) * 512 + blk] = s1;
        part[131072 + (size_t)(o0 + r) * 512 + blk] = s2;
      }
    }
  }
}

// ---------------------------------------------------------------------------
// BN stats per channel over (B, N), fp32 [b][nch][N] input, biased var.
// ---------------------------------------------------------------------------
__global__ __launch_bounds__(256) void k_bnstats(const float* __restrict__ y, int nch,
                                                 float* __restrict__ mean,
                                                 float* __restrict__ rsig) {
  const int c = blockIdx.x, t = threadIdx.x;
  float s = 0.f, s2 = 0.f;
  for (int b = 0; b < kB; ++b) {
    const float* p = y + ((size_t)b * nch + c) * kN;
    for (int n = t; n < kN; n += 256) {
      const float v = p[n];
      s += v;
      s2 += v * v;
    }
  }
  __shared__ float r1[256], r2[256];
  r1[t] = s;
  r2[t] = s2;
  __syncthreads();
  for (int k = 128; k > 0; k >>= 1) {
    if (t < k) {
      r1[t] += r1[t + k];
      r2[t] += r2[t + k];
    }
    __syncthreads();
  }
  if (t == 0) {
    const float im = 1.f / (float)(kB * kN);
    const float m = r1[0] * im;
    const float var = r2[0] * im - m * m;
    mean[c] = m;
    rsig[c] = rsqrtf(var + 1e-5f);
  }
}

// ---------------------------------------------------------------------------
// dc2: tpre[b,j,n] = dc2_b[j] + sum_c dc2_w[j,c] * leaky(bn(h[b,c,n]))
// ---------------------------------------------------------------------------
__global__ __launch_bounds__(256) void k_dc2(const float* __restrict__ h,
                                             const float* __restrict__ mean,
                                             const float* __restrict__ rsig,
                                             const float* __restrict__ g,
                                             const float* __restrict__ bb,
                                             const float* __restrict__ w,
                                             const float* __restrict__ d2b,
                                             float* __restrict__ tpre) {
  __shared__ float wS[3][kC];
  __shared__ float aS[kC], cS[kC];
  const int t = threadIdx.x, b = blockIdx.y;
  const int n = blockIdx.x * 256 + t;
  {
    const float a = g[t] * rsig[t];
    aS[t] = a;
    cS[t] = bb[t] - a * mean[t];
    wS[0][t] = w[t];
    wS[1][t] = w[kC + t];
    wS[2][t] = w[2 * kC + t];
  }
  __syncthreads();
  float a0 = d2b[0], a1 = d2b[1], a2 = d2b[2];
  const float* hb = h + (size_t)b * kC * kN + n;
  for (int c = 0; c < kC; ++c) {
    float z = hb[(size_t)c * kN] * aS[c] + cS[c];
    z = z > 0.f ? z : 0.2f * z;
    a0 += wS[0][c] * z;
    a1 += wS[1][c] * z;
    a2 += wS[2][c] * z;
  }
  tpre[((size_t)b * 3 + 0) * kN + n] = a0;
  tpre[((size_t)b * 3 + 1) * kN + n] = a1;
  tpre[((size_t)b * 3 + 2) * kN + n] = a2;
}

// ---------------------------------------------------------------------------
// Final: out[b,n,j] = tanh(g[j]*(tpre[b,j,n]-mean[j])*rsig[j] + b[j])
// ---------------------------------------------------------------------------
__global__ __launch_bounds__(256) void k_final(const float* __restrict__ tpre,
                                               const float* __restrict__ mean,
                                               const float* __restrict__ rsig,
                                               const float* __restrict__ g,
                                               const float* __restrict__ bb,
                                               float* __restrict__ out) {
  const int i = blockIdx.x * 256 + threadIdx.x;  // over B*N
  const int n = i & (kN - 1), b = i >> 11;
#pragma unroll
  for (int j = 0; j < 3; ++j) {
    const float v = tpre[((size_t)b * 3 + j) * kN + n];
    const float z = g[j] * (v - mean[j]) * rsig[j] + bb[j];
    out[(size_t)i * 3 + j] = tanhf(z);
  }
}

// ---------------------------------------------------------------------------
extern "C" void kernel_launch(void* const* d_in, const int* in_sizes, int n_in,
                              void* d_out, int out_size, void* d_ws, size_t ws_size,
                              hipStream_t stream) {
  const float* feature  = (const float*)d_in[0];
  const float* prior    = (const float*)d_in[1];
  const float* mlp_w    = (const float*)d_in[2];
  const float* mlp_b    = (const float*)d_in[3];
  const float* qk_w     = (const float*)d_in[4];
  const float* qk_b     = (const float*)d_in[5];
  const float* v_w      = (const float*)d_in[6];
  const float* v_b      = (const float*)d_in[7];
  const float* t_w      = (const float*)d_in[8];
  const float* t_b      = (const float*)d_in[9];
  const float* bn_g     = (const float*)d_in[10];
  const float* bn_b     = (const float*)d_in[11];
  const float* dc1_w    = (const float*)d_in[12];
  const float* dc1_bn_g = (const float*)d_in[13];
  const float* dc1_bn_b = (const float*)d_in[14];
  const float* dc2_w    = (const float*)d_in[15];
  const float* dc2_b    = (const float*)d_in[16];
  const float* dc2_bn_g = (const float*)d_in[17];
  const float* dc2_bn_b = (const float*)d_in[18];
  float* out = (float*)d_out;

  // Workspace carve. Total ~125 MiB.
  char* base = (char*)d_ws;
  size_t off = 0;
  auto carve = [&](size_t bytes) {
    char* p = base + off;
    off += (bytes + 255) & ~(size_t)255;
    return p;
  };
  const size_t ne = (size_t)kB * kN * kC;                 // 8,388,608
  ushort_t* psh  = (ushort_t*)carve(ne * 2);              // p hi   16 MiB
  ushort_t* psl  = (ushort_t*)carve(ne * 2);              // p lo   16 MiB
  ushort_t* ush  = (ushort_t*)carve(ne * 2);              // Y hi   16 MiB
  ushort_t* usl  = (ushort_t*)carve(ne * 2);              // Y lo   16 MiB
  float*    hacc = (float*)carve(ne * 4);                 // dc1    32 MiB
  ushort_t* Qhi  = (ushort_t*)carve((size_t)kB * kN * kH * 2);  // 4 MiB
  ushort_t* Qlo  = (ushort_t*)carve((size_t)kB * kN * kH * 2);  // 4 MiB
  bf16*     Vb   = (bf16*)carve(ne * 2);                  // V      16 MiB
  ushort_t* wfh  = (ushort_t*)carve((size_t)851968 * 2);  // 1.63 MiB
  ushort_t* wfl  = (ushort_t*)carve((size_t)851968 * 2);  // 1.63 MiB
  float*    part = (float*)carve((size_t)2 * 131072 * 4); // 1 MiB
  float*    rmx  = (float*)carve((size_t)kB * kN * 4);
  float*    rsn  = (float*)carve((size_t)kB * kN * 4);
  float*    fb   = (float*)carve((size_t)kB * kC * 4);
  float*    bnm  = (float*)carve(kC * 4);
  float*    bnr  = (float*)carve(kC * 4);
  float*    tpre = (float*)carve((size_t)kB * 3 * kN * 4);

  k_wsplit<<<416, 256, 0, stream>>>(qk_w, v_w, t_w, dc1_w, wfh, wfl);
  k_fb<<<kB * kC, 256, 0, stream>>>(feature, mlp_w, mlp_b, fb);
  k_p0<<<(int)(ne / 256), 256, 0, stream>>>(prior, mlp_w, fb, psh, psl);

  const dim3 gC(kN / 64, kB);
  // layer-0 Q/V
  k_qv<<<gC, 256, 0, stream>>>(psh, psl, wfh, wfl, wfh + 65536, wfl + 65536,
                               qk_b, v_b, Qhi, Qlo, Vb);
  for (int l = 0; l < 4; ++l) {
    const size_t t_off   = 327680 + (size_t)l * 65536;
    const size_t dc1_off = 589824 + (size_t)l * 65536;
    k_rowstats<<<gC, 256, 0, stream>>>(Qhi, Qlo, rmx, rsn);
    // fused colpass + T-conv (u stays in LDS; Y -> ush/usl + BN partials)
    k_colt<<<gC, 256, 0, stream>>>(Qhi, Qlo, Vb, rmx, rsn, psh, psl,
                                   wfh + t_off, wfl + t_off, t_b + l * kC,
                                   ush, usl, part);
    k_bnred<<<kC, 128, 0, stream>>>(part, bn_g + l * kC, bn_b + l * kC, bnm, bnr);
    if (l == 0) {
      k_fuse<1, 1><<<gC, 256, 0, stream>>>(ush, usl, psh, psl, bnm, bnr,
                                           wfh + 16384, wfl + 16384,
                                           wfh + 131072, wfl + 131072,
                                           wfh + dc1_off, wfl + dc1_off,
                                           qk_b + kH, v_b + kC,
                                           Qhi, Qlo, Vb, hacc);
    } else if (l < 3) {
      const size_t qk_n = (size_t)(l + 1) * 16384;
      const size_t v_n  = 65536 + (size_t)(l + 1) * 65536;
      k_fuse<1, 0><<<gC, 256, 0, stream>>>(ush, usl, psh, psl, bnm, bnr,
                                           wfh + qk_n, wfl + qk_n,
                                           wfh + v_n, wfl + v_n,
                                           wfh + dc1_off, wfl + dc1_off,
                                           qk_b + (l + 1) * kH, v_b + (l + 1) * kC,
                                           Qhi, Qlo, Vb, hacc);
    } else {
      k_fuse<0, 0><<<gC, 256, 0, stream>>>(ush, usl, psh, psl, bnm, bnr,
                                           nullptr, nullptr, nullptr, nullptr,
                                           wfh + dc1_off, wfl + dc1_off,
                                           nullptr, nullptr,
                                           nullptr, nullptr, nullptr, hacc);
    }
  }

  k_bnstats<<<kC, 256, 0, stream>>>(hacc, kC, bnm, bnr);
  k_dc2<<<dim3(kN / 256, kB), 256, 0, stream>>>(hacc, bnm, bnr, dc1_bn_g, dc1_bn_b,
                                                dc2_w, dc2_b, tpre);
  k_bnstats<<<3, 256, 0, stream>>>(tpre, 3, bnm, bnr);
  k_final<<<(kB * kN) / 256, 256, 0, stream>>>(tpre, bnm, bnr, dc2_bn_g, dc2_bn_b, out);
}